// Round 3
// baseline (396.690 us; speedup 1.0000x reference)
//
#include <hip/hip_runtime.h>
#include <hip/hip_bf16.h>

#define BTOT 32768
#define TB 64

typedef __attribute__((ext_vector_type(8))) short bhalf8;   // 8 bf16 = 4 VGPRs
typedef __attribute__((ext_vector_type(4))) float f32x4;    // MFMA acc

static __device__ __forceinline__ unsigned short f2bf(float x) {
    unsigned int u = __float_as_uint(x);
    u = (u + 0x7fffu + ((u >> 16) & 1u)) >> 16;
    return (unsigned short)u;
}
static __device__ __forceinline__ float bf2f(unsigned short s) {
    return __uint_as_float(((unsigned int)s) << 16);
}
static __device__ __forceinline__ float bflo(unsigned int u) {
    return __uint_as_float(u << 16);
}
static __device__ __forceinline__ float bfhi(unsigned int u) {
    return __uint_as_float(u & 0xffff0000u);
}

// ---------------------------------------------------------------------------
// Weight preprocessing into MFMA B-fragment-linear SPLIT bf16 (hi|lo).
// B-frag for (kt, nt): lane l holds B[k=kt*32+(l>>4)*8+j][n=nt*16+(l&15)],
// hi at idx = ((nt*KT+kt)*64 + l)*16 + j, lo at +8+j.
// ws: Mf2  @0       131072 B (M = Wq@Wk^T as [64 x 512], KT=2, NT=32)
//     Wef2 @131072  344064 B (per agent We[96 x 128], KT=3, NT=8)
//     Wvf2 @475136  65536 B  (Wv as [128 x 128], n=h*32+d, KT=4, NT=8)
// Quarantine note: rounds 5/6's fused preprocess + 2-pass t-phase correlated
// with nondeterminism; kept as three kernels + single-pass t-phase.
// R9 lesson: min-waves launch_bounds that forces VGPR below the natural 128
// bin causes massive scratch spills (WRITE_SIZE 128KB->147MB). 128 is the
// proven no-spill bin (R10).
// R10 lesson: barrier count (21->14) and staging-latency hiding moved only
// ~1.5% -> stall is per-phase latency at low wave residency, not barriers.
// ---------------------------------------------------------------------------
__global__ __launch_bounds__(256) void fold_M_frag(
        const float* __restrict__ Wk, const float* __restrict__ Wq,
        unsigned short* __restrict__ Mf2)
{
    int tid = blockIdx.x * 256 + threadIdx.x;   // 32768
    int h  = tid >> 13;
    int jq = (tid >> 7) & 63;
    int j  = tid & 127;
    const float* q = Wq + (h*64 + jq)*32;
    const float* k = Wk + (h*128 + j)*32;
    float acc = 0.f;
#pragma unroll
    for (int d = 0; d < 32; d += 4) {
        float4 a = *(const float4*)(q + d);
        float4 b = *(const float4*)(k + d);
        acc += a.x*b.x + a.y*b.y + a.z*b.z + a.w*b.w;
    }
    unsigned short hi = f2bf(acc);
    unsigned short lo = f2bf(acc - bf2f(hi));
    int n  = h*128 + j;
    int kt = jq >> 5, qd = (jq >> 3) & 3, jj = jq & 7;
    int nt = n >> 4,  ln = n & 15;
    size_t base = (((nt*2 + kt)*64) + qd*16 + ln)*16;
    Mf2[base + jj]     = hi;
    Mf2[base + 8 + jj] = lo;
}

__global__ __launch_bounds__(256) void conv_We(
        const float* __restrict__ We, unsigned short* __restrict__ Wef2)
{
    int tid = blockIdx.x * 256 + threadIdx.x;   // 7*96*128 = 86016
    int a = tid / 12288;
    int r = tid - a*12288;
    int k = r >> 7;          // 0..95
    int n = r & 127;
    float v = (k < 82) ? We[((size_t)a*82 + k)*128 + n] : 0.f;
    unsigned short hi = f2bf(v);
    unsigned short lo = f2bf(v - bf2f(hi));
    int kt = k >> 5, qd = (k >> 3) & 3, j = k & 7;
    int nt = n >> 4, ln = n & 15;
    size_t base = (size_t)a*24576 + (((nt*3 + kt)*64) + qd*16 + ln)*16;
    Wef2[base + j]     = hi;
    Wef2[base + 8 + j] = lo;
}

__global__ __launch_bounds__(256) void conv_Wv(
        const float* __restrict__ Wv, unsigned short* __restrict__ Wvf2)
{
    int tid = blockIdx.x * 256 + threadIdx.x;   // 4*128*32 = 16384
    int h = tid >> 12;
    int j = (tid >> 5) & 127;
    int d = tid & 31;
    float v = Wv[tid];
    unsigned short hi = f2bf(v);
    unsigned short lo = f2bf(v - bf2f(hi));
    int k = j, n = h*32 + d;
    int kt = k >> 5, qd = (k >> 3) & 3, jj = k & 7;
    int nt = n >> 4, ln = n & 15;
    size_t base = (((nt*4 + kt)*64) + qd*16 + ln)*16;
    Wvf2[base + jj]     = hi;
    Wvf2[base + 8 + jj] = lo;
}

// ---------------------------------------------------------------------------
// Fused critic. R11: TB=64 rows/block, 512 threads (8 waves = 2 row-groups
// x 4 heads), 512 blocks -> exactly 2 blocks/CU co-resident (LDS 74752 B,
// VGPR pinned 128 via launch_bounds(512,4) = R10's natural bin).
// Rationale: R10 showed barriers/staging-latency are NOT the stall; counters
// (MfmaUtil 11 / VALU 28 / HBM 3.5 / Occ 23%) say latency-bound at ~8
// waves/CU. Doubling rows/block doubles resident waves per CU (16) with an
// UNCHANGED per-wave program: wave (g = t>>8) handles rows g*32..g*32+31,
// head w = (t>>6)&3. Phase/barrier events per CU halve.
// All LDS producer->consumer pairs cross a __syncthreads (quarantine:
// online-softmax stats in registers; three prep kernels; 1-pass t-phase).
// LDS 74752 B (2 blocks/CU):
//   self : sX f32[64x84]@0, sX1 f32[64x68]@21504, sX2 f32[64x68]@38912,
//          sX1bH bf16[64x72]@56320, sX1bL @65536 (ends 74752)
//   t    : sT bf16[64x520]@0 (66560; overlays self after last sX1b read)
//   agent: sInH bf16[64x104]@0, sInL @13312, sEnH bf16[64x136]@26624,
//          sEnL @44032 (ends 61440)
//   final: sOv f32[64x132]@0 (33792)
// ---------------------------------------------------------------------------
__global__ __launch_bounds__(512, 4) void fused_critic(
    const float* __restrict__ state_one, const float* __restrict__ act_one,
    const float* __restrict__ state_others, const float* __restrict__ act_others,
    const float* __restrict__ W1, const float* __restrict__ b1,
    const float* __restrict__ W2, const float* __restrict__ b2,
    const float* __restrict__ w3_self, const float* __restrict__ be,
    const float* __restrict__ bvp, const float* __restrict__ w3_others,
    const float* __restrict__ Wout, const float* __restrict__ bout,
    const unsigned short* __restrict__ Mf2, const unsigned short* __restrict__ Wef2,
    const unsigned short* __restrict__ Wvf2, float* __restrict__ out)
{
    __shared__ __align__(16) unsigned char smem[74752];
    float*          sX    = (float*)smem;                    // stride 84
    float*          sX1   = (float*)(smem + 21504);          // stride 68
    float*          sX2   = (float*)(smem + 38912);          // stride 68
    unsigned short* sX1bH = (unsigned short*)(smem + 56320); // stride 72
    unsigned short* sX1bL = (unsigned short*)(smem + 65536); // stride 72
    unsigned short* sT    = (unsigned short*)smem;           // stride 520
    unsigned short* sInH  = (unsigned short*)smem;           // stride 104
    unsigned short* sInL  = (unsigned short*)(smem + 13312); // stride 104
    unsigned short* sEnH  = (unsigned short*)(smem + 26624); // stride 136
    unsigned short* sEnL  = (unsigned short*)(smem + 44032); // stride 136
    float*          sOv   = (float*)smem;                    // stride 132

    const int t  = threadIdx.x;
    const int b0 = blockIdx.x * TB;
    const int w  = (t >> 6) & 3;  // head
    const int g  = t >> 8;        // row-group (0: rows 0..31, 1: rows 32..63)
    const int ro = g << 5;        // row offset
    const int l  = t & 63;
    const int m  = l & 15;        // MFMA A row / C col
    const int qd = l >> 4;        // quad

    const int act_r = t >> 3, act_c = t & 7;   // act_r 0..63 covers all rows

    // staging helper: split-bf16 convert regs -> sIn (cols 0..81, 64 rows)
    // thread t covers state rows (t>>4) and (t>>4)+32, cols (t&15)*4..+3
    auto stageIn = [&](const float4& vA, const float4& vB, const float* av) {
        const int r0 = t >> 4, c4 = (t & 15) << 2;
        ushort4 h4, l4;
        h4.x = f2bf(vA.x); l4.x = f2bf(vA.x - bf2f(h4.x));
        h4.y = f2bf(vA.y); l4.y = f2bf(vA.y - bf2f(h4.y));
        h4.z = f2bf(vA.z); l4.z = f2bf(vA.z - bf2f(h4.z));
        h4.w = f2bf(vA.w); l4.w = f2bf(vA.w - bf2f(h4.w));
        *(ushort4*)(sInH + r0*104 + c4) = h4;
        *(ushort4*)(sInL + r0*104 + c4) = l4;
        h4.x = f2bf(vB.x); l4.x = f2bf(vB.x - bf2f(h4.x));
        h4.y = f2bf(vB.y); l4.y = f2bf(vB.y - bf2f(h4.y));
        h4.z = f2bf(vB.z); l4.z = f2bf(vB.z - bf2f(h4.z));
        h4.w = f2bf(vB.w); l4.w = f2bf(vB.w - bf2f(h4.w));
        *(ushort4*)(sInH + (r0+32)*104 + c4) = h4;
        *(ushort4*)(sInL + (r0+32)*104 + c4) = l4;
        if (act_c < 6) {
#pragma unroll
            for (int e = 0; e < 3; ++e) {
                float v = av[e];
                unsigned short hh = f2bf(v);
                sInH[act_r*104 + 64 + act_c*3 + e] = hh;
                sInL[act_r*104 + 64 + act_c*3 + e] = f2bf(v - bf2f(hh));
            }
        }
    };

    // ---- stage self input [64 x 78] f32 ----
    for (int f = t; f < TB*16; f += 512) {
        int r = f >> 4, c4 = (f & 15) << 2;
        *(float4*)(sX + r*84 + c4) =
            *(const float4*)(state_one + (size_t)(b0 + r)*64 + c4);
    }
    for (int f = t; f < TB*14; f += 512) {
        int r = f / 14, c = f - r*14;
        sX[r*84 + 64 + c] = act_one[(size_t)(b0 + r)*14 + c];
    }
    __syncthreads();

    const int cg = t & 15, rg = t >> 4;   // self/final map: 2 rows x 4 cols
    const int c0 = cg << 2;               // rg 0..31 -> rows 0..63

    // ---- phase 1: x1 = relu(x @ W1 + b1) -> sX1 f32 + split bf16 ----
    {
        float acc[2][4] = {};
#pragma unroll 2
        for (int k = 0; k < 78; ++k) {
            float4 wv = *(const float4*)(W1 + k*64 + c0);
            float a0 = sX[(rg*2+0)*84 + k];
            float a1 = sX[(rg*2+1)*84 + k];
            acc[0][0] += a0*wv.x; acc[0][1] += a0*wv.y; acc[0][2] += a0*wv.z; acc[0][3] += a0*wv.w;
            acc[1][0] += a1*wv.x; acc[1][1] += a1*wv.y; acc[1][2] += a1*wv.z; acc[1][3] += a1*wv.w;
        }
        float4 bb = *(const float4*)(b1 + c0);
#pragma unroll
        for (int i = 0; i < 2; ++i) {
            int r = rg*2 + i;
            float v[4];
            v[0] = fmaxf(acc[i][0] + bb.x, 0.f);
            v[1] = fmaxf(acc[i][1] + bb.y, 0.f);
            v[2] = fmaxf(acc[i][2] + bb.z, 0.f);
            v[3] = fmaxf(acc[i][3] + bb.w, 0.f);
#pragma unroll
            for (int e = 0; e < 4; ++e) {
                sX1[r*68 + c0+e] = v[e];
                unsigned short hh = f2bf(v[e]);
                sX1bH[r*72 + c0+e] = hh;
                sX1bL[r*72 + c0+e] = f2bf(v[e] - bf2f(hh));
            }
        }
    }
    __syncthreads();

    // ---- phase 2: x2 = relu(x1 @ W2 + b2) -> sX2 f32 ----
    {
        float acc[2][4] = {};
#pragma unroll 4
        for (int k = 0; k < 64; ++k) {
            float4 wv = *(const float4*)(W2 + k*64 + c0);
            float a0 = sX1[(rg*2+0)*68 + k];
            float a1 = sX1[(rg*2+1)*68 + k];
            acc[0][0] += a0*wv.x; acc[0][1] += a0*wv.y; acc[0][2] += a0*wv.z; acc[0][3] += a0*wv.w;
            acc[1][0] += a1*wv.x; acc[1][1] += a1*wv.y; acc[1][2] += a1*wv.z; acc[1][3] += a1*wv.w;
        }
        float4 bb = *(const float4*)(b2 + c0);
#pragma unroll
        for (int i = 0; i < 2; ++i) {
            int r = rg*2 + i;
            sX2[r*68 + c0+0] = fmaxf(acc[i][0] + bb.x, 0.f);
            sX2[r*68 + c0+1] = fmaxf(acc[i][1] + bb.y, 0.f);
            sX2[r*68 + c0+2] = fmaxf(acc[i][2] + bb.z, 0.f);
            sX2[r*68 + c0+3] = fmaxf(acc[i][3] + bb.w, 0.f);
        }
    }
    __syncthreads();

    // ---- phase 3: x3_self fragment in registers (final-phase map) ----
    float x3s[2][4] = {};
    {
#pragma unroll 4
        for (int k = 0; k < 64; ++k) {
            float4 wv = *(const float4*)(w3_self + k*64 + c0);
            float a0 = sX2[(rg*2+0)*68 + k];
            float a1 = sX2[(rg*2+1)*68 + k];
            x3s[0][0] += a0*wv.x; x3s[0][1] += a0*wv.y; x3s[0][2] += a0*wv.z; x3s[0][3] += a0*wv.w;
            x3s[1][0] += a1*wv.x; x3s[1][1] += a1*wv.y; x3s[1][2] += a1*wv.z; x3s[1][3] += a1*wv.w;
        }
    }

    // ---- phase 4: t = x1 @ M, split 3-term MFMA (~f32), -> sT bf16 ----
    {
        f32x4 tacc[2][8] = {};
#pragma unroll
        for (int kt = 0; kt < 2; ++kt) {
            bhalf8 ah0 = *(const bhalf8*)(sX1bH + (ro+m)*72    + kt*32 + qd*8);
            bhalf8 ah1 = *(const bhalf8*)(sX1bH + (ro+16+m)*72 + kt*32 + qd*8);
            bhalf8 al0 = *(const bhalf8*)(sX1bL + (ro+m)*72    + kt*32 + qd*8);
            bhalf8 al1 = *(const bhalf8*)(sX1bL + (ro+16+m)*72 + kt*32 + qd*8);
#pragma unroll
            for (int nt2 = 0; nt2 < 8; ++nt2) {
                int nt = w*8 + nt2;
                const unsigned short* bp = Mf2 + ((nt*2 + kt)*64 + l)*16;
                bhalf8 bh = *(const bhalf8*)(bp);
                bhalf8 bl = *(const bhalf8*)(bp + 8);
                tacc[0][nt2] = __builtin_amdgcn_mfma_f32_16x16x32_bf16(ah0, bh, tacc[0][nt2], 0, 0, 0);
                tacc[1][nt2] = __builtin_amdgcn_mfma_f32_16x16x32_bf16(ah1, bh, tacc[1][nt2], 0, 0, 0);
                tacc[0][nt2] = __builtin_amdgcn_mfma_f32_16x16x32_bf16(ah0, bl, tacc[0][nt2], 0, 0, 0);
                tacc[1][nt2] = __builtin_amdgcn_mfma_f32_16x16x32_bf16(ah1, bl, tacc[1][nt2], 0, 0, 0);
                tacc[0][nt2] = __builtin_amdgcn_mfma_f32_16x16x32_bf16(al0, bh, tacc[0][nt2], 0, 0, 0);
                tacc[1][nt2] = __builtin_amdgcn_mfma_f32_16x16x32_bf16(al1, bh, tacc[1][nt2], 0, 0, 0);
            }
        }
        __syncthreads();   // all reads of sX1b*/sX2 done before sT overwrite
#pragma unroll
        for (int rt = 0; rt < 2; ++rt)
#pragma unroll
            for (int nt2 = 0; nt2 < 8; ++nt2)
#pragma unroll
                for (int r = 0; r < 4; ++r)
                    sT[(ro + rt*16 + qd*4 + r)*520 + w*128 + nt2*16 + m] =
                        f2bf(tacc[rt][nt2][r]);
    }
    __syncthreads();

    // ---- load this thread's t-slice into registers ----
    const int b_l = l & 31, half = l >> 5;
    uint4 tq[8];
    {
        const uint4* tp4 = (const uint4*)(sT + (ro + b_l)*520 + w*128 + half*64);
#pragma unroll
        for (int i = 0; i < 8; ++i) tq[i] = tp4[i];
    }
    __syncthreads();   // sT region free for sInH/sInL

    // zero-pad sIn cols 82..95 once (80,81 are act cols, staged every agent)
    for (int f = t; f < TB*16; f += 512) {
        int r = f >> 4, c = f & 15;
        if (c >= 2) {
            sInH[r*104 + 80 + c] = 0;
            sInL[r*104 + 80 + c] = 0;
        }
    }
    // stage agent 0 directly (no long-lived prefetch registers)
    {
        const float* sa = state_others + (size_t)b0 * 64;
        float4 vA = *(const float4*)(sa + t*4);
        float4 vB = *(const float4*)(sa + t*4 + 2048);
        float av[3] = {0.f, 0.f, 0.f};
        if (act_c < 6) {
            const float* aa = act_others + (size_t)(b0 + act_r)*18 + act_c*3;
            av[0] = aa[0]; av[1] = aa[1]; av[2] = aa[2];
        }
        stageIn(vA, vB, av);
    }
    __syncthreads();   // sIn(agent 0) ready

    const float bv0 = bvp[w*32 + m];
    const float bv1 = bvp[w*32 + 16 + m];
    f32x4 o4[2][2] = {};
    // online-softmax state for row ro+b_l of head w, replicated in both halves
    float mR = -1e30f, sR = 0.f;

    float4 pfA, pfB; float pfa[3] = {0.f, 0.f, 0.f};

    for (int a = 0; a < 7; ++a) {
        // ---- step 1: issue next agent's HBM loads (regs); hides under enc
        if (a < 6) {
            const float* sa = state_others + ((size_t)(a+1)*BTOT + b0)*64;
            pfA = *(const float4*)(sa + t*4);
            pfB = *(const float4*)(sa + t*4 + 2048);
            if (act_c < 6) {
                const float* aa = act_others
                    + ((size_t)(a+1)*BTOT + b0 + act_r)*18 + act_c*3;
                pfa[0] = aa[0]; pfa[1] = aa[1]; pfa[2] = aa[2];
            }
        }
        float be0 = be[a*128 + 32*w + m];
        float be1 = be[a*128 + 32*w + 16 + m];

        // ---- step 2: enc = inp @ We_a, split 3-term, wave slice 32 cols ----
        f32x4 eacc[2][2] = {};
#pragma unroll
        for (int kt = 0; kt < 3; ++kt) {
            bhalf8 ah0 = *(const bhalf8*)(sInH + (ro+m)*104    + kt*32 + qd*8);
            bhalf8 ah1 = *(const bhalf8*)(sInH + (ro+16+m)*104 + kt*32 + qd*8);
            bhalf8 al0 = *(const bhalf8*)(sInL + (ro+m)*104    + kt*32 + qd*8);
            bhalf8 al1 = *(const bhalf8*)(sInL + (ro+16+m)*104 + kt*32 + qd*8);
#pragma unroll
            for (int nt2 = 0; nt2 < 2; ++nt2) {
                int nt = 2*w + nt2;
                const unsigned short* bp =
                    Wef2 + (size_t)a*24576 + ((nt*3 + kt)*64 + l)*16;
                bhalf8 bh = *(const bhalf8*)(bp);
                bhalf8 bl = *(const bhalf8*)(bp + 8);
                eacc[0][nt2] = __builtin_amdgcn_mfma_f32_16x16x32_bf16(ah0, bh, eacc[0][nt2], 0, 0, 0);
                eacc[1][nt2] = __builtin_amdgcn_mfma_f32_16x16x32_bf16(ah1, bh, eacc[1][nt2], 0, 0, 0);
                eacc[0][nt2] = __builtin_amdgcn_mfma_f32_16x16x32_bf16(ah0, bl, eacc[0][nt2], 0, 0, 0);
                eacc[1][nt2] = __builtin_amdgcn_mfma_f32_16x16x32_bf16(ah1, bl, eacc[1][nt2], 0, 0, 0);
                eacc[0][nt2] = __builtin_amdgcn_mfma_f32_16x16x32_bf16(al0, bh, eacc[0][nt2], 0, 0, 0);
                eacc[1][nt2] = __builtin_amdgcn_mfma_f32_16x16x32_bf16(al1, bh, eacc[1][nt2], 0, 0, 0);
            }
        }

        // ---- B1: enc reads of sIn done; prev logits/vals reads of sEn done
        __syncthreads();

        // ---- step 4: write sEn(a) (relu+bias, split); stage sIn(a+1) ----
        {
#pragma unroll
            for (int rt = 0; rt < 2; ++rt)
#pragma unroll
                for (int nt2 = 0; nt2 < 2; ++nt2) {
                    float bb = nt2 ? be1 : be0;
#pragma unroll
                    for (int r = 0; r < 4; ++r) {
                        float e = fmaxf(eacc[rt][nt2][r] + bb, 0.f);
                        int row = ro + rt*16 + qd*4 + r;
                        int col = 32*w + nt2*16 + m;
                        unsigned short hh = f2bf(e);
                        sEnH[row*136 + col] = hh;
                        sEnL[row*136 + col] = f2bf(e - bf2f(hh));
                    }
                }
        }
        if (a < 6) stageIn(pfA, pfB, pfa);

        // ---- B2: sEn(a) and sIn(a+1) ready
        __syncthreads();

        // ---- step 6a: logits ((hi+lo) f32 enc x bf16 t); stats in regs ----
        float alpha, pp;
        {
            const uint4* ehp = (const uint4*)(sEnH + (ro+b_l)*136 + half*64);
            const uint4* elp = (const uint4*)(sEnL + (ro+b_l)*136 + half*64);
            float part = 0.f;
#pragma unroll
            for (int i = 0; i < 8; ++i) {
                uint4 eh = ehp[i];
                uint4 el = elp[i];
                uint4 tt = tq[i];
                part += (bflo(eh.x)+bflo(el.x))*bflo(tt.x)
                      + (bfhi(eh.x)+bfhi(el.x))*bfhi(tt.x);
                part += (bflo(eh.y)+bflo(el.y))*bflo(tt.y)
                      + (bfhi(eh.y)+bfhi(el.y))*bfhi(tt.y);
                part += (bflo(eh.z)+bflo(el.z))*bflo(tt.z)
                      + (bfhi(eh.z)+bfhi(el.z))*bfhi(tt.z);
                part += (bflo(eh.w)+bflo(el.w))*bflo(tt.w)
                      + (bfhi(eh.w)+bfhi(el.w))*bfhi(tt.w);
            }
            part += __shfl_xor(part, 32);   // both halves now bit-identical
            float lg = part * 0.17677669529663687f;   // 1/sqrt(32)
            float mn = fmaxf(mR, lg);
            alpha = __expf(mR - mn);
            pp    = __expf(lg - mn);
            sR = sR*alpha + pp;
            mR = mn;
        }

        // ---- step 6b: vals = relu(enc @ Wv + bv); online accumulate ----
        {
            f32x4 vacc[2][2] = {};
#pragma unroll
            for (int kt = 0; kt < 4; ++kt) {
                bhalf8 ah0 = *(const bhalf8*)(sEnH + (ro+m)*136    + kt*32 + qd*8);
                bhalf8 ah1 = *(const bhalf8*)(sEnH + (ro+16+m)*136 + kt*32 + qd*8);
                bhalf8 al0 = *(const bhalf8*)(sEnL + (ro+m)*136    + kt*32 + qd*8);
                bhalf8 al1 = *(const bhalf8*)(sEnL + (ro+16+m)*136 + kt*32 + qd*8);
#pragma unroll
                for (int nt2 = 0; nt2 < 2; ++nt2) {
                    int nt = 2*w + nt2;
                    const unsigned short* bp = Wvf2 + ((nt*4 + kt)*64 + l)*16;
                    bhalf8 bh = *(const bhalf8*)(bp);
                    bhalf8 bl = *(const bhalf8*)(bp + 8);
                    vacc[0][nt2] = __builtin_amdgcn_mfma_f32_16x16x32_bf16(ah0, bh, vacc[0][nt2], 0, 0, 0);
                    vacc[1][nt2] = __builtin_amdgcn_mfma_f32_16x16x32_bf16(ah1, bh, vacc[1][nt2], 0, 0, 0);
                    vacc[0][nt2] = __builtin_amdgcn_mfma_f32_16x16x32_bf16(ah0, bl, vacc[0][nt2], 0, 0, 0);
                    vacc[1][nt2] = __builtin_amdgcn_mfma_f32_16x16x32_bf16(ah1, bl, vacc[1][nt2], 0, 0, 0);
                    vacc[0][nt2] = __builtin_amdgcn_mfma_f32_16x16x32_bf16(al0, bh, vacc[0][nt2], 0, 0, 0);
                    vacc[1][nt2] = __builtin_amdgcn_mfma_f32_16x16x32_bf16(al1, bh, vacc[1][nt2], 0, 0, 0);
                }
            }
#pragma unroll
            for (int rt = 0; rt < 2; ++rt)
#pragma unroll
                for (int r = 0; r < 4; ++r) {
                    int row = rt*16 + qd*4 + r;   // lane holding stats (0..31)
                    float al = __shfl(alpha, row);
                    float p  = __shfl(pp, row);
#pragma unroll
                    for (int nt2 = 0; nt2 < 2; ++nt2) {
                        float bb = nt2 ? bv1 : bv0;
                        o4[rt][nt2][r] = o4[rt][nt2][r]*al
                                       + p*fmaxf(vacc[rt][nt2][r] + bb, 0.f);
                    }
                }
        }
    }
    __syncthreads();   // all sEn reads done; sOv overwrites union region

    // ---- normalize (1/s via shfl) and dump ov to sOv f32 (stride 132) ----
    {
        float rinv = 1.0f / sR;
#pragma unroll
        for (int rt = 0; rt < 2; ++rt)
#pragma unroll
            for (int r = 0; r < 4; ++r) {
                int row = rt*16 + qd*4 + r;
                float inv = __shfl(rinv, row);
#pragma unroll
                for (int nt2 = 0; nt2 < 2; ++nt2)
                    sOv[(ro + row)*132 + 32*w + nt2*16 + m] = o4[rt][nt2][r]*inv;
            }
    }
    __syncthreads();

    // ---- final: x3o = ov @ w3_others (f32); out = relu(x3s+x3o).Wout + bout
    {
        float acc[2][4] = {};
#pragma unroll 4
        for (int k = 0; k < 128; ++k) {
            float4 w4 = *(const float4*)(w3_others + k*64 + c0);
            float a0 = sOv[(rg*2+0)*132 + k];
            float a1 = sOv[(rg*2+1)*132 + k];
            acc[0][0] += a0*w4.x; acc[0][1] += a0*w4.y; acc[0][2] += a0*w4.z; acc[0][3] += a0*w4.w;
            acc[1][0] += a1*w4.x; acc[1][1] += a1*w4.y; acc[1][2] += a1*w4.z; acc[1][3] += a1*w4.w;
        }
        float4 wo = *(const float4*)(Wout + c0);
        float bo = bout[0];
#pragma unroll
        for (int i = 0; i < 2; ++i) {
            float p = fmaxf(acc[i][0] + x3s[i][0], 0.f) * wo.x
                    + fmaxf(acc[i][1] + x3s[i][1], 0.f) * wo.y
                    + fmaxf(acc[i][2] + x3s[i][2], 0.f) * wo.z
                    + fmaxf(acc[i][3] + x3s[i][3], 0.f) * wo.w;
#pragma unroll
            for (int off = 1; off < 16; off <<= 1)
                p += __shfl_xor(p, off);
            if (cg == 0) out[b0 + rg*2 + i] = p + bo;
        }
    }
}

extern "C" void kernel_launch(void* const* d_in, const int* in_sizes, int n_in,
                              void* d_out, int out_size, void* d_ws, size_t ws_size,
                              hipStream_t stream) {
    (void)in_sizes; (void)n_in; (void)out_size; (void)ws_size;
    const float* state_one    = (const float*)d_in[0];
    const float* act_one      = (const float*)d_in[1];
    const float* state_others = (const float*)d_in[2];
    const float* act_others   = (const float*)d_in[3];
    const float* W1           = (const float*)d_in[4];
    const float* b1           = (const float*)d_in[5];
    const float* W2           = (const float*)d_in[6];
    const float* b2           = (const float*)d_in[7];
    const float* w3_self      = (const float*)d_in[8];
    const float* We           = (const float*)d_in[9];
    const float* be           = (const float*)d_in[10];
    const float* Wk           = (const float*)d_in[11];
    const float* Wq           = (const float*)d_in[12];
    const float* Wv           = (const float*)d_in[13];
    const float* bv           = (const float*)d_in[14];
    const float* w3_others    = (const float*)d_in[15];
    const float* Wout         = (const float*)d_in[16];
    const float* bout         = (const float*)d_in[17];
    float* out = (float*)d_out;

    unsigned short* Mf2  = (unsigned short*)d_ws;                    // 131072 B
    unsigned short* Wef2 = (unsigned short*)((char*)d_ws + 131072);  // 344064 B
    unsigned short* Wvf2 = (unsigned short*)((char*)d_ws + 475136);  // 65536 B

    fold_M_frag<<<128, 256, 0, stream>>>(Wk, Wq, Mf2);
    conv_We<<<336, 256, 0, stream>>>(We, Wef2);
    conv_Wv<<<64, 256, 0, stream>>>(Wv, Wvf2);
    fused_critic<<<BTOT/TB, 512, 0, stream>>>(
        state_one, act_one, state_others, act_others,
        W1, b1, W2, b2, w3_self, be, bv, w3_others, Wout, bout,
        Mf2, Wef2, Wvf2, out);
}

// Round 4
// 263.857 us; speedup vs baseline: 1.5034x; 1.5034x over previous
//
#include <hip/hip_runtime.h>
#include <hip/hip_bf16.h>

#define BTOT 32768
#define TB 32

typedef __attribute__((ext_vector_type(8))) short bhalf8;   // 8 bf16 = 4 VGPRs
typedef __attribute__((ext_vector_type(4))) float f32x4;    // MFMA acc

// R12: native cast (single v_cvt) instead of 5-op integer RNE; same
// round-to-nearest-even semantics, finite inputs only.
static __device__ __forceinline__ unsigned short f2bf(float x) {
    __hip_bfloat16 h = __float2bfloat16(x);
    unsigned short u;
    __builtin_memcpy(&u, &h, sizeof(u));
    return u;
}
static __device__ __forceinline__ float bf2f(unsigned short s) {
    return __uint_as_float(((unsigned int)s) << 16);
}
static __device__ __forceinline__ float bflo(unsigned int u) {
    return __uint_as_float(u << 16);
}
static __device__ __forceinline__ float bfhi(unsigned int u) {
    return __uint_as_float(u & 0xffff0000u);
}

// ---------------------------------------------------------------------------
// Weight preprocessing into MFMA B-fragment-linear SPLIT bf16 (hi|lo).
// B-frag for (kt, nt): lane l holds B[k=kt*32+(l>>4)*8+j][n=nt*16+(l&15)],
// hi at idx = ((nt*KT+kt)*64 + l)*16 + j, lo at +8+j.
// ws: Mf2  @0       131072 B (M = Wq@Wk^T as [64 x 512], KT=2, NT=32)
//     Wef2 @131072  344064 B (per agent We[96 x 128], KT=3, NT=8)
//     Wvf2 @475136  65536 B  (Wv as [128 x 128], n=h*32+d, KT=4, NT=8)
// Quarantine note: rounds 5/6's fused preprocess + 2-pass t-phase correlated
// with nondeterminism; kept as three kernels + single-pass t-phase.
// R9/R11 lesson (twice): launch_bounds second-arg that implies VGPR<120
// collapses the allocator to 64 VGPR -> ~500MB scratch spill traffic.
// Never request more than 2 waves/EU for fused_critic.
// R10 lesson: barrier count 21->14 + staging-latency hiding moved ~1.5% ->
// stall is per-phase dependent latency at 8 waves/CU, and the VGPR file
// pins 8 waves/CU. Occupancy axis is dead; attack in-wave ILP instead.
// ---------------------------------------------------------------------------
__global__ __launch_bounds__(256) void fold_M_frag(
        const float* __restrict__ Wk, const float* __restrict__ Wq,
        unsigned short* __restrict__ Mf2)
{
    int tid = blockIdx.x * 256 + threadIdx.x;   // 32768
    int h  = tid >> 13;
    int jq = (tid >> 7) & 63;
    int j  = tid & 127;
    const float* q = Wq + (h*64 + jq)*32;
    const float* k = Wk + (h*128 + j)*32;
    float acc = 0.f;
#pragma unroll
    for (int d = 0; d < 32; d += 4) {
        float4 a = *(const float4*)(q + d);
        float4 b = *(const float4*)(k + d);
        acc += a.x*b.x + a.y*b.y + a.z*b.z + a.w*b.w;
    }
    unsigned short hi = f2bf(acc);
    unsigned short lo = f2bf(acc - bf2f(hi));
    int n  = h*128 + j;
    int kt = jq >> 5, qd = (jq >> 3) & 3, jj = jq & 7;
    int nt = n >> 4,  ln = n & 15;
    size_t base = (((nt*2 + kt)*64) + qd*16 + ln)*16;
    Mf2[base + jj]     = hi;
    Mf2[base + 8 + jj] = lo;
}

__global__ __launch_bounds__(256) void conv_We(
        const float* __restrict__ We, unsigned short* __restrict__ Wef2)
{
    int tid = blockIdx.x * 256 + threadIdx.x;   // 7*96*128 = 86016
    int a = tid / 12288;
    int r = tid - a*12288;
    int k = r >> 7;          // 0..95
    int n = r & 127;
    float v = (k < 82) ? We[((size_t)a*82 + k)*128 + n] : 0.f;
    unsigned short hi = f2bf(v);
    unsigned short lo = f2bf(v - bf2f(hi));
    int kt = k >> 5, qd = (k >> 3) & 3, j = k & 7;
    int nt = n >> 4, ln = n & 15;
    size_t base = (size_t)a*24576 + (((nt*3 + kt)*64) + qd*16 + ln)*16;
    Wef2[base + j]     = hi;
    Wef2[base + 8 + j] = lo;
}

__global__ __launch_bounds__(256) void conv_Wv(
        const float* __restrict__ Wv, unsigned short* __restrict__ Wvf2)
{
    int tid = blockIdx.x * 256 + threadIdx.x;   // 4*128*32 = 16384
    int h = tid >> 12;
    int j = (tid >> 5) & 127;
    int d = tid & 31;
    float v = Wv[tid];
    unsigned short hi = f2bf(v);
    unsigned short lo = f2bf(v - bf2f(hi));
    int k = j, n = h*32 + d;
    int kt = k >> 5, qd = (k >> 3) & 3, jj = k & 7;
    int nt = n >> 4, ln = n & 15;
    size_t base = (((nt*4 + kt)*64) + qd*16 + ln)*16;
    Wvf2[base + jj]     = hi;
    Wvf2[base + 8 + jj] = lo;
}

// ---------------------------------------------------------------------------
// Fused critic. TB=32 rows/block, 256 threads (4 waves), 1024 blocks.
// R12 = R10 with the agent loop DOUBLE-BUFFERED (sIn x2, sEn x2) so each
// agent costs ONE barrier, and vals(a) + enc(a+1) become independent work
// in the SAME barrier interval (MFMA streams + logits VALU + prefetch all
// co-scheduled). Interval audit (buffers alternate by a&1):
//   interval I_a = (B_{a-1} .. B_a) contains: logits(a-1)/vals(a-1) reading
//   sEn[(a-1)&1]; enc(a) reading sIn[a&1]; writes sEn[a&1]; stageIn(a+1)
//   writing sIn[(a+1)&1]. All same-interval pairs touch DISJOINT buffers;
//   every producer->consumer crosses exactly one __syncthreads.
// Conversions use native __float2bfloat16 (R12) — ~2.5K VALU cyc/wave less.
// LDS 61440 B:
//   self : sX f32[32x84]@0, sX1 f32[32x68]@10752, sX2 f32[32x68]@19456,
//          sX1bH bf16[32x72]@28160, sX1bL @32768 (ends 37376)
//   t    : sT bf16[32x520]@0 (freed after tq reg load)
//   agent: sIn buf k: H@k*13312, L@k*13312+6656 (k=0,1; ends 26624)
//          sEn buf k: H@26624+k*17408, L@+8704 (ends 61440)
//   final: sOv f32[32x132]@0 (no overlap with sEn)
// ---------------------------------------------------------------------------
__global__ __launch_bounds__(256, 2) void fused_critic(
    const float* __restrict__ state_one, const float* __restrict__ act_one,
    const float* __restrict__ state_others, const float* __restrict__ act_others,
    const float* __restrict__ W1, const float* __restrict__ b1,
    const float* __restrict__ W2, const float* __restrict__ b2,
    const float* __restrict__ w3_self, const float* __restrict__ be,
    const float* __restrict__ bvp, const float* __restrict__ w3_others,
    const float* __restrict__ Wout, const float* __restrict__ bout,
    const unsigned short* __restrict__ Mf2, const unsigned short* __restrict__ Wef2,
    const unsigned short* __restrict__ Wvf2, float* __restrict__ out)
{
    __shared__ __align__(16) unsigned char smem[61440];
    float*          sX    = (float*)smem;                    // stride 84
    float*          sX1   = (float*)(smem + 10752);          // stride 68
    float*          sX2   = (float*)(smem + 19456);          // stride 68
    unsigned short* sX1bH = (unsigned short*)(smem + 28160); // stride 72
    unsigned short* sX1bL = (unsigned short*)(smem + 32768); // stride 72
    unsigned short* sT    = (unsigned short*)smem;           // stride 520
    float*          sOv   = (float*)smem;                    // stride 132

    const int t  = threadIdx.x;
    const int b0 = blockIdx.x * TB;
    const int w  = t >> 6;        // wave = head
    const int l  = t & 63;
    const int m  = l & 15;        // MFMA A row / C col
    const int qd = l >> 4;        // quad

    const int act_r = t >> 3, act_c = t & 7;

    // staging helper: split-bf16 convert regs -> given sIn buffer (cols 0..81)
    auto stageIn = [&](unsigned short* dH, unsigned short* dL,
                       const float4& vA, const float4& vB, const float* av) {
        const int r0 = t >> 4, c4 = (t & 15) << 2;
        ushort4 h4, l4;
        h4.x = f2bf(vA.x); l4.x = f2bf(vA.x - bf2f(h4.x));
        h4.y = f2bf(vA.y); l4.y = f2bf(vA.y - bf2f(h4.y));
        h4.z = f2bf(vA.z); l4.z = f2bf(vA.z - bf2f(h4.z));
        h4.w = f2bf(vA.w); l4.w = f2bf(vA.w - bf2f(h4.w));
        *(ushort4*)(dH + r0*104 + c4) = h4;
        *(ushort4*)(dL + r0*104 + c4) = l4;
        h4.x = f2bf(vB.x); l4.x = f2bf(vB.x - bf2f(h4.x));
        h4.y = f2bf(vB.y); l4.y = f2bf(vB.y - bf2f(h4.y));
        h4.z = f2bf(vB.z); l4.z = f2bf(vB.z - bf2f(h4.z));
        h4.w = f2bf(vB.w); l4.w = f2bf(vB.w - bf2f(h4.w));
        *(ushort4*)(dH + (r0+16)*104 + c4) = h4;
        *(ushort4*)(dL + (r0+16)*104 + c4) = l4;
        if (act_c < 6) {
#pragma unroll
            for (int e = 0; e < 3; ++e) {
                float v = av[e];
                unsigned short hh = f2bf(v);
                dH[act_r*104 + 64 + act_c*3 + e] = hh;
                dL[act_r*104 + 64 + act_c*3 + e] = f2bf(v - bf2f(hh));
            }
        }
    };

    // ---- stage self input [32 x 78] f32 ----
    for (int f = t; f < TB*16; f += 256) {
        int r = f >> 4, c4 = (f & 15) << 2;
        *(float4*)(sX + r*84 + c4) =
            *(const float4*)(state_one + (size_t)(b0 + r)*64 + c4);
    }
    for (int f = t; f < TB*14; f += 256) {
        int r = f / 14, c = f - r*14;
        sX[r*84 + 64 + c] = act_one[(size_t)(b0 + r)*14 + c];
    }
    __syncthreads();

    const int cg = t & 15, rg = t >> 4;   // self/final map: 2 rows x 4 cols
    const int c0 = cg << 2;

    // ---- phase 1: x1 = relu(x @ W1 + b1) -> sX1 f32 + split bf16 ----
    {
        float acc[2][4] = {};
#pragma unroll 2
        for (int k = 0; k < 78; ++k) {
            float4 wv = *(const float4*)(W1 + k*64 + c0);
            float a0 = sX[(rg*2+0)*84 + k];
            float a1 = sX[(rg*2+1)*84 + k];
            acc[0][0] += a0*wv.x; acc[0][1] += a0*wv.y; acc[0][2] += a0*wv.z; acc[0][3] += a0*wv.w;
            acc[1][0] += a1*wv.x; acc[1][1] += a1*wv.y; acc[1][2] += a1*wv.z; acc[1][3] += a1*wv.w;
        }
        float4 bb = *(const float4*)(b1 + c0);
#pragma unroll
        for (int i = 0; i < 2; ++i) {
            int r = rg*2 + i;
            float v[4];
            v[0] = fmaxf(acc[i][0] + bb.x, 0.f);
            v[1] = fmaxf(acc[i][1] + bb.y, 0.f);
            v[2] = fmaxf(acc[i][2] + bb.z, 0.f);
            v[3] = fmaxf(acc[i][3] + bb.w, 0.f);
#pragma unroll
            for (int e = 0; e < 4; ++e) {
                sX1[r*68 + c0+e] = v[e];
                unsigned short hh = f2bf(v[e]);
                sX1bH[r*72 + c0+e] = hh;
                sX1bL[r*72 + c0+e] = f2bf(v[e] - bf2f(hh));
            }
        }
    }
    __syncthreads();

    // ---- phase 2: x2 = relu(x1 @ W2 + b2) -> sX2 f32 ----
    {
        float acc[2][4] = {};
#pragma unroll 4
        for (int k = 0; k < 64; ++k) {
            float4 wv = *(const float4*)(W2 + k*64 + c0);
            float a0 = sX1[(rg*2+0)*68 + k];
            float a1 = sX1[(rg*2+1)*68 + k];
            acc[0][0] += a0*wv.x; acc[0][1] += a0*wv.y; acc[0][2] += a0*wv.z; acc[0][3] += a0*wv.w;
            acc[1][0] += a1*wv.x; acc[1][1] += a1*wv.y; acc[1][2] += a1*wv.z; acc[1][3] += a1*wv.w;
        }
        float4 bb = *(const float4*)(b2 + c0);
#pragma unroll
        for (int i = 0; i < 2; ++i) {
            int r = rg*2 + i;
            sX2[r*68 + c0+0] = fmaxf(acc[i][0] + bb.x, 0.f);
            sX2[r*68 + c0+1] = fmaxf(acc[i][1] + bb.y, 0.f);
            sX2[r*68 + c0+2] = fmaxf(acc[i][2] + bb.z, 0.f);
            sX2[r*68 + c0+3] = fmaxf(acc[i][3] + bb.w, 0.f);
        }
    }
    __syncthreads();

    // ---- phase 3: x3_self fragment in registers (final-phase map) ----
    float x3s[2][4] = {};
    {
#pragma unroll 4
        for (int k = 0; k < 64; ++k) {
            float4 wv = *(const float4*)(w3_self + k*64 + c0);
            float a0 = sX2[(rg*2+0)*68 + k];
            float a1 = sX2[(rg*2+1)*68 + k];
            x3s[0][0] += a0*wv.x; x3s[0][1] += a0*wv.y; x3s[0][2] += a0*wv.z; x3s[0][3] += a0*wv.w;
            x3s[1][0] += a1*wv.x; x3s[1][1] += a1*wv.y; x3s[1][2] += a1*wv.z; x3s[1][3] += a1*wv.w;
        }
    }

    // ---- phase 4: t = x1 @ M, split 3-term MFMA (~f32), -> sT bf16 ----
    {
        f32x4 tacc[2][8] = {};
#pragma unroll
        for (int kt = 0; kt < 2; ++kt) {
            bhalf8 ah0 = *(const bhalf8*)(sX1bH + m*72      + kt*32 + qd*8);
            bhalf8 ah1 = *(const bhalf8*)(sX1bH + (16+m)*72 + kt*32 + qd*8);
            bhalf8 al0 = *(const bhalf8*)(sX1bL + m*72      + kt*32 + qd*8);
            bhalf8 al1 = *(const bhalf8*)(sX1bL + (16+m)*72 + kt*32 + qd*8);
#pragma unroll
            for (int nt2 = 0; nt2 < 8; ++nt2) {
                int nt = w*8 + nt2;
                const unsigned short* bp = Mf2 + ((nt*2 + kt)*64 + l)*16;
                bhalf8 bh = *(const bhalf8*)(bp);
                bhalf8 bl = *(const bhalf8*)(bp + 8);
                tacc[0][nt2] = __builtin_amdgcn_mfma_f32_16x16x32_bf16(ah0, bh, tacc[0][nt2], 0, 0, 0);
                tacc[1][nt2] = __builtin_amdgcn_mfma_f32_16x16x32_bf16(ah1, bh, tacc[1][nt2], 0, 0, 0);
                tacc[0][nt2] = __builtin_amdgcn_mfma_f32_16x16x32_bf16(ah0, bl, tacc[0][nt2], 0, 0, 0);
                tacc[1][nt2] = __builtin_amdgcn_mfma_f32_16x16x32_bf16(ah1, bl, tacc[1][nt2], 0, 0, 0);
                tacc[0][nt2] = __builtin_amdgcn_mfma_f32_16x16x32_bf16(al0, bh, tacc[0][nt2], 0, 0, 0);
                tacc[1][nt2] = __builtin_amdgcn_mfma_f32_16x16x32_bf16(al1, bh, tacc[1][nt2], 0, 0, 0);
            }
        }
        __syncthreads();   // all reads of sX1b*/sX2 done before sT overwrite
#pragma unroll
        for (int rt = 0; rt < 2; ++rt)
#pragma unroll
            for (int nt2 = 0; nt2 < 8; ++nt2)
#pragma unroll
                for (int r = 0; r < 4; ++r)
                    sT[(rt*16 + qd*4 + r)*520 + w*128 + nt2*16 + m] =
                        f2bf(tacc[rt][nt2][r]);
    }
    __syncthreads();

    // ---- load this thread's t-slice into registers ----
    const int b_l = l & 31, half = l >> 5;
    uint4 tq[8];
    {
        const uint4* tp4 = (const uint4*)(sT + b_l*520 + w*128 + half*64);
#pragma unroll
        for (int i = 0; i < 8; ++i) tq[i] = tp4[i];
    }
    __syncthreads();   // sT region free for sIn buffers

    // zero-pad cols 82..95 of BOTH sIn buffers once
    // (cols 80,81 are act cols, staged every agent by stageIn)
    for (int f = t; f < TB*16; f += 256) {
        int r = f >> 4, c = f & 15;
        if (c >= 2) {
#pragma unroll
            for (int k = 0; k < 2; ++k) {
                unsigned short* dH = (unsigned short*)(smem + k*13312);
                unsigned short* dL = (unsigned short*)(smem + k*13312 + 6656);
                dH[r*104 + 80 + c] = 0;
                dL[r*104 + 80 + c] = 0;
            }
        }
    }
    // stage agent 0 directly into buffer 0
    {
        const float* sa = state_others + (size_t)b0 * 64;
        float4 vA = *(const float4*)(sa + t*4);
        float4 vB = *(const float4*)(sa + t*4 + 1024);
        float av[3] = {0.f, 0.f, 0.f};
        if (act_c < 6) {
            const float* aa = act_others + (size_t)(b0 + act_r)*18 + act_c*3;
            av[0] = aa[0]; av[1] = aa[1]; av[2] = aa[2];
        }
        stageIn((unsigned short*)smem, (unsigned short*)(smem + 6656),
                vA, vB, av);
    }
    __syncthreads();   // sIn buf0 (agent 0) ready

    const float bv0 = bvp[w*32 + m];
    const float bv1 = bvp[w*32 + 16 + m];
    f32x4 o4[2][2] = {};
    // online-softmax state for row b_l of head w, replicated in both halves
    float mR = -1e30f, sR = 0.f;

    float4 pfA, pfB; float pfa[3] = {0.f, 0.f, 0.f};

    for (int a = 0; a < 7; ++a) {
        // per-iteration buffer bases (byte offsets; no runtime-indexed arrays)
        unsigned short* sInHc = (unsigned short*)(smem + (a&1)*13312);
        unsigned short* sInLc = (unsigned short*)(smem + (a&1)*13312 + 6656);
        unsigned short* sEnHc = (unsigned short*)(smem + 26624 + (a&1)*17408);
        unsigned short* sEnLc = (unsigned short*)(smem + 26624 + (a&1)*17408 + 8704);
        unsigned short* sInHn = (unsigned short*)(smem + ((a+1)&1)*13312);
        unsigned short* sInLn = (unsigned short*)(smem + ((a+1)&1)*13312 + 6656);

        // ---- issue next agent's HBM loads (regs); hides under enc/vals ----
        if (a < 6) {
            const float* sa = state_others + ((size_t)(a+1)*BTOT + b0)*64;
            pfA = *(const float4*)(sa + t*4);
            pfB = *(const float4*)(sa + t*4 + 1024);
            if (act_c < 6) {
                const float* aa = act_others
                    + ((size_t)(a+1)*BTOT + b0 + act_r)*18 + act_c*3;
                pfa[0] = aa[0]; pfa[1] = aa[1]; pfa[2] = aa[2];
            }
        }
        float be0 = be[a*128 + 32*w + m];
        float be1 = be[a*128 + 32*w + 16 + m];

        // ---- enc(a) = inp @ We_a, split 3-term, wave slice 32 cols ----
        f32x4 eacc[2][2] = {};
#pragma unroll
        for (int kt = 0; kt < 3; ++kt) {
            bhalf8 ah0 = *(const bhalf8*)(sInHc + m*104      + kt*32 + qd*8);
            bhalf8 ah1 = *(const bhalf8*)(sInHc + (16+m)*104 + kt*32 + qd*8);
            bhalf8 al0 = *(const bhalf8*)(sInLc + m*104      + kt*32 + qd*8);
            bhalf8 al1 = *(const bhalf8*)(sInLc + (16+m)*104 + kt*32 + qd*8);
#pragma unroll
            for (int nt2 = 0; nt2 < 2; ++nt2) {
                int nt = 2*w + nt2;
                const unsigned short* bp =
                    Wef2 + (size_t)a*24576 + ((nt*3 + kt)*64 + l)*16;
                bhalf8 bh = *(const bhalf8*)(bp);
                bhalf8 bl = *(const bhalf8*)(bp + 8);
                eacc[0][nt2] = __builtin_amdgcn_mfma_f32_16x16x32_bf16(ah0, bh, eacc[0][nt2], 0, 0, 0);
                eacc[1][nt2] = __builtin_amdgcn_mfma_f32_16x16x32_bf16(ah1, bh, eacc[1][nt2], 0, 0, 0);
                eacc[0][nt2] = __builtin_amdgcn_mfma_f32_16x16x32_bf16(ah0, bl, eacc[0][nt2], 0, 0, 0);
                eacc[1][nt2] = __builtin_amdgcn_mfma_f32_16x16x32_bf16(ah1, bl, eacc[1][nt2], 0, 0, 0);
                eacc[0][nt2] = __builtin_amdgcn_mfma_f32_16x16x32_bf16(al0, bh, eacc[0][nt2], 0, 0, 0);
                eacc[1][nt2] = __builtin_amdgcn_mfma_f32_16x16x32_bf16(al1, bh, eacc[1][nt2], 0, 0, 0);
            }
        }

        // ---- write sEn(a) (relu+bias, split) into current sEn buffer ----
        {
#pragma unroll
            for (int rt = 0; rt < 2; ++rt)
#pragma unroll
                for (int nt2 = 0; nt2 < 2; ++nt2) {
                    float bb = nt2 ? be1 : be0;
#pragma unroll
                    for (int r = 0; r < 4; ++r) {
                        float e = fmaxf(eacc[rt][nt2][r] + bb, 0.f);
                        int row = rt*16 + qd*4 + r;
                        int col = 32*w + nt2*16 + m;
                        unsigned short hh = f2bf(e);
                        sEnHc[row*136 + col] = hh;
                        sEnLc[row*136 + col] = f2bf(e - bf2f(hh));
                    }
                }
        }
        // ---- stage sIn(a+1) into the other buffer (same interval, disjoint)
        if (a < 6) stageIn(sInHn, sInLn, pfA, pfB, pfa);

        // ---- THE barrier: sEn(a) and sIn(a+1) visible to all waves ----
        __syncthreads();

        // ---- logits(a) ((hi+lo) f32 enc x bf16 t); stats in registers ----
        float alpha, pp;
        {
            const uint4* ehp = (const uint4*)(sEnHc + b_l*136 + half*64);
            const uint4* elp = (const uint4*)(sEnLc + b_l*136 + half*64);
            float part = 0.f;
#pragma unroll
            for (int i = 0; i < 8; ++i) {
                uint4 eh = ehp[i];
                uint4 el = elp[i];
                uint4 tt = tq[i];
                part += (bflo(eh.x)+bflo(el.x))*bflo(tt.x)
                      + (bfhi(eh.x)+bfhi(el.x))*bfhi(tt.x);
                part += (bflo(eh.y)+bflo(el.y))*bflo(tt.y)
                      + (bfhi(eh.y)+bfhi(el.y))*bfhi(tt.y);
                part += (bflo(eh.z)+bflo(el.z))*bflo(tt.z)
                      + (bfhi(eh.z)+bfhi(el.z))*bfhi(tt.z);
                part += (bflo(eh.w)+bflo(el.w))*bflo(tt.w)
                      + (bfhi(eh.w)+bfhi(el.w))*bfhi(tt.w);
            }
            part += __shfl_xor(part, 32);   // both halves now bit-identical
            float lg = part * 0.17677669529663687f;   // 1/sqrt(32)
            float mn = fmaxf(mR, lg);
            alpha = __expf(mR - mn);
            pp    = __expf(lg - mn);
            sR = sR*alpha + pp;
            mR = mn;
        }

        // ---- vals(a) = relu(enc @ Wv + bv); online accumulate ----
        // (next iteration's enc(a+1) is independent of this — same-interval
        //  co-scheduling is the point of the double buffer)
        {
            f32x4 vacc[2][2] = {};
#pragma unroll
            for (int kt = 0; kt < 4; ++kt) {
                bhalf8 ah0 = *(const bhalf8*)(sEnHc + m*136      + kt*32 + qd*8);
                bhalf8 ah1 = *(const bhalf8*)(sEnHc + (16+m)*136 + kt*32 + qd*8);
                bhalf8 al0 = *(const bhalf8*)(sEnLc + m*136      + kt*32 + qd*8);
                bhalf8 al1 = *(const bhalf8*)(sEnLc + (16+m)*136 + kt*32 + qd*8);
#pragma unroll
                for (int nt2 = 0; nt2 < 2; ++nt2) {
                    int nt = 2*w + nt2;
                    const unsigned short* bp = Wvf2 + ((nt*4 + kt)*64 + l)*16;
                    bhalf8 bh = *(const bhalf8*)(bp);
                    bhalf8 bl = *(const bhalf8*)(bp + 8);
                    vacc[0][nt2] = __builtin_amdgcn_mfma_f32_16x16x32_bf16(ah0, bh, vacc[0][nt2], 0, 0, 0);
                    vacc[1][nt2] = __builtin_amdgcn_mfma_f32_16x16x32_bf16(ah1, bh, vacc[1][nt2], 0, 0, 0);
                    vacc[0][nt2] = __builtin_amdgcn_mfma_f32_16x16x32_bf16(ah0, bl, vacc[0][nt2], 0, 0, 0);
                    vacc[1][nt2] = __builtin_amdgcn_mfma_f32_16x16x32_bf16(ah1, bl, vacc[1][nt2], 0, 0, 0);
                    vacc[0][nt2] = __builtin_amdgcn_mfma_f32_16x16x32_bf16(al0, bh, vacc[0][nt2], 0, 0, 0);
                    vacc[1][nt2] = __builtin_amdgcn_mfma_f32_16x16x32_bf16(al1, bh, vacc[1][nt2], 0, 0, 0);
                }
            }
#pragma unroll
            for (int rt = 0; rt < 2; ++rt)
#pragma unroll
                for (int r = 0; r < 4; ++r) {
                    int row = rt*16 + qd*4 + r;
                    float al = __shfl(alpha, row);
                    float p  = __shfl(pp, row);
#pragma unroll
                    for (int nt2 = 0; nt2 < 2; ++nt2) {
                        float bb = nt2 ? bv1 : bv0;
                        o4[rt][nt2][r] = o4[rt][nt2][r]*al
                                       + p*fmaxf(vacc[rt][nt2][r] + bb, 0.f);
                    }
                }
        }
    }
    __syncthreads();   // all sEn/sIn reads done; sOv overwrites sIn region

    // ---- normalize (1/s via shfl) and dump ov to sOv f32 (stride 132) ----
    {
        float rinv = 1.0f / sR;
#pragma unroll
        for (int rt = 0; rt < 2; ++rt)
#pragma unroll
            for (int r = 0; r < 4; ++r) {
                int row = rt*16 + qd*4 + r;
                float inv = __shfl(rinv, row);
#pragma unroll
                for (int nt2 = 0; nt2 < 2; ++nt2)
                    sOv[row*132 + 32*w + nt2*16 + m] = o4[rt][nt2][r]*inv;
            }
    }
    __syncthreads();

    // ---- final: x3o = ov @ w3_others (f32); out = relu(x3s+x3o).Wout + bout
    {
        float acc[2][4] = {};
#pragma unroll 4
        for (int k = 0; k < 128; ++k) {
            float4 w4 = *(const float4*)(w3_others + k*64 + c0);
            float a0 = sOv[(rg*2+0)*132 + k];
            float a1 = sOv[(rg*2+1)*132 + k];
            acc[0][0] += a0*w4.x; acc[0][1] += a0*w4.y; acc[0][2] += a0*w4.z; acc[0][3] += a0*w4.w;
            acc[1][0] += a1*w4.x; acc[1][1] += a1*w4.y; acc[1][2] += a1*w4.z; acc[1][3] += a1*w4.w;
        }
        float4 wo = *(const float4*)(Wout + c0);
        float bo = bout[0];
#pragma unroll
        for (int i = 0; i < 2; ++i) {
            float p = fmaxf(acc[i][0] + x3s[i][0], 0.f) * wo.x
                    + fmaxf(acc[i][1] + x3s[i][1], 0.f) * wo.y
                    + fmaxf(acc[i][2] + x3s[i][2], 0.f) * wo.z
                    + fmaxf(acc[i][3] + x3s[i][3], 0.f) * wo.w;
#pragma unroll
            for (int off = 1; off < 16; off <<= 1)
                p += __shfl_xor(p, off);
            if (cg == 0) out[b0 + rg*2 + i] = p + bo;
        }
    }
}

extern "C" void kernel_launch(void* const* d_in, const int* in_sizes, int n_in,
                              void* d_out, int out_size, void* d_ws, size_t ws_size,
                              hipStream_t stream) {
    (void)in_sizes; (void)n_in; (void)out_size; (void)ws_size;
    const float* state_one    = (const float*)d_in[0];
    const float* act_one      = (const float*)d_in[1];
    const float* state_others = (const float*)d_in[2];
    const float* act_others   = (const float*)d_in[3];
    const float* W1           = (const float*)d_in[4];
    const float* b1           = (const float*)d_in[5];
    const float* W2           = (const float*)d_in[6];
    const float* b2           = (const float*)d_in[7];
    const float* w3_self      = (const float*)d_in[8];
    const float* We           = (const float*)d_in[9];
    const float* be           = (const float*)d_in[10];
    const float* Wk           = (const float*)d_in[11];
    const float* Wq           = (const float*)d_in[12];
    const float* Wv           = (const float*)d_in[13];
    const float* bv           = (const float*)d_in[14];
    const float* w3_others    = (const float*)d_in[15];
    const float* Wout         = (const float*)d_in[16];
    const float* bout         = (const float*)d_in[17];
    float* out = (float*)d_out;

    unsigned short* Mf2  = (unsigned short*)d_ws;                    // 131072 B
    unsigned short* Wef2 = (unsigned short*)((char*)d_ws + 131072);  // 344064 B
    unsigned short* Wvf2 = (unsigned short*)((char*)d_ws + 475136);  // 65536 B

    fold_M_frag<<<128, 256, 0, stream>>>(Wk, Wq, Mf2);
    conv_We<<<336, 256, 0, stream>>>(We, Wef2);
    conv_Wv<<<64, 256, 0, stream>>>(Wv, Wvf2);
    fused_critic<<<BTOT/TB, 256, 0, stream>>>(
        state_one, act_one, state_others, act_others,
        W1, b1, W2, b2, w3_self, be, bv, w3_others, Wout, bout,
        Mf2, Wef2, Wvf2, out);
}

// Round 5
// 233.756 us; speedup vs baseline: 1.6970x; 1.1288x over previous
//
#include <hip/hip_runtime.h>
#include <hip/hip_bf16.h>

#define BTOT 32768
#define TB 32

typedef __attribute__((ext_vector_type(8))) short bhalf8;   // 8 bf16 = 4 VGPRs
typedef __attribute__((ext_vector_type(4))) float f32x4;    // MFMA acc

// R12: native cast (single v_cvt) instead of 5-op integer RNE.
static __device__ __forceinline__ unsigned short f2bf(float x) {
    __hip_bfloat16 h = __float2bfloat16(x);
    unsigned short u;
    __builtin_memcpy(&u, &h, sizeof(u));
    return u;
}
static __device__ __forceinline__ float bf2f(unsigned short s) {
    return __uint_as_float(((unsigned int)s) << 16);
}
static __device__ __forceinline__ float bflo(unsigned int u) {
    return __uint_as_float(u << 16);
}
static __device__ __forceinline__ float bfhi(unsigned int u) {
    return __uint_as_float(u & 0xffff0000u);
}

// ---------------------------------------------------------------------------
// Weight preprocessing into MFMA B-fragment-linear SPLIT bf16 (hi|lo).
// B-frag for (kt, nt): lane l holds B[k=kt*32+(l>>4)*8+j][n=nt*16+(l&15)],
// hi at idx = ((nt*KT+kt)*64 + l)*16 + j, lo at +8+j.
// ws: Mf2  @0       131072 B (M = Wq@Wk^T as [64 x 512], KT=2, NT=32)
//     Wef2 @131072  344064 B (per agent We[96 x 128], KT=3, NT=8)
//     Wvf2 @475136  65536 B  (Wv as [128 x 128], n=h*32+d, KT=4, NT=8)
//     W2f  @540672  16384 B  (W2 [64 x 64], KT=2, NT=4)          [R13]
//     w3sf @557056  16384 B  (w3_self [64 x 64], KT=2, NT=4)     [R13]
//     w3of @573440  32768 B  (w3_others [128 x 64], KT=4, NT=4)  [R13]
// Quarantine note: rounds 5/6's fused preprocess + 2-pass t-phase correlated
// with nondeterminism; kept as separate prep kernels + single-pass t-phase.
// R9/R11 lesson (twice): launch_bounds second-arg implying VGPR<120 collapses
// the allocator to 64 VGPR -> ~500MB scratch spills. Never request >2
// waves/EU for fused_critic. Occupancy axis is dead (VGPR-pinned 8 waves/CU).
// R10 lesson: barrier count / staging latency were not the stall.
// R12 lesson: one-barrier-per-agent + co-scheduled enc/vals = -7%.
// R13: VALU audit showed f32 scalar GEMMs = 10.7K of 13K VALU-cyc/wave.
// Phases 2,3,final -> MFMA (split-bf16, same 3-term scheme as t/enc/vals).
// ---------------------------------------------------------------------------
__global__ __launch_bounds__(256) void fold_M_frag(
        const float* __restrict__ Wk, const float* __restrict__ Wq,
        unsigned short* __restrict__ Mf2)
{
    int tid = blockIdx.x * 256 + threadIdx.x;   // 32768
    int h  = tid >> 13;
    int jq = (tid >> 7) & 63;
    int j  = tid & 127;
    const float* q = Wq + (h*64 + jq)*32;
    const float* k = Wk + (h*128 + j)*32;
    float acc = 0.f;
#pragma unroll
    for (int d = 0; d < 32; d += 4) {
        float4 a = *(const float4*)(q + d);
        float4 b = *(const float4*)(k + d);
        acc += a.x*b.x + a.y*b.y + a.z*b.z + a.w*b.w;
    }
    unsigned short hi = f2bf(acc);
    unsigned short lo = f2bf(acc - bf2f(hi));
    int n  = h*128 + j;
    int kt = jq >> 5, qd = (jq >> 3) & 3, jj = jq & 7;
    int nt = n >> 4,  ln = n & 15;
    size_t base = (((nt*2 + kt)*64) + qd*16 + ln)*16;
    Mf2[base + jj]     = hi;
    Mf2[base + 8 + jj] = lo;
}

__global__ __launch_bounds__(256) void conv_We(
        const float* __restrict__ We, unsigned short* __restrict__ Wef2)
{
    int tid = blockIdx.x * 256 + threadIdx.x;   // 7*96*128 = 86016
    int a = tid / 12288;
    int r = tid - a*12288;
    int k = r >> 7;          // 0..95
    int n = r & 127;
    float v = (k < 82) ? We[((size_t)a*82 + k)*128 + n] : 0.f;
    unsigned short hi = f2bf(v);
    unsigned short lo = f2bf(v - bf2f(hi));
    int kt = k >> 5, qd = (k >> 3) & 3, j = k & 7;
    int nt = n >> 4, ln = n & 15;
    size_t base = (size_t)a*24576 + (((nt*3 + kt)*64) + qd*16 + ln)*16;
    Wef2[base + j]     = hi;
    Wef2[base + 8 + j] = lo;
}

__global__ __launch_bounds__(256) void conv_Wv(
        const float* __restrict__ Wv, unsigned short* __restrict__ Wvf2)
{
    int tid = blockIdx.x * 256 + threadIdx.x;   // 4*128*32 = 16384
    int h = tid >> 12;
    int j = (tid >> 5) & 127;
    int d = tid & 31;
    float v = Wv[tid];
    unsigned short hi = f2bf(v);
    unsigned short lo = f2bf(v - bf2f(hi));
    int k = j, n = h*32 + d;
    int kt = k >> 5, qd = (k >> 3) & 3, jj = k & 7;
    int nt = n >> 4, ln = n & 15;
    size_t base = (((nt*4 + kt)*64) + qd*16 + ln)*16;
    Wvf2[base + jj]     = hi;
    Wvf2[base + 8 + jj] = lo;
}

// R13: W2 [64x64] KT=2, w3_self [64x64] KT=2, w3_others [128x64] KT=4
__global__ __launch_bounds__(256) void conv_self(
        const float* __restrict__ W2, const float* __restrict__ w3_self,
        const float* __restrict__ w3_others,
        unsigned short* __restrict__ W2f, unsigned short* __restrict__ w3sf,
        unsigned short* __restrict__ w3of)
{
    int tid = blockIdx.x * 256 + threadIdx.x;   // 16384
    const float* src;
    unsigned short* dst;
    int idx, KT;
    if (tid < 4096)       { src = W2;        dst = W2f;  idx = tid;        KT = 2; }
    else if (tid < 8192)  { src = w3_self;   dst = w3sf; idx = tid - 4096; KT = 2; }
    else                  { src = w3_others; dst = w3of; idx = tid - 8192; KT = 4; }
    int k = idx >> 6;
    int n = idx & 63;
    float v = src[k*64 + n];
    unsigned short hi = f2bf(v);
    unsigned short lo = f2bf(v - bf2f(hi));
    int kt = k >> 5, qd = (k >> 3) & 3, j = k & 7;
    int nt = n >> 4, ln = n & 15;
    size_t base = (((nt*KT + kt)*64) + qd*16 + ln)*16;
    dst[base + j]     = hi;
    dst[base + 8 + j] = lo;
}

// ---------------------------------------------------------------------------
// Fused critic. TB=32 rows/block, 256 threads (4 waves), 1024 blocks.
// R13 = R12 agent loop unchanged; self/final phases MFMA-ized:
//   phase 1 (x@W1+b1): f32 VALU (exact; feeds split chain) -> sX1b split only
//   phase 2 (x1@W2+b2): MFMA 12/wave, A=sX1b, B=W2f -> sX2b split
//   phase 3 (x2@w3_self): MFMA 12/wave -> x3a accumulator REGISTERS
//   final   (ov@w3_others): ov -> split LDS; MFMA 24/wave accumulates INTO
//           x3a (x3_self + x3_others = free C-operand add); relu*Wout,
//           shfl_xor m-reduce, cross-wave LDS reduce (sRed).
// Wave n-tile map for self phases: wave w owns cols 16w..16w+15 (NT=4).
// LDS 61440 B:
//   self : sX f32[32x84]@0..10752, sX1bH[32x72]@10752, sX1bL@15360,
//          sX2bH@19968, sX2bL@24576 (ends 29184)
//   t    : sT bf16[32x520]@0..33280 (overlays self; written only after the
//          internal barrier that ends all sX1b/sX2b reads — R8 discipline)
//   agent: sIn buf k: H@k*13312, L@+6656 (ends 26624)
//          sEn buf k: H@26624+k*17408, L@+8704 (ends 61440)
//   final: sOvH bf16[32x136]@0, sOvL@8704, sRed f32[32x4]@17408 (ends 17920)
// Every LDS producer->consumer crosses exactly one __syncthreads.
// ---------------------------------------------------------------------------
__global__ __launch_bounds__(256, 2) void fused_critic(
    const float* __restrict__ state_one, const float* __restrict__ act_one,
    const float* __restrict__ state_others, const float* __restrict__ act_others,
    const float* __restrict__ W1, const float* __restrict__ b1,
    const float* __restrict__ b2, const float* __restrict__ be,
    const float* __restrict__ bvp, const float* __restrict__ Wout,
    const float* __restrict__ bout,
    const unsigned short* __restrict__ Mf2, const unsigned short* __restrict__ Wef2,
    const unsigned short* __restrict__ Wvf2, const unsigned short* __restrict__ W2f,
    const unsigned short* __restrict__ w3sf, const unsigned short* __restrict__ w3of,
    float* __restrict__ out)
{
    __shared__ __align__(16) unsigned char smem[61440];
    float*          sX    = (float*)smem;                    // stride 84
    unsigned short* sX1bH = (unsigned short*)(smem + 10752); // stride 72
    unsigned short* sX1bL = (unsigned short*)(smem + 15360); // stride 72
    unsigned short* sX2bH = (unsigned short*)(smem + 19968); // stride 72
    unsigned short* sX2bL = (unsigned short*)(smem + 24576); // stride 72
    unsigned short* sT    = (unsigned short*)smem;           // stride 520
    unsigned short* sOvH  = (unsigned short*)smem;           // stride 136
    unsigned short* sOvL  = (unsigned short*)(smem + 8704);  // stride 136
    float*          sRed  = (float*)(smem + 17408);          // [32][4]

    const int t  = threadIdx.x;
    const int b0 = blockIdx.x * TB;
    const int w  = t >> 6;        // wave = head / self-col-tile
    const int l  = t & 63;
    const int m  = l & 15;        // MFMA A row / C col
    const int qd = l >> 4;        // quad

    const int act_r = t >> 3, act_c = t & 7;

    // staging helper: split-bf16 convert regs -> given sIn buffer (cols 0..81)
    auto stageIn = [&](unsigned short* dH, unsigned short* dL,
                       const float4& vA, const float4& vB, const float* av) {
        const int r0 = t >> 4, c4 = (t & 15) << 2;
        ushort4 h4, l4;
        h4.x = f2bf(vA.x); l4.x = f2bf(vA.x - bf2f(h4.x));
        h4.y = f2bf(vA.y); l4.y = f2bf(vA.y - bf2f(h4.y));
        h4.z = f2bf(vA.z); l4.z = f2bf(vA.z - bf2f(h4.z));
        h4.w = f2bf(vA.w); l4.w = f2bf(vA.w - bf2f(h4.w));
        *(ushort4*)(dH + r0*104 + c4) = h4;
        *(ushort4*)(dL + r0*104 + c4) = l4;
        h4.x = f2bf(vB.x); l4.x = f2bf(vB.x - bf2f(h4.x));
        h4.y = f2bf(vB.y); l4.y = f2bf(vB.y - bf2f(h4.y));
        h4.z = f2bf(vB.z); l4.z = f2bf(vB.z - bf2f(h4.z));
        h4.w = f2bf(vB.w); l4.w = f2bf(vB.w - bf2f(h4.w));
        *(ushort4*)(dH + (r0+16)*104 + c4) = h4;
        *(ushort4*)(dL + (r0+16)*104 + c4) = l4;
        if (act_c < 6) {
#pragma unroll
            for (int e = 0; e < 3; ++e) {
                float v = av[e];
                unsigned short hh = f2bf(v);
                dH[act_r*104 + 64 + act_c*3 + e] = hh;
                dL[act_r*104 + 64 + act_c*3 + e] = f2bf(v - bf2f(hh));
            }
        }
    };

    // ---- stage self input [32 x 78] f32 ----
    for (int f = t; f < TB*16; f += 256) {
        int r = f >> 4, c4 = (f & 15) << 2;
        *(float4*)(sX + r*84 + c4) =
            *(const float4*)(state_one + (size_t)(b0 + r)*64 + c4);
    }
    for (int f = t; f < TB*14; f += 256) {
        int r = f / 14, c = f - r*14;
        sX[r*84 + 64 + c] = act_one[(size_t)(b0 + r)*14 + c];
    }
    __syncthreads();

    const int cg = t & 15, rg = t >> 4;   // phase-1 map: 2 rows x 4 cols
    const int c0 = cg << 2;

    // ---- phase 1: x1 = relu(x @ W1 + b1), f32 exact -> split bf16 LDS ----
    {
        float acc[2][4] = {};
#pragma unroll 2
        for (int k = 0; k < 78; ++k) {
            float4 wv = *(const float4*)(W1 + k*64 + c0);
            float a0 = sX[(rg*2+0)*84 + k];
            float a1 = sX[(rg*2+1)*84 + k];
            acc[0][0] += a0*wv.x; acc[0][1] += a0*wv.y; acc[0][2] += a0*wv.z; acc[0][3] += a0*wv.w;
            acc[1][0] += a1*wv.x; acc[1][1] += a1*wv.y; acc[1][2] += a1*wv.z; acc[1][3] += a1*wv.w;
        }
        float4 bb = *(const float4*)(b1 + c0);
#pragma unroll
        for (int i = 0; i < 2; ++i) {
            int r = rg*2 + i;
            float v[4];
            v[0] = fmaxf(acc[i][0] + bb.x, 0.f);
            v[1] = fmaxf(acc[i][1] + bb.y, 0.f);
            v[2] = fmaxf(acc[i][2] + bb.z, 0.f);
            v[3] = fmaxf(acc[i][3] + bb.w, 0.f);
#pragma unroll
            for (int e = 0; e < 4; ++e) {
                unsigned short hh = f2bf(v[e]);
                sX1bH[r*72 + c0+e] = hh;
                sX1bL[r*72 + c0+e] = f2bf(v[e] - bf2f(hh));
            }
        }
    }
    __syncthreads();

    // ---- phase 2 (MFMA): x2 = relu(x1 @ W2 + b2) -> split bf16 LDS ----
    {
        f32x4 acc2[2] = {};
#pragma unroll
        for (int kt = 0; kt < 2; ++kt) {
            bhalf8 ah0 = *(const bhalf8*)(sX1bH + m*72      + kt*32 + qd*8);
            bhalf8 ah1 = *(const bhalf8*)(sX1bH + (16+m)*72 + kt*32 + qd*8);
            bhalf8 al0 = *(const bhalf8*)(sX1bL + m*72      + kt*32 + qd*8);
            bhalf8 al1 = *(const bhalf8*)(sX1bL + (16+m)*72 + kt*32 + qd*8);
            const unsigned short* bp = W2f + ((w*2 + kt)*64 + l)*16;
            bhalf8 bh = *(const bhalf8*)(bp);
            bhalf8 bl = *(const bhalf8*)(bp + 8);
            acc2[0] = __builtin_amdgcn_mfma_f32_16x16x32_bf16(ah0, bh, acc2[0], 0, 0, 0);
            acc2[1] = __builtin_amdgcn_mfma_f32_16x16x32_bf16(ah1, bh, acc2[1], 0, 0, 0);
            acc2[0] = __builtin_amdgcn_mfma_f32_16x16x32_bf16(ah0, bl, acc2[0], 0, 0, 0);
            acc2[1] = __builtin_amdgcn_mfma_f32_16x16x32_bf16(ah1, bl, acc2[1], 0, 0, 0);
            acc2[0] = __builtin_amdgcn_mfma_f32_16x16x32_bf16(al0, bh, acc2[0], 0, 0, 0);
            acc2[1] = __builtin_amdgcn_mfma_f32_16x16x32_bf16(al1, bh, acc2[1], 0, 0, 0);
        }
        int col = w*16 + m;
        float b2c = b2[col];
#pragma unroll
        for (int rt = 0; rt < 2; ++rt)
#pragma unroll
            for (int r = 0; r < 4; ++r) {
                float e = fmaxf(acc2[rt][r] + b2c, 0.f);
                int row = rt*16 + qd*4 + r;
                unsigned short hh = f2bf(e);
                sX2bH[row*72 + col] = hh;
                sX2bL[row*72 + col] = f2bf(e - bf2f(hh));
            }
    }
    __syncthreads();

    // ---- phase 3 (MFMA): x3a = x2 @ w3_self, kept in registers ----
    f32x4 x3a[2] = {};
    {
#pragma unroll
        for (int kt = 0; kt < 2; ++kt) {
            bhalf8 ah0 = *(const bhalf8*)(sX2bH + m*72      + kt*32 + qd*8);
            bhalf8 ah1 = *(const bhalf8*)(sX2bH + (16+m)*72 + kt*32 + qd*8);
            bhalf8 al0 = *(const bhalf8*)(sX2bL + m*72      + kt*32 + qd*8);
            bhalf8 al1 = *(const bhalf8*)(sX2bL + (16+m)*72 + kt*32 + qd*8);
            const unsigned short* bp = w3sf + ((w*2 + kt)*64 + l)*16;
            bhalf8 bh = *(const bhalf8*)(bp);
            bhalf8 bl = *(const bhalf8*)(bp + 8);
            x3a[0] = __builtin_amdgcn_mfma_f32_16x16x32_bf16(ah0, bh, x3a[0], 0, 0, 0);
            x3a[1] = __builtin_amdgcn_mfma_f32_16x16x32_bf16(ah1, bh, x3a[1], 0, 0, 0);
            x3a[0] = __builtin_amdgcn_mfma_f32_16x16x32_bf16(ah0, bl, x3a[0], 0, 0, 0);
            x3a[1] = __builtin_amdgcn_mfma_f32_16x16x32_bf16(ah1, bl, x3a[1], 0, 0, 0);
            x3a[0] = __builtin_amdgcn_mfma_f32_16x16x32_bf16(al0, bh, x3a[0], 0, 0, 0);
            x3a[1] = __builtin_amdgcn_mfma_f32_16x16x32_bf16(al1, bh, x3a[1], 0, 0, 0);
        }
    }

    // ---- phase 4: t = x1 @ M, split 3-term MFMA, -> sT bf16 ----
    {
        f32x4 tacc[2][8] = {};
#pragma unroll
        for (int kt = 0; kt < 2; ++kt) {
            bhalf8 ah0 = *(const bhalf8*)(sX1bH + m*72      + kt*32 + qd*8);
            bhalf8 ah1 = *(const bhalf8*)(sX1bH + (16+m)*72 + kt*32 + qd*8);
            bhalf8 al0 = *(const bhalf8*)(sX1bL + m*72      + kt*32 + qd*8);
            bhalf8 al1 = *(const bhalf8*)(sX1bL + (16+m)*72 + kt*32 + qd*8);
#pragma unroll
            for (int nt2 = 0; nt2 < 8; ++nt2) {
                int nt = w*8 + nt2;
                const unsigned short* bp = Mf2 + ((nt*2 + kt)*64 + l)*16;
                bhalf8 bh = *(const bhalf8*)(bp);
                bhalf8 bl = *(const bhalf8*)(bp + 8);
                tacc[0][nt2] = __builtin_amdgcn_mfma_f32_16x16x32_bf16(ah0, bh, tacc[0][nt2], 0, 0, 0);
                tacc[1][nt2] = __builtin_amdgcn_mfma_f32_16x16x32_bf16(ah1, bh, tacc[1][nt2], 0, 0, 0);
                tacc[0][nt2] = __builtin_amdgcn_mfma_f32_16x16x32_bf16(ah0, bl, tacc[0][nt2], 0, 0, 0);
                tacc[1][nt2] = __builtin_amdgcn_mfma_f32_16x16x32_bf16(ah1, bl, tacc[1][nt2], 0, 0, 0);
                tacc[0][nt2] = __builtin_amdgcn_mfma_f32_16x16x32_bf16(al0, bh, tacc[0][nt2], 0, 0, 0);
                tacc[1][nt2] = __builtin_amdgcn_mfma_f32_16x16x32_bf16(al1, bh, tacc[1][nt2], 0, 0, 0);
            }
        }
        __syncthreads();   // ALL reads of sX1b/sX2b done before sT overlays
#pragma unroll
        for (int rt = 0; rt < 2; ++rt)
#pragma unroll
            for (int nt2 = 0; nt2 < 8; ++nt2)
#pragma unroll
                for (int r = 0; r < 4; ++r)
                    sT[(rt*16 + qd*4 + r)*520 + w*128 + nt2*16 + m] =
                        f2bf(tacc[rt][nt2][r]);
    }
    __syncthreads();

    // ---- load this thread's t-slice into registers ----
    const int b_l = l & 31, half = l >> 5;
    uint4 tq[8];
    {
        const uint4* tp4 = (const uint4*)(sT + b_l*520 + w*128 + half*64);
#pragma unroll
        for (int i = 0; i < 8; ++i) tq[i] = tp4[i];
    }
    __syncthreads();   // sT region free for sIn buffers

    // zero-pad cols 82..95 of BOTH sIn buffers once
    for (int f = t; f < TB*16; f += 256) {
        int r = f >> 4, c = f & 15;
        if (c >= 2) {
#pragma unroll
            for (int k = 0; k < 2; ++k) {
                unsigned short* dH = (unsigned short*)(smem + k*13312);
                unsigned short* dL = (unsigned short*)(smem + k*13312 + 6656);
                dH[r*104 + 80 + c] = 0;
                dL[r*104 + 80 + c] = 0;
            }
        }
    }
    // stage agent 0 directly into buffer 0
    {
        const float* sa = state_others + (size_t)b0 * 64;
        float4 vA = *(const float4*)(sa + t*4);
        float4 vB = *(const float4*)(sa + t*4 + 1024);
        float av[3] = {0.f, 0.f, 0.f};
        if (act_c < 6) {
            const float* aa = act_others + (size_t)(b0 + act_r)*18 + act_c*3;
            av[0] = aa[0]; av[1] = aa[1]; av[2] = aa[2];
        }
        stageIn((unsigned short*)smem, (unsigned short*)(smem + 6656),
                vA, vB, av);
    }
    __syncthreads();   // sIn buf0 (agent 0) ready

    const float bv0 = bvp[w*32 + m];
    const float bv1 = bvp[w*32 + 16 + m];
    f32x4 o4[2][2] = {};
    float mR = -1e30f, sR = 0.f;

    float4 pfA, pfB; float pfa[3] = {0.f, 0.f, 0.f};

    for (int a = 0; a < 7; ++a) {
        unsigned short* sInHc = (unsigned short*)(smem + (a&1)*13312);
        unsigned short* sInLc = (unsigned short*)(smem + (a&1)*13312 + 6656);
        unsigned short* sEnHc = (unsigned short*)(smem + 26624 + (a&1)*17408);
        unsigned short* sEnLc = (unsigned short*)(smem + 26624 + (a&1)*17408 + 8704);
        unsigned short* sInHn = (unsigned short*)(smem + ((a+1)&1)*13312);
        unsigned short* sInLn = (unsigned short*)(smem + ((a+1)&1)*13312 + 6656);

        // ---- issue next agent's HBM loads (regs); hides under enc/vals ----
        if (a < 6) {
            const float* sa = state_others + ((size_t)(a+1)*BTOT + b0)*64;
            pfA = *(const float4*)(sa + t*4);
            pfB = *(const float4*)(sa + t*4 + 1024);
            if (act_c < 6) {
                const float* aa = act_others
                    + ((size_t)(a+1)*BTOT + b0 + act_r)*18 + act_c*3;
                pfa[0] = aa[0]; pfa[1] = aa[1]; pfa[2] = aa[2];
            }
        }
        float be0 = be[a*128 + 32*w + m];
        float be1 = be[a*128 + 32*w + 16 + m];

        // ---- enc(a) = inp @ We_a, split 3-term, wave slice 32 cols ----
        f32x4 eacc[2][2] = {};
#pragma unroll
        for (int kt = 0; kt < 3; ++kt) {
            bhalf8 ah0 = *(const bhalf8*)(sInHc + m*104      + kt*32 + qd*8);
            bhalf8 ah1 = *(const bhalf8*)(sInHc + (16+m)*104 + kt*32 + qd*8);
            bhalf8 al0 = *(const bhalf8*)(sInLc + m*104      + kt*32 + qd*8);
            bhalf8 al1 = *(const bhalf8*)(sInLc + (16+m)*104 + kt*32 + qd*8);
#pragma unroll
            for (int nt2 = 0; nt2 < 2; ++nt2) {
                int nt = 2*w + nt2;
                const unsigned short* bp =
                    Wef2 + (size_t)a*24576 + ((nt*3 + kt)*64 + l)*16;
                bhalf8 bh = *(const bhalf8*)(bp);
                bhalf8 bl = *(const bhalf8*)(bp + 8);
                eacc[0][nt2] = __builtin_amdgcn_mfma_f32_16x16x32_bf16(ah0, bh, eacc[0][nt2], 0, 0, 0);
                eacc[1][nt2] = __builtin_amdgcn_mfma_f32_16x16x32_bf16(ah1, bh, eacc[1][nt2], 0, 0, 0);
                eacc[0][nt2] = __builtin_amdgcn_mfma_f32_16x16x32_bf16(ah0, bl, eacc[0][nt2], 0, 0, 0);
                eacc[1][nt2] = __builtin_amdgcn_mfma_f32_16x16x32_bf16(ah1, bl, eacc[1][nt2], 0, 0, 0);
                eacc[0][nt2] = __builtin_amdgcn_mfma_f32_16x16x32_bf16(al0, bh, eacc[0][nt2], 0, 0, 0);
                eacc[1][nt2] = __builtin_amdgcn_mfma_f32_16x16x32_bf16(al1, bh, eacc[1][nt2], 0, 0, 0);
            }
        }

        // ---- write sEn(a) (relu+bias, split) ----
        {
#pragma unroll
            for (int rt = 0; rt < 2; ++rt)
#pragma unroll
                for (int nt2 = 0; nt2 < 2; ++nt2) {
                    float bb = nt2 ? be1 : be0;
#pragma unroll
                    for (int r = 0; r < 4; ++r) {
                        float e = fmaxf(eacc[rt][nt2][r] + bb, 0.f);
                        int row = rt*16 + qd*4 + r;
                        int col = 32*w + nt2*16 + m;
                        unsigned short hh = f2bf(e);
                        sEnHc[row*136 + col] = hh;
                        sEnLc[row*136 + col] = f2bf(e - bf2f(hh));
                    }
                }
        }
        if (a < 6) stageIn(sInHn, sInLn, pfA, pfB, pfa);

        // ---- THE barrier: sEn(a) and sIn(a+1) visible to all waves ----
        __syncthreads();

        // ---- logits(a); stats in registers ----
        float alpha, pp;
        {
            const uint4* ehp = (const uint4*)(sEnHc + b_l*136 + half*64);
            const uint4* elp = (const uint4*)(sEnLc + b_l*136 + half*64);
            float part = 0.f;
#pragma unroll
            for (int i = 0; i < 8; ++i) {
                uint4 eh = ehp[i];
                uint4 el = elp[i];
                uint4 tt = tq[i];
                part += (bflo(eh.x)+bflo(el.x))*bflo(tt.x)
                      + (bfhi(eh.x)+bfhi(el.x))*bfhi(tt.x);
                part += (bflo(eh.y)+bflo(el.y))*bflo(tt.y)
                      + (bfhi(eh.y)+bfhi(el.y))*bfhi(tt.y);
                part += (bflo(eh.z)+bflo(el.z))*bflo(tt.z)
                      + (bfhi(eh.z)+bfhi(el.z))*bfhi(tt.z);
                part += (bflo(eh.w)+bflo(el.w))*bflo(tt.w)
                      + (bfhi(eh.w)+bfhi(el.w))*bfhi(tt.w);
            }
            part += __shfl_xor(part, 32);
            float lg = part * 0.17677669529663687f;   // 1/sqrt(32)
            float mn = fmaxf(mR, lg);
            alpha = __expf(mR - mn);
            pp    = __expf(lg - mn);
            sR = sR*alpha + pp;
            mR = mn;
        }

        // ---- vals(a) = relu(enc @ Wv + bv); online accumulate ----
        {
            f32x4 vacc[2][2] = {};
#pragma unroll
            for (int kt = 0; kt < 4; ++kt) {
                bhalf8 ah0 = *(const bhalf8*)(sEnHc + m*136      + kt*32 + qd*8);
                bhalf8 ah1 = *(const bhalf8*)(sEnHc + (16+m)*136 + kt*32 + qd*8);
                bhalf8 al0 = *(const bhalf8*)(sEnLc + m*136      + kt*32 + qd*8);
                bhalf8 al1 = *(const bhalf8*)(sEnLc + (16+m)*136 + kt*32 + qd*8);
#pragma unroll
                for (int nt2 = 0; nt2 < 2; ++nt2) {
                    int nt = 2*w + nt2;
                    const unsigned short* bp = Wvf2 + ((nt*4 + kt)*64 + l)*16;
                    bhalf8 bh = *(const bhalf8*)(bp);
                    bhalf8 bl = *(const bhalf8*)(bp + 8);
                    vacc[0][nt2] = __builtin_amdgcn_mfma_f32_16x16x32_bf16(ah0, bh, vacc[0][nt2], 0, 0, 0);
                    vacc[1][nt2] = __builtin_amdgcn_mfma_f32_16x16x32_bf16(ah1, bh, vacc[1][nt2], 0, 0, 0);
                    vacc[0][nt2] = __builtin_amdgcn_mfma_f32_16x16x32_bf16(ah0, bl, vacc[0][nt2], 0, 0, 0);
                    vacc[1][nt2] = __builtin_amdgcn_mfma_f32_16x16x32_bf16(ah1, bl, vacc[1][nt2], 0, 0, 0);
                    vacc[0][nt2] = __builtin_amdgcn_mfma_f32_16x16x32_bf16(al0, bh, vacc[0][nt2], 0, 0, 0);
                    vacc[1][nt2] = __builtin_amdgcn_mfma_f32_16x16x32_bf16(al1, bh, vacc[1][nt2], 0, 0, 0);
                }
            }
#pragma unroll
            for (int rt = 0; rt < 2; ++rt)
#pragma unroll
                for (int r = 0; r < 4; ++r) {
                    int row = rt*16 + qd*4 + r;
                    float al = __shfl(alpha, row);
                    float p  = __shfl(pp, row);
#pragma unroll
                    for (int nt2 = 0; nt2 < 2; ++nt2) {
                        float bb = nt2 ? bv1 : bv0;
                        o4[rt][nt2][r] = o4[rt][nt2][r]*al
                                       + p*fmaxf(vacc[rt][nt2][r] + bb, 0.f);
                    }
                }
        }
    }
    __syncthreads();   // all sEn/sIn reads done; sOv overlays sIn region

    // ---- normalize, write ov as SPLIT bf16 (A-operand for final MFMA) ----
    {
        float rinv = 1.0f / sR;
#pragma unroll
        for (int rt = 0; rt < 2; ++rt)
#pragma unroll
            for (int r = 0; r < 4; ++r) {
                int row = rt*16 + qd*4 + r;
                float inv = __shfl(rinv, row);
#pragma unroll
                for (int nt2 = 0; nt2 < 2; ++nt2) {
                    float v = o4[rt][nt2][r]*inv;
                    int col = 32*w + nt2*16 + m;
                    unsigned short hh = f2bf(v);
                    sOvH[row*136 + col] = hh;
                    sOvL[row*136 + col] = f2bf(v - bf2f(hh));
                }
            }
    }
    __syncthreads();

    // ---- final (MFMA): x3a += ov @ w3_others; out = relu(x3a).Wout + bout
    {
#pragma unroll
        for (int kt = 0; kt < 4; ++kt) {
            bhalf8 ah0 = *(const bhalf8*)(sOvH + m*136      + kt*32 + qd*8);
            bhalf8 ah1 = *(const bhalf8*)(sOvH + (16+m)*136 + kt*32 + qd*8);
            bhalf8 al0 = *(const bhalf8*)(sOvL + m*136      + kt*32 + qd*8);
            bhalf8 al1 = *(const bhalf8*)(sOvL + (16+m)*136 + kt*32 + qd*8);
            const unsigned short* bp = w3of + ((w*4 + kt)*64 + l)*16;
            bhalf8 bh = *(const bhalf8*)(bp);
            bhalf8 bl = *(const bhalf8*)(bp + 8);
            x3a[0] = __builtin_amdgcn_mfma_f32_16x16x32_bf16(ah0, bh, x3a[0], 0, 0, 0);
            x3a[1] = __builtin_amdgcn_mfma_f32_16x16x32_bf16(ah1, bh, x3a[1], 0, 0, 0);
            x3a[0] = __builtin_amdgcn_mfma_f32_16x16x32_bf16(ah0, bl, x3a[0], 0, 0, 0);
            x3a[1] = __builtin_amdgcn_mfma_f32_16x16x32_bf16(ah1, bl, x3a[1], 0, 0, 0);
            x3a[0] = __builtin_amdgcn_mfma_f32_16x16x32_bf16(al0, bh, x3a[0], 0, 0, 0);
            x3a[1] = __builtin_amdgcn_mfma_f32_16x16x32_bf16(al1, bh, x3a[1], 0, 0, 0);
        }
        // lane holds x3[row=rt*16+qd*4+r][col=16w+m]; relu, *Wout, reduce m
        float wo = Wout[w*16 + m];
#pragma unroll
        for (int rt = 0; rt < 2; ++rt)
#pragma unroll
            for (int r = 0; r < 4; ++r) {
                float p = fmaxf(x3a[rt][r], 0.f) * wo;
                p += __shfl_xor(p, 1);
                p += __shfl_xor(p, 2);
                p += __shfl_xor(p, 4);
                p += __shfl_xor(p, 8);
                if (m == 0)
                    sRed[(rt*16 + qd*4 + r)*4 + w] = p;
            }
    }
    __syncthreads();
    if (t < 32)
        out[b0 + t] = sRed[t*4+0] + sRed[t*4+1] + sRed[t*4+2] + sRed[t*4+3]
                    + bout[0];
}

extern "C" void kernel_launch(void* const* d_in, const int* in_sizes, int n_in,
                              void* d_out, int out_size, void* d_ws, size_t ws_size,
                              hipStream_t stream) {
    (void)in_sizes; (void)n_in; (void)out_size; (void)ws_size;
    const float* state_one    = (const float*)d_in[0];
    const float* act_one      = (const float*)d_in[1];
    const float* state_others = (const float*)d_in[2];
    const float* act_others   = (const float*)d_in[3];
    const float* W1           = (const float*)d_in[4];
    const float* b1           = (const float*)d_in[5];
    const float* W2           = (const float*)d_in[6];
    const float* b2           = (const float*)d_in[7];
    const float* w3_self      = (const float*)d_in[8];
    const float* We           = (const float*)d_in[9];
    const float* be           = (const float*)d_in[10];
    const float* Wk           = (const float*)d_in[11];
    const float* Wq           = (const float*)d_in[12];
    const float* Wv           = (const float*)d_in[13];
    const float* bv           = (const float*)d_in[14];
    const float* w3_others    = (const float*)d_in[15];
    const float* Wout         = (const float*)d_in[16];
    const float* bout         = (const float*)d_in[17];
    float* out = (float*)d_out;

    unsigned short* Mf2  = (unsigned short*)d_ws;                    // 131072 B
    unsigned short* Wef2 = (unsigned short*)((char*)d_ws + 131072);  // 344064 B
    unsigned short* Wvf2 = (unsigned short*)((char*)d_ws + 475136);  // 65536 B
    unsigned short* W2f  = (unsigned short*)((char*)d_ws + 540672);  // 16384 B
    unsigned short* w3sf = (unsigned short*)((char*)d_ws + 557056);  // 16384 B
    unsigned short* w3of = (unsigned short*)((char*)d_ws + 573440);  // 32768 B

    fold_M_frag<<<128, 256, 0, stream>>>(Wk, Wq, Mf2);
    conv_We<<<336, 256, 0, stream>>>(We, Wef2);
    conv_Wv<<<64, 256, 0, stream>>>(Wv, Wvf2);
    conv_self<<<64, 256, 0, stream>>>(W2, w3_self, w3_others, W2f, w3sf, w3of);
    fused_critic<<<BTOT/TB, 256, 0, stream>>>(
        state_one, act_one, state_others, act_others,
        W1, b1, b2, be, bv, Wout, bout,
        Mf2, Wef2, Wvf2, W2f, w3sf, w3of, out);
}

// Round 6
// 207.908 us; speedup vs baseline: 1.9080x; 1.1243x over previous
//
#include <hip/hip_runtime.h>
#include <hip/hip_bf16.h>

#define BTOT 32768
#define TB 32

typedef __attribute__((ext_vector_type(8))) short bhalf8;   // 8 bf16 = 4 VGPRs
typedef __attribute__((ext_vector_type(4))) float f32x4;    // MFMA acc

// R12: native cast (single v_cvt) instead of 5-op integer RNE.
static __device__ __forceinline__ unsigned short f2bf(float x) {
    __hip_bfloat16 h = __float2bfloat16(x);
    unsigned short u;
    __builtin_memcpy(&u, &h, sizeof(u));
    return u;
}
static __device__ __forceinline__ float bf2f(unsigned short s) {
    return __uint_as_float(((unsigned int)s) << 16);
}

// ---------------------------------------------------------------------------
// Weight preprocessing into MFMA B-fragment-linear SPLIT bf16 (hi|lo).
// B-frag for (kt, nt): lane l holds B[k=kt*32+(l>>4)*8+j][n=nt*16+(l&15)],
// hi at idx = ((nt*KT+kt)*64 + l)*16 + j, lo at +8+j.
// ws: Mf2  @0       131072 B (M = Wq@Wk^T as [64 x 512], KT=2, NT=32)
//     Wef2 @131072  344064 B (per agent We[96 x 128], KT=3, NT=8)
//     Wvf2 @475136  65536 B  (Wv as [128 x 128], n=h*32+d, KT=4, NT=8)
//     W2f  @540672  16384 B  (W2 [64 x 64], KT=2, NT=4)          [R13]
//     w3sf @557056  16384 B  (w3_self [64 x 64], KT=2, NT=4)     [R13]
//     w3of @573440  32768 B  (w3_others [128 x 64], KT=4, NT=4)  [R13]
//     W1f  @606208  24576 B  (W1 [96 x 64] pad k>=78, KT=3, NT=4)[R14]
// R9/R11 lesson (twice): launch_bounds second-arg implying VGPR<120 collapses
// the allocator to 64 VGPR -> ~500MB scratch spills. Never request >2
// waves/EU for fused_critic. Occupancy axis is dead.
// R13 lesson: VALU scalar GEMMs were the dominant removable cost; deleting
// ~4K VALU instr/thread gave -24%. R14 applies the same to logits (MFMA
// diagonal fused into the vals loop) and phase 1 (MFMA with W1 fragment).
// ---------------------------------------------------------------------------
__global__ __launch_bounds__(256) void fold_M_frag(
        const float* __restrict__ Wk, const float* __restrict__ Wq,
        unsigned short* __restrict__ Mf2)
{
    int tid = blockIdx.x * 256 + threadIdx.x;   // 32768
    int h  = tid >> 13;
    int jq = (tid >> 7) & 63;
    int j  = tid & 127;
    const float* q = Wq + (h*64 + jq)*32;
    const float* k = Wk + (h*128 + j)*32;
    float acc = 0.f;
#pragma unroll
    for (int d = 0; d < 32; d += 4) {
        float4 a = *(const float4*)(q + d);
        float4 b = *(const float4*)(k + d);
        acc += a.x*b.x + a.y*b.y + a.z*b.z + a.w*b.w;
    }
    unsigned short hi = f2bf(acc);
    unsigned short lo = f2bf(acc - bf2f(hi));
    int n  = h*128 + j;
    int kt = jq >> 5, qd = (jq >> 3) & 3, jj = jq & 7;
    int nt = n >> 4,  ln = n & 15;
    size_t base = (((nt*2 + kt)*64) + qd*16 + ln)*16;
    Mf2[base + jj]     = hi;
    Mf2[base + 8 + jj] = lo;
}

__global__ __launch_bounds__(256) void conv_We(
        const float* __restrict__ We, unsigned short* __restrict__ Wef2)
{
    int tid = blockIdx.x * 256 + threadIdx.x;   // 7*96*128 = 86016
    int a = tid / 12288;
    int r = tid - a*12288;
    int k = r >> 7;          // 0..95
    int n = r & 127;
    float v = (k < 82) ? We[((size_t)a*82 + k)*128 + n] : 0.f;
    unsigned short hi = f2bf(v);
    unsigned short lo = f2bf(v - bf2f(hi));
    int kt = k >> 5, qd = (k >> 3) & 3, j = k & 7;
    int nt = n >> 4, ln = n & 15;
    size_t base = (size_t)a*24576 + (((nt*3 + kt)*64) + qd*16 + ln)*16;
    Wef2[base + j]     = hi;
    Wef2[base + 8 + j] = lo;
}

__global__ __launch_bounds__(256) void conv_Wv(
        const float* __restrict__ Wv, unsigned short* __restrict__ Wvf2)
{
    int tid = blockIdx.x * 256 + threadIdx.x;   // 4*128*32 = 16384
    int h = tid >> 12;
    int j = (tid >> 5) & 127;
    int d = tid & 31;
    float v = Wv[tid];
    unsigned short hi = f2bf(v);
    unsigned short lo = f2bf(v - bf2f(hi));
    int k = j, n = h*32 + d;
    int kt = k >> 5, qd = (k >> 3) & 3, jj = k & 7;
    int nt = n >> 4, ln = n & 15;
    size_t base = (((nt*4 + kt)*64) + qd*16 + ln)*16;
    Wvf2[base + jj]     = hi;
    Wvf2[base + 8 + jj] = lo;
}

// W2 [64x64] KT=2, w3_self [64x64] KT=2, w3_others [128x64] KT=4,
// W1 [96x64] KT=3 (rows >=78 zero)   [R14]
__global__ __launch_bounds__(256) void conv_self(
        const float* __restrict__ W2, const float* __restrict__ w3_self,
        const float* __restrict__ w3_others, const float* __restrict__ W1,
        unsigned short* __restrict__ W2f, unsigned short* __restrict__ w3sf,
        unsigned short* __restrict__ w3of, unsigned short* __restrict__ W1f)
{
    int tid = blockIdx.x * 256 + threadIdx.x;   // 22528
    if (tid >= 22528) return;
    const float* src;
    unsigned short* dst;
    int idx, KT, kmax;
    if (tid < 4096)       { src = W2;        dst = W2f;  idx = tid;         KT = 2; kmax = 64; }
    else if (tid < 8192)  { src = w3_self;   dst = w3sf; idx = tid - 4096;  KT = 2; kmax = 64; }
    else if (tid < 16384) { src = w3_others; dst = w3of; idx = tid - 8192;  KT = 4; kmax = 128; }
    else                  { src = W1;        dst = W1f;  idx = tid - 16384; KT = 3; kmax = 78; }
    int k = idx >> 6;
    int n = idx & 63;
    float v = (k < kmax) ? src[k*64 + n] : 0.f;
    unsigned short hi = f2bf(v);
    unsigned short lo = f2bf(v - bf2f(hi));
    int kt = k >> 5, qd = (k >> 3) & 3, j = k & 7;
    int nt = n >> 4, ln = n & 15;
    size_t base = (((nt*KT + kt)*64) + qd*16 + ln)*16;
    dst[base + j]     = hi;
    dst[base + 8 + j] = lo;
}

// ---------------------------------------------------------------------------
// Fused critic. TB=32 rows/block, 256 threads (4 waves), 1024 blocks.
// R14 = R13 with:
//   * phase 1 MFMA-ized (self input staged split-bf16 [32x96], W1f KT=3)
//   * logits via MFMA DIAGONAL fused into the vals kt-loop: t kept in
//     B-fragment registers tB0/tB1 (read from sT; same 32 VGPRs as old tq);
//     lacc[rt] = enc_hi@t^T + enc_lo@t^T over full K=128; the logit for row
//     n is C[n][n] -> lane ((n>>2)<<4)|n, reg n&3 (m89 C-layout). Extraction
//     = 6 cndmask + 2 shfl + 1 cndmask. No shfl_xor(32) combine needed;
//     both halves shfl from the same src lane -> identical stats (registers
//     + wave-collective only; quarantine preserved).
// LDS 61440 B:
//   self : sXbH[32x104]@0, sXbL@6656 (13312); sX1bH[32x72]@13312,
//          sX1bL@17920; sX2bH@22528, sX2bL@27136 (ends 31744)
//   t    : sT bf16[32x520]@0..33280 (overlays self; written only after the
//          internal barrier that ends all sX1b/sX2b reads)
//   agent: sIn buf k: H@k*13312, L@+6656 (ends 26624)
//          sEn buf k: H@26624+k*17408, L@+8704 (ends 61440)
//   final: sOvH bf16[32x136]@0, sOvL@8704, sRed f32[32x4]@17408
// Every LDS producer->consumer crosses exactly one __syncthreads.
// ---------------------------------------------------------------------------
__global__ __launch_bounds__(256, 2) void fused_critic(
    const float* __restrict__ state_one, const float* __restrict__ act_one,
    const float* __restrict__ state_others, const float* __restrict__ act_others,
    const float* __restrict__ b1, const float* __restrict__ b2,
    const float* __restrict__ be, const float* __restrict__ bvp,
    const float* __restrict__ Wout, const float* __restrict__ bout,
    const unsigned short* __restrict__ Mf2, const unsigned short* __restrict__ Wef2,
    const unsigned short* __restrict__ Wvf2, const unsigned short* __restrict__ W2f,
    const unsigned short* __restrict__ w3sf, const unsigned short* __restrict__ w3of,
    const unsigned short* __restrict__ W1f, float* __restrict__ out)
{
    __shared__ __align__(16) unsigned char smem[61440];
    unsigned short* sXbH  = (unsigned short*)smem;           // stride 104
    unsigned short* sXbL  = (unsigned short*)(smem + 6656);  // stride 104
    unsigned short* sX1bH = (unsigned short*)(smem + 13312); // stride 72
    unsigned short* sX1bL = (unsigned short*)(smem + 17920); // stride 72
    unsigned short* sX2bH = (unsigned short*)(smem + 22528); // stride 72
    unsigned short* sX2bL = (unsigned short*)(smem + 27136); // stride 72
    unsigned short* sT    = (unsigned short*)smem;           // stride 520
    unsigned short* sOvH  = (unsigned short*)smem;           // stride 136
    unsigned short* sOvL  = (unsigned short*)(smem + 8704);  // stride 136
    float*          sRed  = (float*)(smem + 17408);          // [32][4]

    const int t  = threadIdx.x;
    const int b0 = blockIdx.x * TB;
    const int w  = t >> 6;        // wave = head / self-col-tile
    const int l  = t & 63;
    const int m  = l & 15;        // MFMA A row / C col
    const int qd = l >> 4;        // quad

    const int act_r = t >> 3, act_c = t & 7;

    // staging helper: split-bf16 convert regs -> given sIn buffer (cols 0..81)
    auto stageIn = [&](unsigned short* dH, unsigned short* dL,
                       const float4& vA, const float4& vB, const float* av) {
        const int r0 = t >> 4, c4 = (t & 15) << 2;
        ushort4 h4, l4;
        h4.x = f2bf(vA.x); l4.x = f2bf(vA.x - bf2f(h4.x));
        h4.y = f2bf(vA.y); l4.y = f2bf(vA.y - bf2f(h4.y));
        h4.z = f2bf(vA.z); l4.z = f2bf(vA.z - bf2f(h4.z));
        h4.w = f2bf(vA.w); l4.w = f2bf(vA.w - bf2f(h4.w));
        *(ushort4*)(dH + r0*104 + c4) = h4;
        *(ushort4*)(dL + r0*104 + c4) = l4;
        h4.x = f2bf(vB.x); l4.x = f2bf(vB.x - bf2f(h4.x));
        h4.y = f2bf(vB.y); l4.y = f2bf(vB.y - bf2f(h4.y));
        h4.z = f2bf(vB.z); l4.z = f2bf(vB.z - bf2f(h4.z));
        h4.w = f2bf(vB.w); l4.w = f2bf(vB.w - bf2f(h4.w));
        *(ushort4*)(dH + (r0+16)*104 + c4) = h4;
        *(ushort4*)(dL + (r0+16)*104 + c4) = l4;
        if (act_c < 6) {
#pragma unroll
            for (int e = 0; e < 3; ++e) {
                float v = av[e];
                unsigned short hh = f2bf(v);
                dH[act_r*104 + 64 + act_c*3 + e] = hh;
                dL[act_r*104 + 64 + act_c*3 + e] = f2bf(v - bf2f(hh));
            }
        }
    };

    // ---- stage self input [32 x 96] split bf16 (cols 78..95 zero) ----
    {
        const int r0 = t >> 4, c4 = (t & 15) << 2;
        float4 vA = *(const float4*)(state_one + (size_t)(b0 + r0)*64 + c4);
        float4 vB = *(const float4*)(state_one + (size_t)(b0 + r0 + 16)*64 + c4);
        ushort4 h4, l4;
        h4.x = f2bf(vA.x); l4.x = f2bf(vA.x - bf2f(h4.x));
        h4.y = f2bf(vA.y); l4.y = f2bf(vA.y - bf2f(h4.y));
        h4.z = f2bf(vA.z); l4.z = f2bf(vA.z - bf2f(h4.z));
        h4.w = f2bf(vA.w); l4.w = f2bf(vA.w - bf2f(h4.w));
        *(ushort4*)(sXbH + r0*104 + c4) = h4;
        *(ushort4*)(sXbL + r0*104 + c4) = l4;
        h4.x = f2bf(vB.x); l4.x = f2bf(vB.x - bf2f(h4.x));
        h4.y = f2bf(vB.y); l4.y = f2bf(vB.y - bf2f(h4.y));
        h4.z = f2bf(vB.z); l4.z = f2bf(vB.z - bf2f(h4.z));
        h4.w = f2bf(vB.w); l4.w = f2bf(vB.w - bf2f(h4.w));
        *(ushort4*)(sXbH + (r0+16)*104 + c4) = h4;
        *(ushort4*)(sXbL + (r0+16)*104 + c4) = l4;
        // act cols 64..79 (78,79 zero)
#pragma unroll
        for (int e = 0; e < 2; ++e) {
            int cc = act_c*2 + e;
            float v = (cc < 14) ? act_one[(size_t)(b0 + act_r)*14 + cc] : 0.f;
            unsigned short hh = f2bf(v);
            sXbH[act_r*104 + 64 + cc] = hh;
            sXbL[act_r*104 + 64 + cc] = f2bf(v - bf2f(hh));
        }
        // pad cols 80..95
        for (int f = t; f < TB*16; f += 256) {
            int r = f >> 4, c = 80 + (f & 15);
            sXbH[r*104 + c] = 0;
            sXbL[r*104 + c] = 0;
        }
    }
    __syncthreads();

    // ---- phase 1 (MFMA): x1 = relu(x @ W1 + b1) -> split bf16 LDS ----
    {
        f32x4 acc1[2] = {};
#pragma unroll
        for (int kt = 0; kt < 3; ++kt) {
            bhalf8 ah0 = *(const bhalf8*)(sXbH + m*104      + kt*32 + qd*8);
            bhalf8 ah1 = *(const bhalf8*)(sXbH + (16+m)*104 + kt*32 + qd*8);
            bhalf8 al0 = *(const bhalf8*)(sXbL + m*104      + kt*32 + qd*8);
            bhalf8 al1 = *(const bhalf8*)(sXbL + (16+m)*104 + kt*32 + qd*8);
            const unsigned short* bp = W1f + ((w*3 + kt)*64 + l)*16;
            bhalf8 bh = *(const bhalf8*)(bp);
            bhalf8 bl = *(const bhalf8*)(bp + 8);
            acc1[0] = __builtin_amdgcn_mfma_f32_16x16x32_bf16(ah0, bh, acc1[0], 0, 0, 0);
            acc1[1] = __builtin_amdgcn_mfma_f32_16x16x32_bf16(ah1, bh, acc1[1], 0, 0, 0);
            acc1[0] = __builtin_amdgcn_mfma_f32_16x16x32_bf16(ah0, bl, acc1[0], 0, 0, 0);
            acc1[1] = __builtin_amdgcn_mfma_f32_16x16x32_bf16(ah1, bl, acc1[1], 0, 0, 0);
            acc1[0] = __builtin_amdgcn_mfma_f32_16x16x32_bf16(al0, bh, acc1[0], 0, 0, 0);
            acc1[1] = __builtin_amdgcn_mfma_f32_16x16x32_bf16(al1, bh, acc1[1], 0, 0, 0);
        }
        int col = w*16 + m;
        float b1c = b1[col];
#pragma unroll
        for (int rt = 0; rt < 2; ++rt)
#pragma unroll
            for (int r = 0; r < 4; ++r) {
                float e = fmaxf(acc1[rt][r] + b1c, 0.f);
                int row = rt*16 + qd*4 + r;
                unsigned short hh = f2bf(e);
                sX1bH[row*72 + col] = hh;
                sX1bL[row*72 + col] = f2bf(e - bf2f(hh));
            }
    }
    __syncthreads();

    // ---- phase 2 (MFMA): x2 = relu(x1 @ W2 + b2) -> split bf16 LDS ----
    {
        f32x4 acc2[2] = {};
#pragma unroll
        for (int kt = 0; kt < 2; ++kt) {
            bhalf8 ah0 = *(const bhalf8*)(sX1bH + m*72      + kt*32 + qd*8);
            bhalf8 ah1 = *(const bhalf8*)(sX1bH + (16+m)*72 + kt*32 + qd*8);
            bhalf8 al0 = *(const bhalf8*)(sX1bL + m*72      + kt*32 + qd*8);
            bhalf8 al1 = *(const bhalf8*)(sX1bL + (16+m)*72 + kt*32 + qd*8);
            const unsigned short* bp = W2f + ((w*2 + kt)*64 + l)*16;
            bhalf8 bh = *(const bhalf8*)(bp);
            bhalf8 bl = *(const bhalf8*)(bp + 8);
            acc2[0] = __builtin_amdgcn_mfma_f32_16x16x32_bf16(ah0, bh, acc2[0], 0, 0, 0);
            acc2[1] = __builtin_amdgcn_mfma_f32_16x16x32_bf16(ah1, bh, acc2[1], 0, 0, 0);
            acc2[0] = __builtin_amdgcn_mfma_f32_16x16x32_bf16(ah0, bl, acc2[0], 0, 0, 0);
            acc2[1] = __builtin_amdgcn_mfma_f32_16x16x32_bf16(ah1, bl, acc2[1], 0, 0, 0);
            acc2[0] = __builtin_amdgcn_mfma_f32_16x16x32_bf16(al0, bh, acc2[0], 0, 0, 0);
            acc2[1] = __builtin_amdgcn_mfma_f32_16x16x32_bf16(al1, bh, acc2[1], 0, 0, 0);
        }
        int col = w*16 + m;
        float b2c = b2[col];
#pragma unroll
        for (int rt = 0; rt < 2; ++rt)
#pragma unroll
            for (int r = 0; r < 4; ++r) {
                float e = fmaxf(acc2[rt][r] + b2c, 0.f);
                int row = rt*16 + qd*4 + r;
                unsigned short hh = f2bf(e);
                sX2bH[row*72 + col] = hh;
                sX2bL[row*72 + col] = f2bf(e - bf2f(hh));
            }
    }
    __syncthreads();

    // ---- phase 3 (MFMA): x3a = x2 @ w3_self, kept in registers ----
    f32x4 x3a[2] = {};
    {
#pragma unroll
        for (int kt = 0; kt < 2; ++kt) {
            bhalf8 ah0 = *(const bhalf8*)(sX2bH + m*72      + kt*32 + qd*8);
            bhalf8 ah1 = *(const bhalf8*)(sX2bH + (16+m)*72 + kt*32 + qd*8);
            bhalf8 al0 = *(const bhalf8*)(sX2bL + m*72      + kt*32 + qd*8);
            bhalf8 al1 = *(const bhalf8*)(sX2bL + (16+m)*72 + kt*32 + qd*8);
            const unsigned short* bp = w3sf + ((w*2 + kt)*64 + l)*16;
            bhalf8 bh = *(const bhalf8*)(bp);
            bhalf8 bl = *(const bhalf8*)(bp + 8);
            x3a[0] = __builtin_amdgcn_mfma_f32_16x16x32_bf16(ah0, bh, x3a[0], 0, 0, 0);
            x3a[1] = __builtin_amdgcn_mfma_f32_16x16x32_bf16(ah1, bh, x3a[1], 0, 0, 0);
            x3a[0] = __builtin_amdgcn_mfma_f32_16x16x32_bf16(ah0, bl, x3a[0], 0, 0, 0);
            x3a[1] = __builtin_amdgcn_mfma_f32_16x16x32_bf16(ah1, bl, x3a[1], 0, 0, 0);
            x3a[0] = __builtin_amdgcn_mfma_f32_16x16x32_bf16(al0, bh, x3a[0], 0, 0, 0);
            x3a[1] = __builtin_amdgcn_mfma_f32_16x16x32_bf16(al1, bh, x3a[1], 0, 0, 0);
        }
    }

    // ---- phase 4: t = x1 @ M, split 3-term MFMA, -> sT bf16 ----
    {
        f32x4 tacc[2][8] = {};
#pragma unroll
        for (int kt = 0; kt < 2; ++kt) {
            bhalf8 ah0 = *(const bhalf8*)(sX1bH + m*72      + kt*32 + qd*8);
            bhalf8 ah1 = *(const bhalf8*)(sX1bH + (16+m)*72 + kt*32 + qd*8);
            bhalf8 al0 = *(const bhalf8*)(sX1bL + m*72      + kt*32 + qd*8);
            bhalf8 al1 = *(const bhalf8*)(sX1bL + (16+m)*72 + kt*32 + qd*8);
#pragma unroll
            for (int nt2 = 0; nt2 < 8; ++nt2) {
                int nt = w*8 + nt2;
                const unsigned short* bp = Mf2 + ((nt*2 + kt)*64 + l)*16;
                bhalf8 bh = *(const bhalf8*)(bp);
                bhalf8 bl = *(const bhalf8*)(bp + 8);
                tacc[0][nt2] = __builtin_amdgcn_mfma_f32_16x16x32_bf16(ah0, bh, tacc[0][nt2], 0, 0, 0);
                tacc[1][nt2] = __builtin_amdgcn_mfma_f32_16x16x32_bf16(ah1, bh, tacc[1][nt2], 0, 0, 0);
                tacc[0][nt2] = __builtin_amdgcn_mfma_f32_16x16x32_bf16(ah0, bl, tacc[0][nt2], 0, 0, 0);
                tacc[1][nt2] = __builtin_amdgcn_mfma_f32_16x16x32_bf16(ah1, bl, tacc[1][nt2], 0, 0, 0);
                tacc[0][nt2] = __builtin_amdgcn_mfma_f32_16x16x32_bf16(al0, bh, tacc[0][nt2], 0, 0, 0);
                tacc[1][nt2] = __builtin_amdgcn_mfma_f32_16x16x32_bf16(al1, bh, tacc[1][nt2], 0, 0, 0);
            }
        }
        __syncthreads();   // ALL reads of sXb/sX1b/sX2b done before sT overlays
#pragma unroll
        for (int rt = 0; rt < 2; ++rt)
#pragma unroll
            for (int nt2 = 0; nt2 < 8; ++nt2)
#pragma unroll
                for (int r = 0; r < 4; ++r)
                    sT[(rt*16 + qd*4 + r)*520 + w*128 + nt2*16 + m] =
                        f2bf(tacc[rt][nt2][r]);
    }
    __syncthreads();

    // ---- load t as B-FRAGMENT registers (logits MFMA), rows m / 16+m ----
    // tB0[kt]: lane l holds t[l&15][w*128 + kt*32 + qd*8 + j]  (B-frag)
    const int b_l = l & 31;
    bhalf8 tB0[4], tB1[4];
    {
#pragma unroll
        for (int kt = 0; kt < 4; ++kt) {
            tB0[kt] = *(const bhalf8*)(sT + m*520      + w*128 + kt*32 + qd*8);
            tB1[kt] = *(const bhalf8*)(sT + (16+m)*520 + w*128 + kt*32 + qd*8);
        }
    }
    __syncthreads();   // sT region free for sIn buffers

    // zero-pad cols 82..95 of BOTH sIn buffers once
    for (int f = t; f < TB*16; f += 256) {
        int r = f >> 4, c = f & 15;
        if (c >= 2) {
#pragma unroll
            for (int k = 0; k < 2; ++k) {
                unsigned short* dH = (unsigned short*)(smem + k*13312);
                unsigned short* dL = (unsigned short*)(smem + k*13312 + 6656);
                dH[r*104 + 80 + c] = 0;
                dL[r*104 + 80 + c] = 0;
            }
        }
    }
    // stage agent 0 directly into buffer 0
    {
        const float* sa = state_others + (size_t)b0 * 64;
        float4 vA = *(const float4*)(sa + t*4);
        float4 vB = *(const float4*)(sa + t*4 + 1024);
        float av[3] = {0.f, 0.f, 0.f};
        if (act_c < 6) {
            const float* aa = act_others + (size_t)(b0 + act_r)*18 + act_c*3;
            av[0] = aa[0]; av[1] = aa[1]; av[2] = aa[2];
        }
        stageIn((unsigned short*)smem, (unsigned short*)(smem + 6656),
                vA, vB, av);
    }
    __syncthreads();   // sIn buf0 (agent 0) ready

    const float bv0 = bvp[w*32 + m];
    const float bv1 = bvp[w*32 + 16 + m];
    f32x4 o4[2][2] = {};
    float mR = -1e30f, sR = 0.f;

    // diag extraction constants: logit row b_l sits in lane src, lacc[b_l>>4]
    const int nsel = l & 15;
    const int srcl = ((nsel >> 2) << 4) | nsel;

    float4 pfA, pfB; float pfa[3] = {0.f, 0.f, 0.f};

    for (int a = 0; a < 7; ++a) {
        unsigned short* sInHc = (unsigned short*)(smem + (a&1)*13312);
        unsigned short* sInLc = (unsigned short*)(smem + (a&1)*13312 + 6656);
        unsigned short* sEnHc = (unsigned short*)(smem + 26624 + (a&1)*17408);
        unsigned short* sEnLc = (unsigned short*)(smem + 26624 + (a&1)*17408 + 8704);
        unsigned short* sInHn = (unsigned short*)(smem + ((a+1)&1)*13312);
        unsigned short* sInLn = (unsigned short*)(smem + ((a+1)&1)*13312 + 6656);

        // ---- issue next agent's HBM loads (regs); hides under enc/vals ----
        if (a < 6) {
            const float* sa = state_others + ((size_t)(a+1)*BTOT + b0)*64;
            pfA = *(const float4*)(sa + t*4);
            pfB = *(const float4*)(sa + t*4 + 1024);
            if (act_c < 6) {
                const float* aa = act_others
                    + ((size_t)(a+1)*BTOT + b0 + act_r)*18 + act_c*3;
                pfa[0] = aa[0]; pfa[1] = aa[1]; pfa[2] = aa[2];
            }
        }
        float be0 = be[a*128 + 32*w + m];
        float be1 = be[a*128 + 32*w + 16 + m];

        // ---- enc(a) = inp @ We_a, split 3-term, wave slice 32 cols ----
        f32x4 eacc[2][2] = {};
#pragma unroll
        for (int kt = 0; kt < 3; ++kt) {
            bhalf8 ah0 = *(const bhalf8*)(sInHc + m*104      + kt*32 + qd*8);
            bhalf8 ah1 = *(const bhalf8*)(sInHc + (16+m)*104 + kt*32 + qd*8);
            bhalf8 al0 = *(const bhalf8*)(sInLc + m*104      + kt*32 + qd*8);
            bhalf8 al1 = *(const bhalf8*)(sInLc + (16+m)*104 + kt*32 + qd*8);
#pragma unroll
            for (int nt2 = 0; nt2 < 2; ++nt2) {
                int nt = 2*w + nt2;
                const unsigned short* bp =
                    Wef2 + (size_t)a*24576 + ((nt*3 + kt)*64 + l)*16;
                bhalf8 bh = *(const bhalf8*)(bp);
                bhalf8 bl = *(const bhalf8*)(bp + 8);
                eacc[0][nt2] = __builtin_amdgcn_mfma_f32_16x16x32_bf16(ah0, bh, eacc[0][nt2], 0, 0, 0);
                eacc[1][nt2] = __builtin_amdgcn_mfma_f32_16x16x32_bf16(ah1, bh, eacc[1][nt2], 0, 0, 0);
                eacc[0][nt2] = __builtin_amdgcn_mfma_f32_16x16x32_bf16(ah0, bl, eacc[0][nt2], 0, 0, 0);
                eacc[1][nt2] = __builtin_amdgcn_mfma_f32_16x16x32_bf16(ah1, bl, eacc[1][nt2], 0, 0, 0);
                eacc[0][nt2] = __builtin_amdgcn_mfma_f32_16x16x32_bf16(al0, bh, eacc[0][nt2], 0, 0, 0);
                eacc[1][nt2] = __builtin_amdgcn_mfma_f32_16x16x32_bf16(al1, bh, eacc[1][nt2], 0, 0, 0);
            }
        }

        // ---- write sEn(a) (relu+bias, split) ----
        {
#pragma unroll
            for (int rt = 0; rt < 2; ++rt)
#pragma unroll
                for (int nt2 = 0; nt2 < 2; ++nt2) {
                    float bb = nt2 ? be1 : be0;
#pragma unroll
                    for (int r = 0; r < 4; ++r) {
                        float e = fmaxf(eacc[rt][nt2][r] + bb, 0.f);
                        int row = rt*16 + qd*4 + r;
                        int col = 32*w + nt2*16 + m;
                        unsigned short hh = f2bf(e);
                        sEnHc[row*136 + col] = hh;
                        sEnLc[row*136 + col] = f2bf(e - bf2f(hh));
                    }
                }
        }
        if (a < 6) stageIn(sInHn, sInLn, pfA, pfB, pfa);

        // ---- THE barrier: sEn(a) and sIn(a+1) visible to all waves ----
        __syncthreads();

        // ---- fused vals + logits MFMA loop (shared A-fragments) ----
        f32x4 vacc[2][2] = {};
        f32x4 lacc0 = {}, lacc1 = {};
#pragma unroll
        for (int kt = 0; kt < 4; ++kt) {
            bhalf8 ah0 = *(const bhalf8*)(sEnHc + m*136      + kt*32 + qd*8);
            bhalf8 ah1 = *(const bhalf8*)(sEnHc + (16+m)*136 + kt*32 + qd*8);
            bhalf8 al0 = *(const bhalf8*)(sEnLc + m*136      + kt*32 + qd*8);
            bhalf8 al1 = *(const bhalf8*)(sEnLc + (16+m)*136 + kt*32 + qd*8);
#pragma unroll
            for (int nt2 = 0; nt2 < 2; ++nt2) {
                int nt = 2*w + nt2;
                const unsigned short* bp = Wvf2 + ((nt*4 + kt)*64 + l)*16;
                bhalf8 bh = *(const bhalf8*)(bp);
                bhalf8 bl = *(const bhalf8*)(bp + 8);
                vacc[0][nt2] = __builtin_amdgcn_mfma_f32_16x16x32_bf16(ah0, bh, vacc[0][nt2], 0, 0, 0);
                vacc[1][nt2] = __builtin_amdgcn_mfma_f32_16x16x32_bf16(ah1, bh, vacc[1][nt2], 0, 0, 0);
                vacc[0][nt2] = __builtin_amdgcn_mfma_f32_16x16x32_bf16(ah0, bl, vacc[0][nt2], 0, 0, 0);
                vacc[1][nt2] = __builtin_amdgcn_mfma_f32_16x16x32_bf16(ah1, bl, vacc[1][nt2], 0, 0, 0);
                vacc[0][nt2] = __builtin_amdgcn_mfma_f32_16x16x32_bf16(al0, bh, vacc[0][nt2], 0, 0, 0);
                vacc[1][nt2] = __builtin_amdgcn_mfma_f32_16x16x32_bf16(al1, bh, vacc[1][nt2], 0, 0, 0);
            }
            // logits diag: C[r][n] = enc_rows @ t_rows^T (B-frag from regs)
            lacc0 = __builtin_amdgcn_mfma_f32_16x16x32_bf16(ah0, tB0[kt], lacc0, 0, 0, 0);
            lacc0 = __builtin_amdgcn_mfma_f32_16x16x32_bf16(al0, tB0[kt], lacc0, 0, 0, 0);
            lacc1 = __builtin_amdgcn_mfma_f32_16x16x32_bf16(ah1, tB1[kt], lacc1, 0, 0, 0);
            lacc1 = __builtin_amdgcn_mfma_f32_16x16x32_bf16(al1, tB1[kt], lacc1, 0, 0, 0);
        }

        // ---- extract diag -> stats (registers + wave-collective only) ----
        float alpha, pp;
        {
            // src lane provides both rt candidates at element (l&3)
            float e01 = (l & 1) ? lacc0[1] : lacc0[0];
            float e23 = (l & 1) ? lacc0[3] : lacc0[2];
            float d0  = (l & 2) ? e23 : e01;
            float f01 = (l & 1) ? lacc1[1] : lacc1[0];
            float f23 = (l & 1) ? lacc1[3] : lacc1[2];
            float d1  = (l & 2) ? f23 : f01;
            float g0 = __shfl(d0, srcl);
            float g1 = __shfl(d1, srcl);
            float part = (l & 16) ? g1 : g0;
            float lg = part * 0.17677669529663687f;   // 1/sqrt(32)
            float mn = fmaxf(mR, lg);
            alpha = __expf(mR - mn);
            pp    = __expf(lg - mn);
            sR = sR*alpha + pp;
            mR = mn;
        }

        // ---- online accumulate o4 ----
        {
#pragma unroll
            for (int rt = 0; rt < 2; ++rt)
#pragma unroll
                for (int r = 0; r < 4; ++r) {
                    int row = rt*16 + qd*4 + r;
                    float al = __shfl(alpha, row);
                    float p  = __shfl(pp, row);
#pragma unroll
                    for (int nt2 = 0; nt2 < 2; ++nt2) {
                        float bb = nt2 ? bv1 : bv0;
                        o4[rt][nt2][r] = o4[rt][nt2][r]*al
                                       + p*fmaxf(vacc[rt][nt2][r] + bb, 0.f);
                    }
                }
        }
    }
    __syncthreads();   // all sEn/sIn reads done; sOv overlays sIn region

    // ---- normalize, write ov as SPLIT bf16 (A-operand for final MFMA) ----
    {
        float rinv = 1.0f / sR;
#pragma unroll
        for (int rt = 0; rt < 2; ++rt)
#pragma unroll
            for (int r = 0; r < 4; ++r) {
                int row = rt*16 + qd*4 + r;
                float inv = __shfl(rinv, row);
#pragma unroll
                for (int nt2 = 0; nt2 < 2; ++nt2) {
                    float v = o4[rt][nt2][r]*inv;
                    int col = 32*w + nt2*16 + m;
                    unsigned short hh = f2bf(v);
                    sOvH[row*136 + col] = hh;
                    sOvL[row*136 + col] = f2bf(v - bf2f(hh));
                }
            }
    }
    __syncthreads();

    // ---- final (MFMA): x3a += ov @ w3_others; out = relu(x3a).Wout + bout
    {
#pragma unroll
        for (int kt = 0; kt < 4; ++kt) {
            bhalf8 ah0 = *(const bhalf8*)(sOvH + m*136      + kt*32 + qd*8);
            bhalf8 ah1 = *(const bhalf8*)(sOvH + (16+m)*136 + kt*32 + qd*8);
            bhalf8 al0 = *(const bhalf8*)(sOvL + m*136      + kt*32 + qd*8);
            bhalf8 al1 = *(const bhalf8*)(sOvL + (16+m)*136 + kt*32 + qd*8);
            const unsigned short* bp = w3of + ((w*4 + kt)*64 + l)*16;
            bhalf8 bh = *(const bhalf8*)(bp);
            bhalf8 bl = *(const bhalf8*)(bp + 8);
            x3a[0] = __builtin_amdgcn_mfma_f32_16x16x32_bf16(ah0, bh, x3a[0], 0, 0, 0);
            x3a[1] = __builtin_amdgcn_mfma_f32_16x16x32_bf16(ah1, bh, x3a[1], 0, 0, 0);
            x3a[0] = __builtin_amdgcn_mfma_f32_16x16x32_bf16(ah0, bl, x3a[0], 0, 0, 0);
            x3a[1] = __builtin_amdgcn_mfma_f32_16x16x32_bf16(ah1, bl, x3a[1], 0, 0, 0);
            x3a[0] = __builtin_amdgcn_mfma_f32_16x16x32_bf16(al0, bh, x3a[0], 0, 0, 0);
            x3a[1] = __builtin_amdgcn_mfma_f32_16x16x32_bf16(al1, bh, x3a[1], 0, 0, 0);
        }
        // lane holds x3[row=rt*16+qd*4+r][col=16w+m]; relu, *Wout, reduce m
        float wo = Wout[w*16 + m];
#pragma unroll
        for (int rt = 0; rt < 2; ++rt)
#pragma unroll
            for (int r = 0; r < 4; ++r) {
                float p = fmaxf(x3a[rt][r], 0.f) * wo;
                p += __shfl_xor(p, 1);
                p += __shfl_xor(p, 2);
                p += __shfl_xor(p, 4);
                p += __shfl_xor(p, 8);
                if (m == 0)
                    sRed[(rt*16 + qd*4 + r)*4 + w] = p;
            }
    }
    __syncthreads();
    if (t < 32)
        out[b0 + t] = sRed[t*4+0] + sRed[t*4+1] + sRed[t*4+2] + sRed[t*4+3]
                    + bout[0];
}

extern "C" void kernel_launch(void* const* d_in, const int* in_sizes, int n_in,
                              void* d_out, int out_size, void* d_ws, size_t ws_size,
                              hipStream_t stream) {
    (void)in_sizes; (void)n_in; (void)out_size; (void)ws_size;
    const float* state_one    = (const float*)d_in[0];
    const float* act_one      = (const float*)d_in[1];
    const float* state_others = (const float*)d_in[2];
    const float* act_others   = (const float*)d_in[3];
    const float* W1           = (const float*)d_in[4];
    const float* b1           = (const float*)d_in[5];
    const float* W2           = (const float*)d_in[6];
    const float* b2           = (const float*)d_in[7];
    const float* w3_self      = (const float*)d_in[8];
    const float* We           = (const float*)d_in[9];
    const float* be           = (const float*)d_in[10];
    const float* Wk           = (const float*)d_in[11];
    const float* Wq           = (const float*)d_in[12];
    const float* Wv           = (const float*)d_in[13];
    const float* bv           = (const float*)d_in[14];
    const float* w3_others    = (const float*)d_in[15];
    const float* Wout         = (const float*)d_in[16];
    const float* bout         = (const float*)d_in[17];
    float* out = (float*)d_out;

    unsigned short* Mf2  = (unsigned short*)d_ws;                    // 131072 B
    unsigned short* Wef2 = (unsigned short*)((char*)d_ws + 131072);  // 344064 B
    unsigned short* Wvf2 = (unsigned short*)((char*)d_ws + 475136);  // 65536 B
    unsigned short* W2f  = (unsigned short*)((char*)d_ws + 540672);  // 16384 B
    unsigned short* w3sf = (unsigned short*)((char*)d_ws + 557056);  // 16384 B
    unsigned short* w3of = (unsigned short*)((char*)d_ws + 573440);  // 32768 B
    unsigned short* W1f  = (unsigned short*)((char*)d_ws + 606208);  // 24576 B

    fold_M_frag<<<128, 256, 0, stream>>>(Wk, Wq, Mf2);
    conv_We<<<336, 256, 0, stream>>>(We, Wef2);
    conv_Wv<<<64, 256, 0, stream>>>(Wv, Wvf2);
    conv_self<<<88, 256, 0, stream>>>(W2, w3_self, w3_others, W1,
                                      W2f, w3sf, w3of, W1f);
    fused_critic<<<BTOT/TB, 256, 0, stream>>>(
        state_one, act_one, state_others, act_others,
        b1, b2, be, bv, Wout, bout,
        Mf2, Wef2, Wvf2, W2f, w3sf, w3of, W1f, out);
}

// Round 7
// 202.710 us; speedup vs baseline: 1.9569x; 1.0256x over previous
//
#include <hip/hip_runtime.h>
#include <hip/hip_bf16.h>

#define BTOT 32768
#define TB 32

typedef __attribute__((ext_vector_type(8))) short bhalf8;   // 8 bf16 = 4 VGPRs
typedef __attribute__((ext_vector_type(4))) float f32x4;    // MFMA acc

// R12: native cast (single v_cvt) instead of 5-op integer RNE.
static __device__ __forceinline__ unsigned short f2bf(float x) {
    __hip_bfloat16 h = __float2bfloat16(x);
    unsigned short u;
    __builtin_memcpy(&u, &h, sizeof(u));
    return u;
}
static __device__ __forceinline__ float bf2f(unsigned short s) {
    return __uint_as_float(((unsigned int)s) << 16);
}

// ---------------------------------------------------------------------------
// R15: ALL weight preprocessing merged into ONE kernel (prep_all).
// Rationale: every round showed ~100-117us of non-fused time = 4 tiny
// dispatches + their launch/drain bubbles (fused_critic itself is 91us).
// The four bodies are pure elementwise, disjoint-output, no LDS, no
// cross-block deps -> fusing them into one dispatch by blockIdx range is
// race-free by construction. (Distinct from the quarantined R5/R6 fusion,
// which entangled preprocess with the fused kernel's 2-pass t-phase; that
// nondeterminism was traced to un-barriered LDS dataflow, fixed in R8.)
//
// Fragment layout (unchanged): B-frag for (kt, nt): lane l holds
// B[k=kt*32+(l>>4)*8+j][n=nt*16+(l&15)], hi at ((nt*KT+kt)*64+l)*16+j, lo +8.
// ws: Mf2  @0       131072 B (M = Wq@Wk^T as [64 x 512], KT=2, NT=32)
//     Wef2 @131072  344064 B (per agent We[96 x 128], KT=3, NT=8)
//     Wvf2 @475136  65536 B  (Wv as [128 x 128], n=h*32+d, KT=4, NT=8)
//     W2f  @540672  16384 B  (W2 [64 x 64], KT=2, NT=4)
//     w3sf @557056  16384 B  (w3_self [64 x 64], KT=2, NT=4)
//     w3of @573440  32768 B  (w3_others [128 x 64], KT=4, NT=4)
//     W1f  @606208  24576 B  (W1 [96 x 64] pad k>=78, KT=3, NT=3... KT=3)
// R9/R11 lesson (twice): launch_bounds implying VGPR<120 collapses allocator
// to 64 VGPR -> ~500MB scratch spills. Never request >2 waves/EU for fused.
// R13/R14 lesson: scalar-GEMM VALU was the dominant removable in-kernel cost
// (155->91us); matrix pipe now at 25% of dense peak (3x split inflation).
// ---------------------------------------------------------------------------
__global__ __launch_bounds__(256) void prep_all(
        const float* __restrict__ Wk, const float* __restrict__ Wq,
        const float* __restrict__ We, const float* __restrict__ Wv,
        const float* __restrict__ W2, const float* __restrict__ w3_self,
        const float* __restrict__ w3_others, const float* __restrict__ W1,
        unsigned short* __restrict__ Mf2, unsigned short* __restrict__ Wef2,
        unsigned short* __restrict__ Wvf2, unsigned short* __restrict__ W2f,
        unsigned short* __restrict__ w3sf, unsigned short* __restrict__ w3of,
        unsigned short* __restrict__ W1f)
{
    const int blk = blockIdx.x;
    if (blk < 128) {
        // ---- fold M = Wq @ Wk^T -> Mf2 fragments (32768 threads) ----
        int tid = blk * 256 + threadIdx.x;
        int h  = tid >> 13;
        int jq = (tid >> 7) & 63;
        int j  = tid & 127;
        const float* q = Wq + (h*64 + jq)*32;
        const float* k = Wk + (h*128 + j)*32;
        float acc = 0.f;
#pragma unroll
        for (int d = 0; d < 32; d += 4) {
            float4 a = *(const float4*)(q + d);
            float4 b = *(const float4*)(k + d);
            acc += a.x*b.x + a.y*b.y + a.z*b.z + a.w*b.w;
        }
        unsigned short hi = f2bf(acc);
        unsigned short lo = f2bf(acc - bf2f(hi));
        int n  = h*128 + j;
        int kt = jq >> 5, qd = (jq >> 3) & 3, jj = jq & 7;
        int nt = n >> 4,  ln = n & 15;
        size_t base = (((nt*2 + kt)*64) + qd*16 + ln)*16;
        Mf2[base + jj]     = hi;
        Mf2[base + 8 + jj] = lo;
    } else if (blk < 464) {
        // ---- conv We (7*96*128 = 86016 threads) ----
        int tid = (blk - 128) * 256 + threadIdx.x;
        int a = tid / 12288;
        int r = tid - a*12288;
        int k = r >> 7;          // 0..95
        int n = r & 127;
        float v = (k < 82) ? We[((size_t)a*82 + k)*128 + n] : 0.f;
        unsigned short hi = f2bf(v);
        unsigned short lo = f2bf(v - bf2f(hi));
        int kt = k >> 5, qd = (k >> 3) & 3, j = k & 7;
        int nt = n >> 4, ln = n & 15;
        size_t base = (size_t)a*24576 + (((nt*3 + kt)*64) + qd*16 + ln)*16;
        Wef2[base + j]     = hi;
        Wef2[base + 8 + j] = lo;
    } else if (blk < 528) {
        // ---- conv Wv (4*128*32 = 16384 threads) ----
        int tid = (blk - 464) * 256 + threadIdx.x;
        int h = tid >> 12;
        int j = (tid >> 5) & 127;
        int d = tid & 31;
        float v = Wv[tid];
        unsigned short hi = f2bf(v);
        unsigned short lo = f2bf(v - bf2f(hi));
        int k = j, n = h*32 + d;
        int kt = k >> 5, qd = (k >> 3) & 3, jj = k & 7;
        int nt = n >> 4, ln = n & 15;
        size_t base = (((nt*4 + kt)*64) + qd*16 + ln)*16;
        Wvf2[base + jj]     = hi;
        Wvf2[base + 8 + jj] = lo;
    } else {
        // ---- conv self weights (22528 threads) ----
        int tid = (blk - 528) * 256 + threadIdx.x;
        const float* src;
        unsigned short* dst;
        int idx, KT, kmax;
        if (tid < 4096)       { src = W2;        dst = W2f;  idx = tid;         KT = 2; kmax = 64; }
        else if (tid < 8192)  { src = w3_self;   dst = w3sf; idx = tid - 4096;  KT = 2; kmax = 64; }
        else if (tid < 16384) { src = w3_others; dst = w3of; idx = tid - 8192;  KT = 4; kmax = 128; }
        else                  { src = W1;        dst = W1f;  idx = tid - 16384; KT = 3; kmax = 78; }
        int k = idx >> 6;
        int n = idx & 63;
        float v = (k < kmax) ? src[k*64 + n] : 0.f;
        unsigned short hi = f2bf(v);
        unsigned short lo = f2bf(v - bf2f(hi));
        int kt = k >> 5, qd = (k >> 3) & 3, j = k & 7;
        int nt = n >> 4, ln = n & 15;
        size_t base = (((nt*KT + kt)*64) + qd*16 + ln)*16;
        dst[base + j]     = hi;
        dst[base + 8 + j] = lo;
    }
}

// ---------------------------------------------------------------------------
// Fused critic. TB=32 rows/block, 256 threads (4 waves), 1024 blocks.
// R14 structure (unchanged in R15):
//   * phases 1/2/3/final MFMA-ized (split-bf16 3-term, ~f32 accuracy)
//   * logits via MFMA DIAGONAL fused into the vals kt-loop (tB0/tB1 B-frag
//     registers; logit row n = C[n][n] -> lane ((n>>2)<<4)|n, reg n&3;
//     extraction 6 cndmask + 2 shfl + 1 cndmask; stats registers+shfl only)
//   * agent loop double-buffered, ONE barrier per agent (R12)
// LDS 61440 B:
//   self : sXbH[32x104]@0, sXbL@6656; sX1bH[32x72]@13312, sX1bL@17920;
//          sX2bH@22528, sX2bL@27136 (ends 31744)
//   t    : sT bf16[32x520]@0..33280 (overlays self; written only after the
//          internal barrier that ends all sXb/sX1b/sX2b reads)
//   agent: sIn buf k: H@k*13312, L@+6656 (ends 26624)
//          sEn buf k: H@26624+k*17408, L@+8704 (ends 61440)
//   final: sOvH bf16[32x136]@0, sOvL@8704, sRed f32[32x4]@17408
// Every LDS producer->consumer crosses exactly one __syncthreads.
// ---------------------------------------------------------------------------
__global__ __launch_bounds__(256, 2) void fused_critic(
    const float* __restrict__ state_one, const float* __restrict__ act_one,
    const float* __restrict__ state_others, const float* __restrict__ act_others,
    const float* __restrict__ b1, const float* __restrict__ b2,
    const float* __restrict__ be, const float* __restrict__ bvp,
    const float* __restrict__ Wout, const float* __restrict__ bout,
    const unsigned short* __restrict__ Mf2, const unsigned short* __restrict__ Wef2,
    const unsigned short* __restrict__ Wvf2, const unsigned short* __restrict__ W2f,
    const unsigned short* __restrict__ w3sf, const unsigned short* __restrict__ w3of,
    const unsigned short* __restrict__ W1f, float* __restrict__ out)
{
    __shared__ __align__(16) unsigned char smem[61440];
    unsigned short* sXbH  = (unsigned short*)smem;           // stride 104
    unsigned short* sXbL  = (unsigned short*)(smem + 6656);  // stride 104
    unsigned short* sX1bH = (unsigned short*)(smem + 13312); // stride 72
    unsigned short* sX1bL = (unsigned short*)(smem + 17920); // stride 72
    unsigned short* sX2bH = (unsigned short*)(smem + 22528); // stride 72
    unsigned short* sX2bL = (unsigned short*)(smem + 27136); // stride 72
    unsigned short* sT    = (unsigned short*)smem;           // stride 520
    unsigned short* sOvH  = (unsigned short*)smem;           // stride 136
    unsigned short* sOvL  = (unsigned short*)(smem + 8704);  // stride 136
    float*          sRed  = (float*)(smem + 17408);          // [32][4]

    const int t  = threadIdx.x;
    const int b0 = blockIdx.x * TB;
    const int w  = t >> 6;        // wave = head / self-col-tile
    const int l  = t & 63;
    const int m  = l & 15;        // MFMA A row / C col
    const int qd = l >> 4;        // quad

    const int act_r = t >> 3, act_c = t & 7;

    // staging helper: split-bf16 convert regs -> given sIn buffer (cols 0..81)
    auto stageIn = [&](unsigned short* dH, unsigned short* dL,
                       const float4& vA, const float4& vB, const float* av) {
        const int r0 = t >> 4, c4 = (t & 15) << 2;
        ushort4 h4, l4;
        h4.x = f2bf(vA.x); l4.x = f2bf(vA.x - bf2f(h4.x));
        h4.y = f2bf(vA.y); l4.y = f2bf(vA.y - bf2f(h4.y));
        h4.z = f2bf(vA.z); l4.z = f2bf(vA.z - bf2f(h4.z));
        h4.w = f2bf(vA.w); l4.w = f2bf(vA.w - bf2f(h4.w));
        *(ushort4*)(dH + r0*104 + c4) = h4;
        *(ushort4*)(dL + r0*104 + c4) = l4;
        h4.x = f2bf(vB.x); l4.x = f2bf(vB.x - bf2f(h4.x));
        h4.y = f2bf(vB.y); l4.y = f2bf(vB.y - bf2f(h4.y));
        h4.z = f2bf(vB.z); l4.z = f2bf(vB.z - bf2f(h4.z));
        h4.w = f2bf(vB.w); l4.w = f2bf(vB.w - bf2f(h4.w));
        *(ushort4*)(dH + (r0+16)*104 + c4) = h4;
        *(ushort4*)(dL + (r0+16)*104 + c4) = l4;
        if (act_c < 6) {
#pragma unroll
            for (int e = 0; e < 3; ++e) {
                float v = av[e];
                unsigned short hh = f2bf(v);
                dH[act_r*104 + 64 + act_c*3 + e] = hh;
                dL[act_r*104 + 64 + act_c*3 + e] = f2bf(v - bf2f(hh));
            }
        }
    };

    // ---- stage self input [32 x 96] split bf16 (cols 78..95 zero) ----
    {
        const int r0 = t >> 4, c4 = (t & 15) << 2;
        float4 vA = *(const float4*)(state_one + (size_t)(b0 + r0)*64 + c4);
        float4 vB = *(const float4*)(state_one + (size_t)(b0 + r0 + 16)*64 + c4);
        ushort4 h4, l4;
        h4.x = f2bf(vA.x); l4.x = f2bf(vA.x - bf2f(h4.x));
        h4.y = f2bf(vA.y); l4.y = f2bf(vA.y - bf2f(h4.y));
        h4.z = f2bf(vA.z); l4.z = f2bf(vA.z - bf2f(h4.z));
        h4.w = f2bf(vA.w); l4.w = f2bf(vA.w - bf2f(h4.w));
        *(ushort4*)(sXbH + r0*104 + c4) = h4;
        *(ushort4*)(sXbL + r0*104 + c4) = l4;
        h4.x = f2bf(vB.x); l4.x = f2bf(vB.x - bf2f(h4.x));
        h4.y = f2bf(vB.y); l4.y = f2bf(vB.y - bf2f(h4.y));
        h4.z = f2bf(vB.z); l4.z = f2bf(vB.z - bf2f(h4.z));
        h4.w = f2bf(vB.w); l4.w = f2bf(vB.w - bf2f(h4.w));
        *(ushort4*)(sXbH + (r0+16)*104 + c4) = h4;
        *(ushort4*)(sXbL + (r0+16)*104 + c4) = l4;
        // act cols 64..79 (78,79 zero)
#pragma unroll
        for (int e = 0; e < 2; ++e) {
            int cc = act_c*2 + e;
            float v = (cc < 14) ? act_one[(size_t)(b0 + act_r)*14 + cc] : 0.f;
            unsigned short hh = f2bf(v);
            sXbH[act_r*104 + 64 + cc] = hh;
            sXbL[act_r*104 + 64 + cc] = f2bf(v - bf2f(hh));
        }
        // pad cols 80..95
        for (int f = t; f < TB*16; f += 256) {
            int r = f >> 4, c = 80 + (f & 15);
            sXbH[r*104 + c] = 0;
            sXbL[r*104 + c] = 0;
        }
    }
    __syncthreads();

    // ---- phase 1 (MFMA): x1 = relu(x @ W1 + b1) -> split bf16 LDS ----
    {
        f32x4 acc1[2] = {};
#pragma unroll
        for (int kt = 0; kt < 3; ++kt) {
            bhalf8 ah0 = *(const bhalf8*)(sXbH + m*104      + kt*32 + qd*8);
            bhalf8 ah1 = *(const bhalf8*)(sXbH + (16+m)*104 + kt*32 + qd*8);
            bhalf8 al0 = *(const bhalf8*)(sXbL + m*104      + kt*32 + qd*8);
            bhalf8 al1 = *(const bhalf8*)(sXbL + (16+m)*104 + kt*32 + qd*8);
            const unsigned short* bp = W1f + ((w*3 + kt)*64 + l)*16;
            bhalf8 bh = *(const bhalf8*)(bp);
            bhalf8 bl = *(const bhalf8*)(bp + 8);
            acc1[0] = __builtin_amdgcn_mfma_f32_16x16x32_bf16(ah0, bh, acc1[0], 0, 0, 0);
            acc1[1] = __builtin_amdgcn_mfma_f32_16x16x32_bf16(ah1, bh, acc1[1], 0, 0, 0);
            acc1[0] = __builtin_amdgcn_mfma_f32_16x16x32_bf16(ah0, bl, acc1[0], 0, 0, 0);
            acc1[1] = __builtin_amdgcn_mfma_f32_16x16x32_bf16(ah1, bl, acc1[1], 0, 0, 0);
            acc1[0] = __builtin_amdgcn_mfma_f32_16x16x32_bf16(al0, bh, acc1[0], 0, 0, 0);
            acc1[1] = __builtin_amdgcn_mfma_f32_16x16x32_bf16(al1, bh, acc1[1], 0, 0, 0);
        }
        int col = w*16 + m;
        float b1c = b1[col];
#pragma unroll
        for (int rt = 0; rt < 2; ++rt)
#pragma unroll
            for (int r = 0; r < 4; ++r) {
                float e = fmaxf(acc1[rt][r] + b1c, 0.f);
                int row = rt*16 + qd*4 + r;
                unsigned short hh = f2bf(e);
                sX1bH[row*72 + col] = hh;
                sX1bL[row*72 + col] = f2bf(e - bf2f(hh));
            }
    }
    __syncthreads();

    // ---- phase 2 (MFMA): x2 = relu(x1 @ W2 + b2) -> split bf16 LDS ----
    {
        f32x4 acc2[2] = {};
#pragma unroll
        for (int kt = 0; kt < 2; ++kt) {
            bhalf8 ah0 = *(const bhalf8*)(sX1bH + m*72      + kt*32 + qd*8);
            bhalf8 ah1 = *(const bhalf8*)(sX1bH + (16+m)*72 + kt*32 + qd*8);
            bhalf8 al0 = *(const bhalf8*)(sX1bL + m*72      + kt*32 + qd*8);
            bhalf8 al1 = *(const bhalf8*)(sX1bL + (16+m)*72 + kt*32 + qd*8);
            const unsigned short* bp = W2f + ((w*2 + kt)*64 + l)*16;
            bhalf8 bh = *(const bhalf8*)(bp);
            bhalf8 bl = *(const bhalf8*)(bp + 8);
            acc2[0] = __builtin_amdgcn_mfma_f32_16x16x32_bf16(ah0, bh, acc2[0], 0, 0, 0);
            acc2[1] = __builtin_amdgcn_mfma_f32_16x16x32_bf16(ah1, bh, acc2[1], 0, 0, 0);
            acc2[0] = __builtin_amdgcn_mfma_f32_16x16x32_bf16(ah0, bl, acc2[0], 0, 0, 0);
            acc2[1] = __builtin_amdgcn_mfma_f32_16x16x32_bf16(ah1, bl, acc2[1], 0, 0, 0);
            acc2[0] = __builtin_amdgcn_mfma_f32_16x16x32_bf16(al0, bh, acc2[0], 0, 0, 0);
            acc2[1] = __builtin_amdgcn_mfma_f32_16x16x32_bf16(al1, bh, acc2[1], 0, 0, 0);
        }
        int col = w*16 + m;
        float b2c = b2[col];
#pragma unroll
        for (int rt = 0; rt < 2; ++rt)
#pragma unroll
            for (int r = 0; r < 4; ++r) {
                float e = fmaxf(acc2[rt][r] + b2c, 0.f);
                int row = rt*16 + qd*4 + r;
                unsigned short hh = f2bf(e);
                sX2bH[row*72 + col] = hh;
                sX2bL[row*72 + col] = f2bf(e - bf2f(hh));
            }
    }
    __syncthreads();

    // ---- phase 3 (MFMA): x3a = x2 @ w3_self, kept in registers ----
    f32x4 x3a[2] = {};
    {
#pragma unroll
        for (int kt = 0; kt < 2; ++kt) {
            bhalf8 ah0 = *(const bhalf8*)(sX2bH + m*72      + kt*32 + qd*8);
            bhalf8 ah1 = *(const bhalf8*)(sX2bH + (16+m)*72 + kt*32 + qd*8);
            bhalf8 al0 = *(const bhalf8*)(sX2bL + m*72      + kt*32 + qd*8);
            bhalf8 al1 = *(const bhalf8*)(sX2bL + (16+m)*72 + kt*32 + qd*8);
            const unsigned short* bp = w3sf + ((w*2 + kt)*64 + l)*16;
            bhalf8 bh = *(const bhalf8*)(bp);
            bhalf8 bl = *(const bhalf8*)(bp + 8);
            x3a[0] = __builtin_amdgcn_mfma_f32_16x16x32_bf16(ah0, bh, x3a[0], 0, 0, 0);
            x3a[1] = __builtin_amdgcn_mfma_f32_16x16x32_bf16(ah1, bh, x3a[1], 0, 0, 0);
            x3a[0] = __builtin_amdgcn_mfma_f32_16x16x32_bf16(ah0, bl, x3a[0], 0, 0, 0);
            x3a[1] = __builtin_amdgcn_mfma_f32_16x16x32_bf16(ah1, bl, x3a[1], 0, 0, 0);
            x3a[0] = __builtin_amdgcn_mfma_f32_16x16x32_bf16(al0, bh, x3a[0], 0, 0, 0);
            x3a[1] = __builtin_amdgcn_mfma_f32_16x16x32_bf16(al1, bh, x3a[1], 0, 0, 0);
        }
    }

    // ---- phase 4: t = x1 @ M, split 3-term MFMA, -> sT bf16 ----
    {
        f32x4 tacc[2][8] = {};
#pragma unroll
        for (int kt = 0; kt < 2; ++kt) {
            bhalf8 ah0 = *(const bhalf8*)(sX1bH + m*72      + kt*32 + qd*8);
            bhalf8 ah1 = *(const bhalf8*)(sX1bH + (16+m)*72 + kt*32 + qd*8);
            bhalf8 al0 = *(const bhalf8*)(sX1bL + m*72      + kt*32 + qd*8);
            bhalf8 al1 = *(const bhalf8*)(sX1bL + (16+m)*72 + kt*32 + qd*8);
#pragma unroll
            for (int nt2 = 0; nt2 < 8; ++nt2) {
                int nt = w*8 + nt2;
                const unsigned short* bp = Mf2 + ((nt*2 + kt)*64 + l)*16;
                bhalf8 bh = *(const bhalf8*)(bp);
                bhalf8 bl = *(const bhalf8*)(bp + 8);
                tacc[0][nt2] = __builtin_amdgcn_mfma_f32_16x16x32_bf16(ah0, bh, tacc[0][nt2], 0, 0, 0);
                tacc[1][nt2] = __builtin_amdgcn_mfma_f32_16x16x32_bf16(ah1, bh, tacc[1][nt2], 0, 0, 0);
                tacc[0][nt2] = __builtin_amdgcn_mfma_f32_16x16x32_bf16(ah0, bl, tacc[0][nt2], 0, 0, 0);
                tacc[1][nt2] = __builtin_amdgcn_mfma_f32_16x16x32_bf16(ah1, bl, tacc[1][nt2], 0, 0, 0);
                tacc[0][nt2] = __builtin_amdgcn_mfma_f32_16x16x32_bf16(al0, bh, tacc[0][nt2], 0, 0, 0);
                tacc[1][nt2] = __builtin_amdgcn_mfma_f32_16x16x32_bf16(al1, bh, tacc[1][nt2], 0, 0, 0);
            }
        }
        __syncthreads();   // ALL reads of sXb/sX1b/sX2b done before sT overlays
#pragma unroll
        for (int rt = 0; rt < 2; ++rt)
#pragma unroll
            for (int nt2 = 0; nt2 < 8; ++nt2)
#pragma unroll
                for (int r = 0; r < 4; ++r)
                    sT[(rt*16 + qd*4 + r)*520 + w*128 + nt2*16 + m] =
                        f2bf(tacc[rt][nt2][r]);
    }
    __syncthreads();

    // ---- load t as B-FRAGMENT registers (logits MFMA), rows m / 16+m ----
    bhalf8 tB0[4], tB1[4];
    {
#pragma unroll
        for (int kt = 0; kt < 4; ++kt) {
            tB0[kt] = *(const bhalf8*)(sT + m*520      + w*128 + kt*32 + qd*8);
            tB1[kt] = *(const bhalf8*)(sT + (16+m)*520 + w*128 + kt*32 + qd*8);
        }
    }
    __syncthreads();   // sT region free for sIn buffers

    // zero-pad cols 82..95 of BOTH sIn buffers once
    for (int f = t; f < TB*16; f += 256) {
        int r = f >> 4, c = f & 15;
        if (c >= 2) {
#pragma unroll
            for (int k = 0; k < 2; ++k) {
                unsigned short* dH = (unsigned short*)(smem + k*13312);
                unsigned short* dL = (unsigned short*)(smem + k*13312 + 6656);
                dH[r*104 + 80 + c] = 0;
                dL[r*104 + 80 + c] = 0;
            }
        }
    }
    // stage agent 0 directly into buffer 0
    {
        const float* sa = state_others + (size_t)b0 * 64;
        float4 vA = *(const float4*)(sa + t*4);
        float4 vB = *(const float4*)(sa + t*4 + 1024);
        float av[3] = {0.f, 0.f, 0.f};
        if (act_c < 6) {
            const float* aa = act_others + (size_t)(b0 + act_r)*18 + act_c*3;
            av[0] = aa[0]; av[1] = aa[1]; av[2] = aa[2];
        }
        stageIn((unsigned short*)smem, (unsigned short*)(smem + 6656),
                vA, vB, av);
    }
    __syncthreads();   // sIn buf0 (agent 0) ready

    const float bv0 = bvp[w*32 + m];
    const float bv1 = bvp[w*32 + 16 + m];
    f32x4 o4[2][2] = {};
    float mR = -1e30f, sR = 0.f;

    // diag extraction constants: logit row b_l sits in lane src, lacc[b_l>>4]
    const int nsel = l & 15;
    const int srcl = ((nsel >> 2) << 4) | nsel;

    float4 pfA, pfB; float pfa[3] = {0.f, 0.f, 0.f};

    for (int a = 0; a < 7; ++a) {
        unsigned short* sInHc = (unsigned short*)(smem + (a&1)*13312);
        unsigned short* sInLc = (unsigned short*)(smem + (a&1)*13312 + 6656);
        unsigned short* sEnHc = (unsigned short*)(smem + 26624 + (a&1)*17408);
        unsigned short* sEnLc = (unsigned short*)(smem + 26624 + (a&1)*17408 + 8704);
        unsigned short* sInHn = (unsigned short*)(smem + ((a+1)&1)*13312);
        unsigned short* sInLn = (unsigned short*)(smem + ((a+1)&1)*13312 + 6656);

        // ---- issue next agent's HBM loads (regs); hides under enc/vals ----
        if (a < 6) {
            const float* sa = state_others + ((size_t)(a+1)*BTOT + b0)*64;
            pfA = *(const float4*)(sa + t*4);
            pfB = *(const float4*)(sa + t*4 + 1024);
            if (act_c < 6) {
                const float* aa = act_others
                    + ((size_t)(a+1)*BTOT + b0 + act_r)*18 + act_c*3;
                pfa[0] = aa[0]; pfa[1] = aa[1]; pfa[2] = aa[2];
            }
        }
        float be0 = be[a*128 + 32*w + m];
        float be1 = be[a*128 + 32*w + 16 + m];

        // ---- enc(a) = inp @ We_a, split 3-term, wave slice 32 cols ----
        f32x4 eacc[2][2] = {};
#pragma unroll
        for (int kt = 0; kt < 3; ++kt) {
            bhalf8 ah0 = *(const bhalf8*)(sInHc + m*104      + kt*32 + qd*8);
            bhalf8 ah1 = *(const bhalf8*)(sInHc + (16+m)*104 + kt*32 + qd*8);
            bhalf8 al0 = *(const bhalf8*)(sInLc + m*104      + kt*32 + qd*8);
            bhalf8 al1 = *(const bhalf8*)(sInLc + (16+m)*104 + kt*32 + qd*8);
#pragma unroll
            for (int nt2 = 0; nt2 < 2; ++nt2) {
                int nt = 2*w + nt2;
                const unsigned short* bp =
                    Wef2 + (size_t)a*24576 + ((nt*3 + kt)*64 + l)*16;
                bhalf8 bh = *(const bhalf8*)(bp);
                bhalf8 bl = *(const bhalf8*)(bp + 8);
                eacc[0][nt2] = __builtin_amdgcn_mfma_f32_16x16x32_bf16(ah0, bh, eacc[0][nt2], 0, 0, 0);
                eacc[1][nt2] = __builtin_amdgcn_mfma_f32_16x16x32_bf16(ah1, bh, eacc[1][nt2], 0, 0, 0);
                eacc[0][nt2] = __builtin_amdgcn_mfma_f32_16x16x32_bf16(ah0, bl, eacc[0][nt2], 0, 0, 0);
                eacc[1][nt2] = __builtin_amdgcn_mfma_f32_16x16x32_bf16(ah1, bl, eacc[1][nt2], 0, 0, 0);
                eacc[0][nt2] = __builtin_amdgcn_mfma_f32_16x16x32_bf16(al0, bh, eacc[0][nt2], 0, 0, 0);
                eacc[1][nt2] = __builtin_amdgcn_mfma_f32_16x16x32_bf16(al1, bh, eacc[1][nt2], 0, 0, 0);
            }
        }

        // ---- write sEn(a) (relu+bias, split) ----
        {
#pragma unroll
            for (int rt = 0; rt < 2; ++rt)
#pragma unroll
                for (int nt2 = 0; nt2 < 2; ++nt2) {
                    float bb = nt2 ? be1 : be0;
#pragma unroll
                    for (int r = 0; r < 4; ++r) {
                        float e = fmaxf(eacc[rt][nt2][r] + bb, 0.f);
                        int row = rt*16 + qd*4 + r;
                        int col = 32*w + nt2*16 + m;
                        unsigned short hh = f2bf(e);
                        sEnHc[row*136 + col] = hh;
                        sEnLc[row*136 + col] = f2bf(e - bf2f(hh));
                    }
                }
        }
        if (a < 6) stageIn(sInHn, sInLn, pfA, pfB, pfa);

        // ---- THE barrier: sEn(a) and sIn(a+1) visible to all waves ----
        __syncthreads();

        // ---- fused vals + logits MFMA loop (shared A-fragments) ----
        f32x4 vacc[2][2] = {};
        f32x4 lacc0 = {}, lacc1 = {};
#pragma unroll
        for (int kt = 0; kt < 4; ++kt) {
            bhalf8 ah0 = *(const bhalf8*)(sEnHc + m*136      + kt*32 + qd*8);
            bhalf8 ah1 = *(const bhalf8*)(sEnHc + (16+m)*136 + kt*32 + qd*8);
            bhalf8 al0 = *(const bhalf8*)(sEnLc + m*136      + kt*32 + qd*8);
            bhalf8 al1 = *(const bhalf8*)(sEnLc + (16+m)*136 + kt*32 + qd*8);
#pragma unroll
            for (int nt2 = 0; nt2 < 2; ++nt2) {
                int nt = 2*w + nt2;
                const unsigned short* bp = Wvf2 + ((nt*4 + kt)*64 + l)*16;
                bhalf8 bh = *(const bhalf8*)(bp);
                bhalf8 bl = *(const bhalf8*)(bp + 8);
                vacc[0][nt2] = __builtin_amdgcn_mfma_f32_16x16x32_bf16(ah0, bh, vacc[0][nt2], 0, 0, 0);
                vacc[1][nt2] = __builtin_amdgcn_mfma_f32_16x16x32_bf16(ah1, bh, vacc[1][nt2], 0, 0, 0);
                vacc[0][nt2] = __builtin_amdgcn_mfma_f32_16x16x32_bf16(ah0, bl, vacc[0][nt2], 0, 0, 0);
                vacc[1][nt2] = __builtin_amdgcn_mfma_f32_16x16x32_bf16(ah1, bl, vacc[1][nt2], 0, 0, 0);
                vacc[0][nt2] = __builtin_amdgcn_mfma_f32_16x16x32_bf16(al0, bh, vacc[0][nt2], 0, 0, 0);
                vacc[1][nt2] = __builtin_amdgcn_mfma_f32_16x16x32_bf16(al1, bh, vacc[1][nt2], 0, 0, 0);
            }
            // logits diag: C[r][n] = enc_rows @ t_rows^T (B-frag from regs)
            lacc0 = __builtin_amdgcn_mfma_f32_16x16x32_bf16(ah0, tB0[kt], lacc0, 0, 0, 0);
            lacc0 = __builtin_amdgcn_mfma_f32_16x16x32_bf16(al0, tB0[kt], lacc0, 0, 0, 0);
            lacc1 = __builtin_amdgcn_mfma_f32_16x16x32_bf16(ah1, tB1[kt], lacc1, 0, 0, 0);
            lacc1 = __builtin_amdgcn_mfma_f32_16x16x32_bf16(al1, tB1[kt], lacc1, 0, 0, 0);
        }

        // ---- extract diag -> stats (registers + wave-collective only) ----
        float alpha, pp;
        {
            float e01 = (l & 1) ? lacc0[1] : lacc0[0];
            float e23 = (l & 1) ? lacc0[3] : lacc0[2];
            float d0  = (l & 2) ? e23 : e01;
            float f01 = (l & 1) ? lacc1[1] : lacc1[0];
            float f23 = (l & 1) ? lacc1[3] : lacc1[2];
            float d1  = (l & 2) ? f23 : f01;
            float g0 = __shfl(d0, srcl);
            float g1 = __shfl(d1, srcl);
            float part = (l & 16) ? g1 : g0;
            float lg = part * 0.17677669529663687f;   // 1/sqrt(32)
            float mn = fmaxf(mR, lg);
            alpha = __expf(mR - mn);
            pp    = __expf(lg - mn);
            sR = sR*alpha + pp;
            mR = mn;
        }

        // ---- online accumulate o4 ----
        {
#pragma unroll
            for (int rt = 0; rt < 2; ++rt)
#pragma unroll
                for (int r = 0; r < 4; ++r) {
                    int row = rt*16 + qd*4 + r;
                    float al = __shfl(alpha, row);
                    float p  = __shfl(pp, row);
#pragma unroll
                    for (int nt2 = 0; nt2 < 2; ++nt2) {
                        float bb = nt2 ? bv1 : bv0;
                        o4[rt][nt2][r] = o4[rt][nt2][r]*al
                                       + p*fmaxf(vacc[rt][nt2][r] + bb, 0.f);
                    }
                }
        }
    }
    __syncthreads();   // all sEn/sIn reads done; sOv overlays sIn region

    // ---- normalize, write ov as SPLIT bf16 (A-operand for final MFMA) ----
    {
        float rinv = 1.0f / sR;
#pragma unroll
        for (int rt = 0; rt < 2; ++rt)
#pragma unroll
            for (int r = 0; r < 4; ++r) {
                int row = rt*16 + qd*4 + r;
                float inv = __shfl(rinv, row);
#pragma unroll
                for (int nt2 = 0; nt2 < 2; ++nt2) {
                    float v = o4[rt][nt2][r]*inv;
                    int col = 32*w + nt2*16 + m;
                    unsigned short hh = f2bf(v);
                    sOvH[row*136 + col] = hh;
                    sOvL[row*136 + col] = f2bf(v - bf2f(hh));
                }
            }
    }
    __syncthreads();

    // ---- final (MFMA): x3a += ov @ w3_others; out = relu(x3a).Wout + bout
    {
#pragma unroll
        for (int kt = 0; kt < 4; ++kt) {
            bhalf8 ah0 = *(const bhalf8*)(sOvH + m*136      + kt*32 + qd*8);
            bhalf8 ah1 = *(const bhalf8*)(sOvH + (16+m)*136 + kt*32 + qd*8);
            bhalf8 al0 = *(const bhalf8*)(sOvL + m*136      + kt*32 + qd*8);
            bhalf8 al1 = *(const bhalf8*)(sOvL + (16+m)*136 + kt*32 + qd*8);
            const unsigned short* bp = w3of + ((w*4 + kt)*64 + l)*16;
            bhalf8 bh = *(const bhalf8*)(bp);
            bhalf8 bl = *(const bhalf8*)(bp + 8);
            x3a[0] = __builtin_amdgcn_mfma_f32_16x16x32_bf16(ah0, bh, x3a[0], 0, 0, 0);
            x3a[1] = __builtin_amdgcn_mfma_f32_16x16x32_bf16(ah1, bh, x3a[1], 0, 0, 0);
            x3a[0] = __builtin_amdgcn_mfma_f32_16x16x32_bf16(ah0, bl, x3a[0], 0, 0, 0);
            x3a[1] = __builtin_amdgcn_mfma_f32_16x16x32_bf16(ah1, bl, x3a[1], 0, 0, 0);
            x3a[0] = __builtin_amdgcn_mfma_f32_16x16x32_bf16(al0, bh, x3a[0], 0, 0, 0);
            x3a[1] = __builtin_amdgcn_mfma_f32_16x16x32_bf16(al1, bh, x3a[1], 0, 0, 0);
        }
        // lane holds x3[row=rt*16+qd*4+r][col=16w+m]; relu, *Wout, reduce m
        float wo = Wout[w*16 + m];
#pragma unroll
        for (int rt = 0; rt < 2; ++rt)
#pragma unroll
            for (int r = 0; r < 4; ++r) {
                float p = fmaxf(x3a[rt][r], 0.f) * wo;
                p += __shfl_xor(p, 1);
                p += __shfl_xor(p, 2);
                p += __shfl_xor(p, 4);
                p += __shfl_xor(p, 8);
                if (m == 0)
                    sRed[(rt*16 + qd*4 + r)*4 + w] = p;
            }
    }
    __syncthreads();
    if (t < 32)
        out[b0 + t] = sRed[t*4+0] + sRed[t*4+1] + sRed[t*4+2] + sRed[t*4+3]
                    + bout[0];
}

extern "C" void kernel_launch(void* const* d_in, const int* in_sizes, int n_in,
                              void* d_out, int out_size, void* d_ws, size_t ws_size,
                              hipStream_t stream) {
    (void)in_sizes; (void)n_in; (void)out_size; (void)ws_size;
    const float* state_one    = (const float*)d_in[0];
    const float* act_one      = (const float*)d_in[1];
    const float* state_others = (const float*)d_in[2];
    const float* act_others   = (const float*)d_in[3];
    const float* W1           = (const float*)d_in[4];
    const float* b1           = (const float*)d_in[5];
    const float* W2           = (const float*)d_in[6];
    const float* b2           = (const float*)d_in[7];
    const float* w3_self      = (const float*)d_in[8];
    const float* We           = (const float*)d_in[9];
    const float* be           = (const float*)d_in[10];
    const float* Wk           = (const float*)d_in[11];
    const float* Wq           = (const float*)d_in[12];
    const float* Wv           = (const float*)d_in[13];
    const float* bv           = (const float*)d_in[14];
    const float* w3_others    = (const float*)d_in[15];
    const float* Wout         = (const float*)d_in[16];
    const float* bout         = (const float*)d_in[17];
    float* out = (float*)d_out;

    unsigned short* Mf2  = (unsigned short*)d_ws;                    // 131072 B
    unsigned short* Wef2 = (unsigned short*)((char*)d_ws + 131072);  // 344064 B
    unsigned short* Wvf2 = (unsigned short*)((char*)d_ws + 475136);  // 65536 B
    unsigned short* W2f  = (unsigned short*)((char*)d_ws + 540672);  // 16384 B
    unsigned short* w3sf = (unsigned short*)((char*)d_ws + 557056);  // 16384 B
    unsigned short* w3of = (unsigned short*)((char*)d_ws + 573440);  // 32768 B
    unsigned short* W1f  = (unsigned short*)((char*)d_ws + 606208);  // 24576 B

    prep_all<<<616, 256, 0, stream>>>(Wk, Wq, We, Wv, W2, w3_self, w3_others,
                                      W1, Mf2, Wef2, Wvf2, W2f, w3sf, w3of, W1f);
    fused_critic<<<BTOT/TB, 256, 0, stream>>>(
        state_one, act_one, state_others, act_others,
        b1, b2, be, bv, Wout, bout,
        Mf2, Wef2, Wvf2, W2f, w3sf, w3of, W1f, out);
}

// Round 8
// 199.053 us; speedup vs baseline: 1.9929x; 1.0184x over previous
//
#include <hip/hip_runtime.h>
#include <hip/hip_bf16.h>

#define BTOT 32768
#define TB 32

typedef __attribute__((ext_vector_type(8))) short bhalf8;   // 8 bf16 = 4 VGPRs
typedef __attribute__((ext_vector_type(4))) float f32x4;    // MFMA acc

// R12: native cast (single v_cvt) instead of 5-op integer RNE.
static __device__ __forceinline__ unsigned short f2bf(float x) {
    __hip_bfloat16 h = __float2bfloat16(x);
    unsigned short u;
    __builtin_memcpy(&u, &h, sizeof(u));
    return u;
}
static __device__ __forceinline__ float bf2f(unsigned short s) {
    return __uint_as_float(((unsigned int)s) << 16);
}

// ---------------------------------------------------------------------------
// R15: ALL weight preprocessing in ONE kernel (prep_all); saved ~26us of
// launch bubbles (overhead 117->91us). R15 also showed cross-session clock
// variance of +/-20% on identical code — judge rounds by within-session
// counters (Occupancy, conflicts), not cross-session dur.
//
// Fragment layout: B-frag for (kt, nt): lane l holds
// B[k=kt*32+(l>>4)*8+j][n=nt*16+(l&15)], hi at ((nt*KT+kt)*64+l)*16+j, lo +8.
// ws: Mf2  @0       131072 B (M = Wq@Wk^T as [64 x 512], KT=2, NT=32)
//     Wef2 @131072  344064 B (per agent We[96 x 128], KT=3, NT=8)
//     Wvf2 @475136  65536 B  (Wv as [128 x 128], n=h*32+d, KT=4, NT=8)
//     W2f  @540672  16384 B  (W2 [64 x 64], KT=2)
//     w3sf @557056  16384 B  (w3_self [64 x 64], KT=2)
//     w3of @573440  32768 B  (w3_others [128 x 64], KT=4)
//     W1f  @606208  24576 B  (W1 [96 x 64] pad k>=78, KT=3)
// R9/R11 lesson (twice): launch_bounds implying VGPR<120 collapses allocator
// to 64 VGPR -> ~500MB scratch spills. Never request >2 waves/EU. (256,2) is
// a FLOOR; occupancy is raised via LDS footprint instead (R16).
// R13/R14 lesson: scalar-GEMM VALU was the dominant removable in-kernel cost.
// ---------------------------------------------------------------------------
__global__ __launch_bounds__(256) void prep_all(
        const float* __restrict__ Wk, const float* __restrict__ Wq,
        const float* __restrict__ We, const float* __restrict__ Wv,
        const float* __restrict__ W2, const float* __restrict__ w3_self,
        const float* __restrict__ w3_others, const float* __restrict__ W1,
        unsigned short* __restrict__ Mf2, unsigned short* __restrict__ Wef2,
        unsigned short* __restrict__ Wvf2, unsigned short* __restrict__ W2f,
        unsigned short* __restrict__ w3sf, unsigned short* __restrict__ w3of,
        unsigned short* __restrict__ W1f)
{
    const int blk = blockIdx.x;
    if (blk < 128) {
        // ---- fold M = Wq @ Wk^T -> Mf2 fragments (32768 threads) ----
        int tid = blk * 256 + threadIdx.x;
        int h  = tid >> 13;
        int jq = (tid >> 7) & 63;
        int j  = tid & 127;
        const float* q = Wq + (h*64 + jq)*32;
        const float* k = Wk + (h*128 + j)*32;
        float acc = 0.f;
#pragma unroll
        for (int d = 0; d < 32; d += 4) {
            float4 a = *(const float4*)(q + d);
            float4 b = *(const float4*)(k + d);
            acc += a.x*b.x + a.y*b.y + a.z*b.z + a.w*b.w;
        }
        unsigned short hi = f2bf(acc);
        unsigned short lo = f2bf(acc - bf2f(hi));
        int n  = h*128 + j;
        int kt = jq >> 5, qd = (jq >> 3) & 3, jj = jq & 7;
        int nt = n >> 4,  ln = n & 15;
        size_t base = (((nt*2 + kt)*64) + qd*16 + ln)*16;
        Mf2[base + jj]     = hi;
        Mf2[base + 8 + jj] = lo;
    } else if (blk < 464) {
        // ---- conv We (7*96*128 = 86016 threads) ----
        int tid = (blk - 128) * 256 + threadIdx.x;
        int a = tid / 12288;
        int r = tid - a*12288;
        int k = r >> 7;          // 0..95
        int n = r & 127;
        float v = (k < 82) ? We[((size_t)a*82 + k)*128 + n] : 0.f;
        unsigned short hi = f2bf(v);
        unsigned short lo = f2bf(v - bf2f(hi));
        int kt = k >> 5, qd = (k >> 3) & 3, j = k & 7;
        int nt = n >> 4, ln = n & 15;
        size_t base = (size_t)a*24576 + (((nt*3 + kt)*64) + qd*16 + ln)*16;
        Wef2[base + j]     = hi;
        Wef2[base + 8 + j] = lo;
    } else if (blk < 528) {
        // ---- conv Wv (4*128*32 = 16384 threads) ----
        int tid = (blk - 464) * 256 + threadIdx.x;
        int h = tid >> 12;
        int j = (tid >> 5) & 127;
        int d = tid & 31;
        float v = Wv[tid];
        unsigned short hi = f2bf(v);
        unsigned short lo = f2bf(v - bf2f(hi));
        int k = j, n = h*32 + d;
        int kt = k >> 5, qd = (k >> 3) & 3, jj = k & 7;
        int nt = n >> 4, ln = n & 15;
        size_t base = (((nt*4 + kt)*64) + qd*16 + ln)*16;
        Wvf2[base + jj]     = hi;
        Wvf2[base + 8 + jj] = lo;
    } else {
        // ---- conv self weights (22528 threads) ----
        int tid = (blk - 528) * 256 + threadIdx.x;
        const float* src;
        unsigned short* dst;
        int idx, KT, kmax;
        if (tid < 4096)       { src = W2;        dst = W2f;  idx = tid;         KT = 2; kmax = 64; }
        else if (tid < 8192)  { src = w3_self;   dst = w3sf; idx = tid - 4096;  KT = 2; kmax = 64; }
        else if (tid < 16384) { src = w3_others; dst = w3of; idx = tid - 8192;  KT = 4; kmax = 128; }
        else                  { src = W1;        dst = W1f;  idx = tid - 16384; KT = 3; kmax = 78; }
        int k = idx >> 6;
        int n = idx & 63;
        float v = (k < kmax) ? src[k*64 + n] : 0.f;
        unsigned short hi = f2bf(v);
        unsigned short lo = f2bf(v - bf2f(hi));
        int kt = k >> 5, qd = (k >> 3) & 3, j = k & 7;
        int nt = n >> 4, ln = n & 15;
        size_t base = (((nt*KT + kt)*64) + qd*16 + ln)*16;
        dst[base + j]     = hi;
        dst[base + 8 + j] = lo;
    }
}

// ---------------------------------------------------------------------------
// Fused critic. TB=32 rows/block, 256 threads (4 waves), 1024 blocks.
// R16 = R14/R15 compute structure with sEn SINGLE-buffered:
//   LDS 61440 -> 44032 B  =>  3 blocks/CU (12 waves) at VGPR=128.
//   (Occupancy raised via LDS, NOT launch_bounds — R9/R11 lesson.)
//   Cost: 2 barriers/agent again. Co-scheduling preserved: interval after
//   B2 contains vals(a) AND next iteration's enc(a+1) (enc reads only the
//   still-double-buffered sIn; its sEn write waits at B1).
// Interval audit:
//   B2(a-1)..B1(a): vals(a-1) reads sEn; enc(a) reads sIn[a&1]; prefetch.
//                   NO LDS writes.
//   B1(a)..B2(a):   write sEn(a) (disjoint per-lane cols); stageIn ->
//                   sIn[(a+1)&1] (last read >=2 barriers ago).
// Every LDS producer->consumer crosses a __syncthreads. 3-blocks/CU was the
// historical nondeterminism condition; root cause (un-barriered same-wave
// LDS stats) was eliminated in R8 — this round tests that fix under the
// original condition. Abort criterion: any absmax jump -> revert + quarantine.
// LDS 44032 B:
//   self : sXbH[32x104]@0, sXbL@6656; sX1bH[32x72]@13312, sX1bL@17920;
//          sX2bH@22528, sX2bL@27136 (ends 31744)
//   t    : sT bf16[32x520]@0..33280 (overlays; written only after the
//          internal barrier ending all sXb/sX1b/sX2b reads)
//   agent: sIn buf k: H@k*13312, L@+6656 (ends 26624)
//          sEn (single): H@26624, L@35328 (ends 44032)
//   final: sOvH bf16[32x136]@0, sOvL@8704, sRed f32[32x4]@17408
// ---------------------------------------------------------------------------
__global__ __launch_bounds__(256, 2) void fused_critic(
    const float* __restrict__ state_one, const float* __restrict__ act_one,
    const float* __restrict__ state_others, const float* __restrict__ act_others,
    const float* __restrict__ b1, const float* __restrict__ b2,
    const float* __restrict__ be, const float* __restrict__ bvp,
    const float* __restrict__ Wout, const float* __restrict__ bout,
    const unsigned short* __restrict__ Mf2, const unsigned short* __restrict__ Wef2,
    const unsigned short* __restrict__ Wvf2, const unsigned short* __restrict__ W2f,
    const unsigned short* __restrict__ w3sf, const unsigned short* __restrict__ w3of,
    const unsigned short* __restrict__ W1f, float* __restrict__ out)
{
    __shared__ __align__(16) unsigned char smem[44032];
    unsigned short* sXbH  = (unsigned short*)smem;           // stride 104
    unsigned short* sXbL  = (unsigned short*)(smem + 6656);  // stride 104
    unsigned short* sX1bH = (unsigned short*)(smem + 13312); // stride 72
    unsigned short* sX1bL = (unsigned short*)(smem + 17920); // stride 72
    unsigned short* sX2bH = (unsigned short*)(smem + 22528); // stride 72
    unsigned short* sX2bL = (unsigned short*)(smem + 27136); // stride 72
    unsigned short* sT    = (unsigned short*)smem;           // stride 520
    unsigned short* sEnH  = (unsigned short*)(smem + 26624); // stride 136
    unsigned short* sEnL  = (unsigned short*)(smem + 35328); // stride 136
    unsigned short* sOvH  = (unsigned short*)smem;           // stride 136
    unsigned short* sOvL  = (unsigned short*)(smem + 8704);  // stride 136
    float*          sRed  = (float*)(smem + 17408);          // [32][4]

    const int t  = threadIdx.x;
    const int b0 = blockIdx.x * TB;
    const int w  = t >> 6;        // wave = head / self-col-tile
    const int l  = t & 63;
    const int m  = l & 15;        // MFMA A row / C col
    const int qd = l >> 4;        // quad

    const int act_r = t >> 3, act_c = t & 7;

    // staging helper: split-bf16 convert regs -> given sIn buffer (cols 0..81)
    auto stageIn = [&](unsigned short* dH, unsigned short* dL,
                       const float4& vA, const float4& vB, const float* av) {
        const int r0 = t >> 4, c4 = (t & 15) << 2;
        ushort4 h4, l4;
        h4.x = f2bf(vA.x); l4.x = f2bf(vA.x - bf2f(h4.x));
        h4.y = f2bf(vA.y); l4.y = f2bf(vA.y - bf2f(h4.y));
        h4.z = f2bf(vA.z); l4.z = f2bf(vA.z - bf2f(h4.z));
        h4.w = f2bf(vA.w); l4.w = f2bf(vA.w - bf2f(h4.w));
        *(ushort4*)(dH + r0*104 + c4) = h4;
        *(ushort4*)(dL + r0*104 + c4) = l4;
        h4.x = f2bf(vB.x); l4.x = f2bf(vB.x - bf2f(h4.x));
        h4.y = f2bf(vB.y); l4.y = f2bf(vB.y - bf2f(h4.y));
        h4.z = f2bf(vB.z); l4.z = f2bf(vB.z - bf2f(h4.z));
        h4.w = f2bf(vB.w); l4.w = f2bf(vB.w - bf2f(h4.w));
        *(ushort4*)(dH + (r0+16)*104 + c4) = h4;
        *(ushort4*)(dL + (r0+16)*104 + c4) = l4;
        if (act_c < 6) {
#pragma unroll
            for (int e = 0; e < 3; ++e) {
                float v = av[e];
                unsigned short hh = f2bf(v);
                dH[act_r*104 + 64 + act_c*3 + e] = hh;
                dL[act_r*104 + 64 + act_c*3 + e] = f2bf(v - bf2f(hh));
            }
        }
    };

    // ---- stage self input [32 x 96] split bf16 (cols 78..95 zero) ----
    {
        const int r0 = t >> 4, c4 = (t & 15) << 2;
        float4 vA = *(const float4*)(state_one + (size_t)(b0 + r0)*64 + c4);
        float4 vB = *(const float4*)(state_one + (size_t)(b0 + r0 + 16)*64 + c4);
        ushort4 h4, l4;
        h4.x = f2bf(vA.x); l4.x = f2bf(vA.x - bf2f(h4.x));
        h4.y = f2bf(vA.y); l4.y = f2bf(vA.y - bf2f(h4.y));
        h4.z = f2bf(vA.z); l4.z = f2bf(vA.z - bf2f(h4.z));
        h4.w = f2bf(vA.w); l4.w = f2bf(vA.w - bf2f(h4.w));
        *(ushort4*)(sXbH + r0*104 + c4) = h4;
        *(ushort4*)(sXbL + r0*104 + c4) = l4;
        h4.x = f2bf(vB.x); l4.x = f2bf(vB.x - bf2f(h4.x));
        h4.y = f2bf(vB.y); l4.y = f2bf(vB.y - bf2f(h4.y));
        h4.z = f2bf(vB.z); l4.z = f2bf(vB.z - bf2f(h4.z));
        h4.w = f2bf(vB.w); l4.w = f2bf(vB.w - bf2f(h4.w));
        *(ushort4*)(sXbH + (r0+16)*104 + c4) = h4;
        *(ushort4*)(sXbL + (r0+16)*104 + c4) = l4;
        // act cols 64..79 (78,79 zero)
#pragma unroll
        for (int e = 0; e < 2; ++e) {
            int cc = act_c*2 + e;
            float v = (cc < 14) ? act_one[(size_t)(b0 + act_r)*14 + cc] : 0.f;
            unsigned short hh = f2bf(v);
            sXbH[act_r*104 + 64 + cc] = hh;
            sXbL[act_r*104 + 64 + cc] = f2bf(v - bf2f(hh));
        }
        // pad cols 80..95
        for (int f = t; f < TB*16; f += 256) {
            int r = f >> 4, c = 80 + (f & 15);
            sXbH[r*104 + c] = 0;
            sXbL[r*104 + c] = 0;
        }
    }
    __syncthreads();

    // ---- phase 1 (MFMA): x1 = relu(x @ W1 + b1) -> split bf16 LDS ----
    {
        f32x4 acc1[2] = {};
#pragma unroll
        for (int kt = 0; kt < 3; ++kt) {
            bhalf8 ah0 = *(const bhalf8*)(sXbH + m*104      + kt*32 + qd*8);
            bhalf8 ah1 = *(const bhalf8*)(sXbH + (16+m)*104 + kt*32 + qd*8);
            bhalf8 al0 = *(const bhalf8*)(sXbL + m*104      + kt*32 + qd*8);
            bhalf8 al1 = *(const bhalf8*)(sXbL + (16+m)*104 + kt*32 + qd*8);
            const unsigned short* bp = W1f + ((w*3 + kt)*64 + l)*16;
            bhalf8 bh = *(const bhalf8*)(bp);
            bhalf8 bl = *(const bhalf8*)(bp + 8);
            acc1[0] = __builtin_amdgcn_mfma_f32_16x16x32_bf16(ah0, bh, acc1[0], 0, 0, 0);
            acc1[1] = __builtin_amdgcn_mfma_f32_16x16x32_bf16(ah1, bh, acc1[1], 0, 0, 0);
            acc1[0] = __builtin_amdgcn_mfma_f32_16x16x32_bf16(ah0, bl, acc1[0], 0, 0, 0);
            acc1[1] = __builtin_amdgcn_mfma_f32_16x16x32_bf16(ah1, bl, acc1[1], 0, 0, 0);
            acc1[0] = __builtin_amdgcn_mfma_f32_16x16x32_bf16(al0, bh, acc1[0], 0, 0, 0);
            acc1[1] = __builtin_amdgcn_mfma_f32_16x16x32_bf16(al1, bh, acc1[1], 0, 0, 0);
        }
        int col = w*16 + m;
        float b1c = b1[col];
#pragma unroll
        for (int rt = 0; rt < 2; ++rt)
#pragma unroll
            for (int r = 0; r < 4; ++r) {
                float e = fmaxf(acc1[rt][r] + b1c, 0.f);
                int row = rt*16 + qd*4 + r;
                unsigned short hh = f2bf(e);
                sX1bH[row*72 + col] = hh;
                sX1bL[row*72 + col] = f2bf(e - bf2f(hh));
            }
    }
    __syncthreads();

    // ---- phase 2 (MFMA): x2 = relu(x1 @ W2 + b2) -> split bf16 LDS ----
    {
        f32x4 acc2[2] = {};
#pragma unroll
        for (int kt = 0; kt < 2; ++kt) {
            bhalf8 ah0 = *(const bhalf8*)(sX1bH + m*72      + kt*32 + qd*8);
            bhalf8 ah1 = *(const bhalf8*)(sX1bH + (16+m)*72 + kt*32 + qd*8);
            bhalf8 al0 = *(const bhalf8*)(sX1bL + m*72      + kt*32 + qd*8);
            bhalf8 al1 = *(const bhalf8*)(sX1bL + (16+m)*72 + kt*32 + qd*8);
            const unsigned short* bp = W2f + ((w*2 + kt)*64 + l)*16;
            bhalf8 bh = *(const bhalf8*)(bp);
            bhalf8 bl = *(const bhalf8*)(bp + 8);
            acc2[0] = __builtin_amdgcn_mfma_f32_16x16x32_bf16(ah0, bh, acc2[0], 0, 0, 0);
            acc2[1] = __builtin_amdgcn_mfma_f32_16x16x32_bf16(ah1, bh, acc2[1], 0, 0, 0);
            acc2[0] = __builtin_amdgcn_mfma_f32_16x16x32_bf16(ah0, bl, acc2[0], 0, 0, 0);
            acc2[1] = __builtin_amdgcn_mfma_f32_16x16x32_bf16(ah1, bl, acc2[1], 0, 0, 0);
            acc2[0] = __builtin_amdgcn_mfma_f32_16x16x32_bf16(al0, bh, acc2[0], 0, 0, 0);
            acc2[1] = __builtin_amdgcn_mfma_f32_16x16x32_bf16(al1, bh, acc2[1], 0, 0, 0);
        }
        int col = w*16 + m;
        float b2c = b2[col];
#pragma unroll
        for (int rt = 0; rt < 2; ++rt)
#pragma unroll
            for (int r = 0; r < 4; ++r) {
                float e = fmaxf(acc2[rt][r] + b2c, 0.f);
                int row = rt*16 + qd*4 + r;
                unsigned short hh = f2bf(e);
                sX2bH[row*72 + col] = hh;
                sX2bL[row*72 + col] = f2bf(e - bf2f(hh));
            }
    }
    __syncthreads();

    // ---- phase 3 (MFMA): x3a = x2 @ w3_self, kept in registers ----
    f32x4 x3a[2] = {};
    {
#pragma unroll
        for (int kt = 0; kt < 2; ++kt) {
            bhalf8 ah0 = *(const bhalf8*)(sX2bH + m*72      + kt*32 + qd*8);
            bhalf8 ah1 = *(const bhalf8*)(sX2bH + (16+m)*72 + kt*32 + qd*8);
            bhalf8 al0 = *(const bhalf8*)(sX2bL + m*72      + kt*32 + qd*8);
            bhalf8 al1 = *(const bhalf8*)(sX2bL + (16+m)*72 + kt*32 + qd*8);
            const unsigned short* bp = w3sf + ((w*2 + kt)*64 + l)*16;
            bhalf8 bh = *(const bhalf8*)(bp);
            bhalf8 bl = *(const bhalf8*)(bp + 8);
            x3a[0] = __builtin_amdgcn_mfma_f32_16x16x32_bf16(ah0, bh, x3a[0], 0, 0, 0);
            x3a[1] = __builtin_amdgcn_mfma_f32_16x16x32_bf16(ah1, bh, x3a[1], 0, 0, 0);
            x3a[0] = __builtin_amdgcn_mfma_f32_16x16x32_bf16(ah0, bl, x3a[0], 0, 0, 0);
            x3a[1] = __builtin_amdgcn_mfma_f32_16x16x32_bf16(ah1, bl, x3a[1], 0, 0, 0);
            x3a[0] = __builtin_amdgcn_mfma_f32_16x16x32_bf16(al0, bh, x3a[0], 0, 0, 0);
            x3a[1] = __builtin_amdgcn_mfma_f32_16x16x32_bf16(al1, bh, x3a[1], 0, 0, 0);
        }
    }

    // ---- phase 4: t = x1 @ M, split 3-term MFMA, -> sT bf16 ----
    {
        f32x4 tacc[2][8] = {};
#pragma unroll
        for (int kt = 0; kt < 2; ++kt) {
            bhalf8 ah0 = *(const bhalf8*)(sX1bH + m*72      + kt*32 + qd*8);
            bhalf8 ah1 = *(const bhalf8*)(sX1bH + (16+m)*72 + kt*32 + qd*8);
            bhalf8 al0 = *(const bhalf8*)(sX1bL + m*72      + kt*32 + qd*8);
            bhalf8 al1 = *(const bhalf8*)(sX1bL + (16+m)*72 + kt*32 + qd*8);
#pragma unroll
            for (int nt2 = 0; nt2 < 8; ++nt2) {
                int nt = w*8 + nt2;
                const unsigned short* bp = Mf2 + ((nt*2 + kt)*64 + l)*16;
                bhalf8 bh = *(const bhalf8*)(bp);
                bhalf8 bl = *(const bhalf8*)(bp + 8);
                tacc[0][nt2] = __builtin_amdgcn_mfma_f32_16x16x32_bf16(ah0, bh, tacc[0][nt2], 0, 0, 0);
                tacc[1][nt2] = __builtin_amdgcn_mfma_f32_16x16x32_bf16(ah1, bh, tacc[1][nt2], 0, 0, 0);
                tacc[0][nt2] = __builtin_amdgcn_mfma_f32_16x16x32_bf16(ah0, bl, tacc[0][nt2], 0, 0, 0);
                tacc[1][nt2] = __builtin_amdgcn_mfma_f32_16x16x32_bf16(ah1, bl, tacc[1][nt2], 0, 0, 0);
                tacc[0][nt2] = __builtin_amdgcn_mfma_f32_16x16x32_bf16(al0, bh, tacc[0][nt2], 0, 0, 0);
                tacc[1][nt2] = __builtin_amdgcn_mfma_f32_16x16x32_bf16(al1, bh, tacc[1][nt2], 0, 0, 0);
            }
        }
        __syncthreads();   // ALL reads of sXb/sX1b/sX2b done before sT overlays
#pragma unroll
        for (int rt = 0; rt < 2; ++rt)
#pragma unroll
            for (int nt2 = 0; nt2 < 8; ++nt2)
#pragma unroll
                for (int r = 0; r < 4; ++r)
                    sT[(rt*16 + qd*4 + r)*520 + w*128 + nt2*16 + m] =
                        f2bf(tacc[rt][nt2][r]);
    }
    __syncthreads();

    // ---- load t as B-FRAGMENT registers (logits MFMA), rows m / 16+m ----
    bhalf8 tB0[4], tB1[4];
    {
#pragma unroll
        for (int kt = 0; kt < 4; ++kt) {
            tB0[kt] = *(const bhalf8*)(sT + m*520      + w*128 + kt*32 + qd*8);
            tB1[kt] = *(const bhalf8*)(sT + (16+m)*520 + w*128 + kt*32 + qd*8);
        }
    }
    __syncthreads();   // sT region free for sIn buffers

    // zero-pad cols 82..95 of BOTH sIn buffers once
    for (int f = t; f < TB*16; f += 256) {
        int r = f >> 4, c = f & 15;
        if (c >= 2) {
#pragma unroll
            for (int k = 0; k < 2; ++k) {
                unsigned short* dH = (unsigned short*)(smem + k*13312);
                unsigned short* dL = (unsigned short*)(smem + k*13312 + 6656);
                dH[r*104 + 80 + c] = 0;
                dL[r*104 + 80 + c] = 0;
            }
        }
    }
    // stage agent 0 directly into buffer 0
    {
        const float* sa = state_others + (size_t)b0 * 64;
        float4 vA = *(const float4*)(sa + t*4);
        float4 vB = *(const float4*)(sa + t*4 + 1024);
        float av[3] = {0.f, 0.f, 0.f};
        if (act_c < 6) {
            const float* aa = act_others + (size_t)(b0 + act_r)*18 + act_c*3;
            av[0] = aa[0]; av[1] = aa[1]; av[2] = aa[2];
        }
        stageIn((unsigned short*)smem, (unsigned short*)(smem + 6656),
                vA, vB, av);
    }
    __syncthreads();   // sIn buf0 (agent 0) ready

    const float bv0 = bvp[w*32 + m];
    const float bv1 = bvp[w*32 + 16 + m];
    f32x4 o4[2][2] = {};
    float mR = -1e30f, sR = 0.f;

    // diag extraction constants: logit row b_l sits in lane src, lacc[b_l>>4]
    const int nsel = l & 15;
    const int srcl = ((nsel >> 2) << 4) | nsel;

    float4 pfA, pfB; float pfa[3] = {0.f, 0.f, 0.f};

    for (int a = 0; a < 7; ++a) {
        unsigned short* sInHc = (unsigned short*)(smem + (a&1)*13312);
        unsigned short* sInLc = (unsigned short*)(smem + (a&1)*13312 + 6656);
        unsigned short* sInHn = (unsigned short*)(smem + ((a+1)&1)*13312);
        unsigned short* sInLn = (unsigned short*)(smem + ((a+1)&1)*13312 + 6656);

        // ---- issue next agent's HBM loads (regs); hides under enc ----
        if (a < 6) {
            const float* sa = state_others + ((size_t)(a+1)*BTOT + b0)*64;
            pfA = *(const float4*)(sa + t*4);
            pfB = *(const float4*)(sa + t*4 + 1024);
            if (act_c < 6) {
                const float* aa = act_others
                    + ((size_t)(a+1)*BTOT + b0 + act_r)*18 + act_c*3;
                pfa[0] = aa[0]; pfa[1] = aa[1]; pfa[2] = aa[2];
            }
        }
        float be0 = be[a*128 + 32*w + m];
        float be1 = be[a*128 + 32*w + 16 + m];

        // ---- enc(a) = inp @ We_a -> eacc regs (same interval as vals(a-1))
        f32x4 eacc[2][2] = {};
#pragma unroll
        for (int kt = 0; kt < 3; ++kt) {
            bhalf8 ah0 = *(const bhalf8*)(sInHc + m*104      + kt*32 + qd*8);
            bhalf8 ah1 = *(const bhalf8*)(sInHc + (16+m)*104 + kt*32 + qd*8);
            bhalf8 al0 = *(const bhalf8*)(sInLc + m*104      + kt*32 + qd*8);
            bhalf8 al1 = *(const bhalf8*)(sInLc + (16+m)*104 + kt*32 + qd*8);
#pragma unroll
            for (int nt2 = 0; nt2 < 2; ++nt2) {
                int nt = 2*w + nt2;
                const unsigned short* bp =
                    Wef2 + (size_t)a*24576 + ((nt*3 + kt)*64 + l)*16;
                bhalf8 bh = *(const bhalf8*)(bp);
                bhalf8 bl = *(const bhalf8*)(bp + 8);
                eacc[0][nt2] = __builtin_amdgcn_mfma_f32_16x16x32_bf16(ah0, bh, eacc[0][nt2], 0, 0, 0);
                eacc[1][nt2] = __builtin_amdgcn_mfma_f32_16x16x32_bf16(ah1, bh, eacc[1][nt2], 0, 0, 0);
                eacc[0][nt2] = __builtin_amdgcn_mfma_f32_16x16x32_bf16(ah0, bl, eacc[0][nt2], 0, 0, 0);
                eacc[1][nt2] = __builtin_amdgcn_mfma_f32_16x16x32_bf16(ah1, bl, eacc[1][nt2], 0, 0, 0);
                eacc[0][nt2] = __builtin_amdgcn_mfma_f32_16x16x32_bf16(al0, bh, eacc[0][nt2], 0, 0, 0);
                eacc[1][nt2] = __builtin_amdgcn_mfma_f32_16x16x32_bf16(al1, bh, eacc[1][nt2], 0, 0, 0);
            }
        }

        // ---- B1: vals(a-1) reads of sEn done; safe to overwrite ----
        __syncthreads();

        // ---- write sEn(a) (relu+bias, split); stage sIn(a+1) ----
        {
#pragma unroll
            for (int rt = 0; rt < 2; ++rt)
#pragma unroll
                for (int nt2 = 0; nt2 < 2; ++nt2) {
                    float bb = nt2 ? be1 : be0;
#pragma unroll
                    for (int r = 0; r < 4; ++r) {
                        float e = fmaxf(eacc[rt][nt2][r] + bb, 0.f);
                        int row = rt*16 + qd*4 + r;
                        int col = 32*w + nt2*16 + m;
                        unsigned short hh = f2bf(e);
                        sEnH[row*136 + col] = hh;
                        sEnL[row*136 + col] = f2bf(e - bf2f(hh));
                    }
                }
        }
        if (a < 6) stageIn(sInHn, sInLn, pfA, pfB, pfa);

        // ---- B2: sEn(a) and sIn(a+1) visible to all waves ----
        __syncthreads();

        // ---- fused vals + logits MFMA loop (shared A-fragments) ----
        f32x4 vacc[2][2] = {};
        f32x4 lacc0 = {}, lacc1 = {};
#pragma unroll
        for (int kt = 0; kt < 4; ++kt) {
            bhalf8 ah0 = *(const bhalf8*)(sEnH + m*136      + kt*32 + qd*8);
            bhalf8 ah1 = *(const bhalf8*)(sEnH + (16+m)*136 + kt*32 + qd*8);
            bhalf8 al0 = *(const bhalf8*)(sEnL + m*136      + kt*32 + qd*8);
            bhalf8 al1 = *(const bhalf8*)(sEnL + (16+m)*136 + kt*32 + qd*8);
#pragma unroll
            for (int nt2 = 0; nt2 < 2; ++nt2) {
                int nt = 2*w + nt2;
                const unsigned short* bp = Wvf2 + ((nt*4 + kt)*64 + l)*16;
                bhalf8 bh = *(const bhalf8*)(bp);
                bhalf8 bl = *(const bhalf8*)(bp + 8);
                vacc[0][nt2] = __builtin_amdgcn_mfma_f32_16x16x32_bf16(ah0, bh, vacc[0][nt2], 0, 0, 0);
                vacc[1][nt2] = __builtin_amdgcn_mfma_f32_16x16x32_bf16(ah1, bh, vacc[1][nt2], 0, 0, 0);
                vacc[0][nt2] = __builtin_amdgcn_mfma_f32_16x16x32_bf16(ah0, bl, vacc[0][nt2], 0, 0, 0);
                vacc[1][nt2] = __builtin_amdgcn_mfma_f32_16x16x32_bf16(ah1, bl, vacc[1][nt2], 0, 0, 0);
                vacc[0][nt2] = __builtin_amdgcn_mfma_f32_16x16x32_bf16(al0, bh, vacc[0][nt2], 0, 0, 0);
                vacc[1][nt2] = __builtin_amdgcn_mfma_f32_16x16x32_bf16(al1, bh, vacc[1][nt2], 0, 0, 0);
            }
            // logits diag: C[r][n] = enc_rows @ t_rows^T (B-frag from regs)
            lacc0 = __builtin_amdgcn_mfma_f32_16x16x32_bf16(ah0, tB0[kt], lacc0, 0, 0, 0);
            lacc0 = __builtin_amdgcn_mfma_f32_16x16x32_bf16(al0, tB0[kt], lacc0, 0, 0, 0);
            lacc1 = __builtin_amdgcn_mfma_f32_16x16x32_bf16(ah1, tB1[kt], lacc1, 0, 0, 0);
            lacc1 = __builtin_amdgcn_mfma_f32_16x16x32_bf16(al1, tB1[kt], lacc1, 0, 0, 0);
        }

        // ---- extract diag -> stats (registers + wave-collective only) ----
        float alpha, pp;
        {
            float e01 = (l & 1) ? lacc0[1] : lacc0[0];
            float e23 = (l & 1) ? lacc0[3] : lacc0[2];
            float d0  = (l & 2) ? e23 : e01;
            float f01 = (l & 1) ? lacc1[1] : lacc1[0];
            float f23 = (l & 1) ? lacc1[3] : lacc1[2];
            float d1  = (l & 2) ? f23 : f01;
            float g0 = __shfl(d0, srcl);
            float g1 = __shfl(d1, srcl);
            float part = (l & 16) ? g1 : g0;
            float lg = part * 0.17677669529663687f;   // 1/sqrt(32)
            float mn = fmaxf(mR, lg);
            alpha = __expf(mR - mn);
            pp    = __expf(lg - mn);
            sR = sR*alpha + pp;
            mR = mn;
        }

        // ---- online accumulate o4 ----
        {
#pragma unroll
            for (int rt = 0; rt < 2; ++rt)
#pragma unroll
                for (int r = 0; r < 4; ++r) {
                    int row = rt*16 + qd*4 + r;
                    float al = __shfl(alpha, row);
                    float p  = __shfl(pp, row);
#pragma unroll
                    for (int nt2 = 0; nt2 < 2; ++nt2) {
                        float bb = nt2 ? bv1 : bv0;
                        o4[rt][nt2][r] = o4[rt][nt2][r]*al
                                       + p*fmaxf(vacc[rt][nt2][r] + bb, 0.f);
                    }
                }
        }
    }
    __syncthreads();   // all sEn/sIn reads done; sOv overlays sIn region

    // ---- normalize, write ov as SPLIT bf16 (A-operand for final MFMA) ----
    {
        float rinv = 1.0f / sR;
#pragma unroll
        for (int rt = 0; rt < 2; ++rt)
#pragma unroll
            for (int r = 0; r < 4; ++r) {
                int row = rt*16 + qd*4 + r;
                float inv = __shfl(rinv, row);
#pragma unroll
                for (int nt2 = 0; nt2 < 2; ++nt2) {
                    float v = o4[rt][nt2][r]*inv;
                    int col = 32*w + nt2*16 + m;
                    unsigned short hh = f2bf(v);
                    sOvH[row*136 + col] = hh;
                    sOvL[row*136 + col] = f2bf(v - bf2f(hh));
                }
            }
    }
    __syncthreads();

    // ---- final (MFMA): x3a += ov @ w3_others; out = relu(x3a).Wout + bout
    {
#pragma unroll
        for (int kt = 0; kt < 4; ++kt) {
            bhalf8 ah0 = *(const bhalf8*)(sOvH + m*136      + kt*32 + qd*8);
            bhalf8 ah1 = *(const bhalf8*)(sOvH + (16+m)*136 + kt*32 + qd*8);
            bhalf8 al0 = *(const bhalf8*)(sOvL + m*136      + kt*32 + qd*8);
            bhalf8 al1 = *(const bhalf8*)(sOvL + (16+m)*136 + kt*32 + qd*8);
            const unsigned short* bp = w3of + ((w*4 + kt)*64 + l)*16;
            bhalf8 bh = *(const bhalf8*)(bp);
            bhalf8 bl = *(const bhalf8*)(bp + 8);
            x3a[0] = __builtin_amdgcn_mfma_f32_16x16x32_bf16(ah0, bh, x3a[0], 0, 0, 0);
            x3a[1] = __builtin_amdgcn_mfma_f32_16x16x32_bf16(ah1, bh, x3a[1], 0, 0, 0);
            x3a[0] = __builtin_amdgcn_mfma_f32_16x16x32_bf16(ah0, bl, x3a[0], 0, 0, 0);
            x3a[1] = __builtin_amdgcn_mfma_f32_16x16x32_bf16(ah1, bl, x3a[1], 0, 0, 0);
            x3a[0] = __builtin_amdgcn_mfma_f32_16x16x32_bf16(al0, bh, x3a[0], 0, 0, 0);
            x3a[1] = __builtin_amdgcn_mfma_f32_16x16x32_bf16(al1, bh, x3a[1], 0, 0, 0);
        }
        // lane holds x3[row=rt*16+qd*4+r][col=16w+m]; relu, *Wout, reduce m
        float wo = Wout[w*16 + m];
#pragma unroll
        for (int rt = 0; rt < 2; ++rt)
#pragma unroll
            for (int r = 0; r < 4; ++r) {
                float p = fmaxf(x3a[rt][r], 0.f) * wo;
                p += __shfl_xor(p, 1);
                p += __shfl_xor(p, 2);
                p += __shfl_xor(p, 4);
                p += __shfl_xor(p, 8);
                if (m == 0)
                    sRed[(rt*16 + qd*4 + r)*4 + w] = p;
            }
    }
    __syncthreads();
    if (t < 32)
        out[b0 + t] = sRed[t*4+0] + sRed[t*4+1] + sRed[t*4+2] + sRed[t*4+3]
                    + bout[0];
}

extern "C" void kernel_launch(void* const* d_in, const int* in_sizes, int n_in,
                              void* d_out, int out_size, void* d_ws, size_t ws_size,
                              hipStream_t stream) {
    (void)in_sizes; (void)n_in; (void)out_size; (void)ws_size;
    const float* state_one    = (const float*)d_in[0];
    const float* act_one      = (const float*)d_in[1];
    const float* state_others = (const float*)d_in[2];
    const float* act_others   = (const float*)d_in[3];
    const float* W1           = (const float*)d_in[4];
    const float* b1           = (const float*)d_in[5];
    const float* W2           = (const float*)d_in[6];
    const float* b2           = (const float*)d_in[7];
    const float* w3_self      = (const float*)d_in[8];
    const float* We           = (const float*)d_in[9];
    const float* be           = (const float*)d_in[10];
    const float* Wk           = (const float*)d_in[11];
    const float* Wq           = (const float*)d_in[12];
    const float* Wv           = (const float*)d_in[13];
    const float* bv           = (const float*)d_in[14];
    const float* w3_others    = (const float*)d_in[15];
    const float* Wout         = (const float*)d_in[16];
    const float* bout         = (const float*)d_in[17];
    float* out = (float*)d_out;

    unsigned short* Mf2  = (unsigned short*)d_ws;                    // 131072 B
    unsigned short* Wef2 = (unsigned short*)((char*)d_ws + 131072);  // 344064 B
    unsigned short* Wvf2 = (unsigned short*)((char*)d_ws + 475136);  // 65536 B
    unsigned short* W2f  = (unsigned short*)((char*)d_ws + 540672);  // 16384 B
    unsigned short* w3sf = (unsigned short*)((char*)d_ws + 557056);  // 16384 B
    unsigned short* w3of = (unsigned short*)((char*)d_ws + 573440);  // 32768 B
    unsigned short* W1f  = (unsigned short*)((char*)d_ws + 606208);  // 24576 B

    prep_all<<<616, 256, 0, stream>>>(Wk, Wq, We, Wv, W2, w3_self, w3_others,
                                      W1, Mf2, Wef2, Wvf2, W2f, w3sf, w3of, W1f);
    fused_critic<<<BTOT/TB, 256, 0, stream>>>(
        state_one, act_one, state_others, act_others,
        b1, b2, be, bv, Wout, bout,
        Mf2, Wef2, Wvf2, W2f, w3sf, w3of, W1f, out);
}